// Round 1
// baseline (824.864 us; speedup 1.0000x reference)
//
#include <hip/hip_runtime.h>
#include <math.h>

#define N_NODES 50000
#define N_EDGES 800000
#define BN_EPS_F 1e-5f
#define SCAN_BS 512
#define SCAN_NB 98   // ceil(50000/512)

static __device__ __forceinline__ float4 ld4(const float* p) {
    return *reinterpret_cast<const float4*>(p);
}

// ---------------- CSR build ----------------

__global__ void k_zero_i32(int* __restrict__ p, int n) {
    int i = blockIdx.x * blockDim.x + threadIdx.x;
    if (i < n) p[i] = 0;
}

__global__ void k_count(const int* __restrict__ dst, int* __restrict__ deg) {
    int e = blockIdx.x * blockDim.x + threadIdx.x;
    if (e < N_EDGES) atomicAdd(&deg[dst[e]], 1);
}

__global__ void k_scan1(const int* __restrict__ deg, int* __restrict__ offs, int* __restrict__ bsum) {
    __shared__ int sh[SCAN_BS];
    int t = threadIdx.x;
    int g = blockIdx.x * SCAN_BS + t;
    int v = (g < N_NODES) ? deg[g] : 0;
    sh[t] = v;
    __syncthreads();
    for (int off = 1; off < SCAN_BS; off <<= 1) {
        int add = (t >= off) ? sh[t - off] : 0;
        __syncthreads();
        sh[t] += add;
        __syncthreads();
    }
    if (g < N_NODES) offs[g] = sh[t] - v;   // exclusive within block
    if (t == SCAN_BS - 1) bsum[blockIdx.x] = sh[t];
}

__global__ void k_scan2(int* __restrict__ bsum, int nb) {
    __shared__ int sh[128];
    int t = threadIdx.x;
    int v = (t < nb) ? bsum[t] : 0;
    sh[t] = v;
    __syncthreads();
    for (int off = 1; off < 128; off <<= 1) {
        int add = (t >= off) ? sh[t - off] : 0;
        __syncthreads();
        sh[t] += add;
        __syncthreads();
    }
    if (t < nb) bsum[t] = sh[t] - v;        // exclusive block bases
}

__global__ void k_scan3(const int* __restrict__ deg, int* __restrict__ offs,
                        const int* __restrict__ bsum, float* __restrict__ inv_deg) {
    int g = blockIdx.x * blockDim.x + threadIdx.x;
    if (g < N_NODES) {
        offs[g] += bsum[g / SCAN_BS];
        int d = deg[g];
        inv_deg[g] = 1.0f / (float)(d > 1 ? d : 1);
    }
}

__global__ void k_fill(const int* __restrict__ src, const int* __restrict__ dst,
                       const int* __restrict__ offs, int* __restrict__ cursor,
                       int* __restrict__ eids) {
    int e = blockIdx.x * blockDim.x + threadIdx.x;
    if (e < N_EDGES) {
        int d = dst[e];
        int p = atomicAdd(&cursor[d], 1);
        eids[offs[d] + p] = src[e];
    }
}

// ---------------- mean aggregation: one wave per node ----------------

template<int F>
__global__ __launch_bounds__(256) void k_aggregate(
        const float* __restrict__ h, const int* __restrict__ eids,
        const int* __restrict__ offs, const int* __restrict__ deg,
        const float* __restrict__ inv_deg, float* __restrict__ aggr) {
    int node = (blockIdx.x * 256 + threadIdx.x) >> 6;
    int lane = threadIdx.x & 63;
    if (node >= N_NODES) return;
    constexpr int V = F / 64;   // 2 (F=128) or 4 (F=256) floats per lane
    float acc[V];
#pragma unroll
    for (int v = 0; v < V; ++v) acc[v] = 0.f;
    int beg = offs[node];
    int d = deg[node];
    const int c0 = lane * V;
    for (int j = 0; j < d; ++j) {
        int s = eids[beg + j];
        const float* row = h + (size_t)s * F + c0;
        if constexpr (V == 2) {
            float2 t = *reinterpret_cast<const float2*>(row);
            acc[0] += t.x; acc[1] += t.y;
        } else {
            float4 t = ld4(row);
            acc[0] += t.x; acc[1] += t.y; acc[2] += t.z; acc[3] += t.w;
        }
    }
    float sc = inv_deg[node];
    float* o = aggr + (size_t)node * F + c0;
    if constexpr (V == 2) {
        *reinterpret_cast<float2*>(o) = make_float2(acc[0] * sc, acc[1] * sc);
    } else {
        *reinterpret_cast<float4*>(o) = make_float4(acc[0] * sc, acc[1] * sc, acc[2] * sc, acc[3] * sc);
    }
}

// ---------------- dual GEMM: out = A1@W1 + A2@W2 + b, optional ReLU ----------------
// 64x64 tile, BK=32, 256 threads, 4x4 micro-tile.

template<int RELU>
__global__ __launch_bounds__(256) void k_gemm_dual(
        const float* __restrict__ A1, const float* __restrict__ A2,
        const float* __restrict__ W1, const float* __restrict__ W2,
        const float* __restrict__ bias, float* __restrict__ out,
        int K, int F) {
    __shared__ __align__(16) float As[32][68];
    __shared__ __align__(16) float Ws[32][64];
    const int row0 = blockIdx.x * 64;
    const int col0 = blockIdx.y * 64;
    const int tid = threadIdx.x;
    const int tx = tid & 15, ty = tid >> 4;
    float acc[4][4] = {{0.f}};
    for (int m = 0; m < 2; ++m) {
        const float* __restrict__ A = m ? A2 : A1;
        const float* __restrict__ W = m ? W2 : W1;
        for (int k0 = 0; k0 < K; k0 += 32) {
            __syncthreads();
            // A tile 64x32 (transposed into LDS [k][row])
#pragma unroll
            for (int l = 0; l < 2; ++l) {
                int idx = tid + l * 256;
                int r = idx >> 3;
                int c4 = (idx & 7) * 4;
                int gr = row0 + r;
                float4 v = make_float4(0.f, 0.f, 0.f, 0.f);
                if (gr < N_NODES) v = ld4(&A[(size_t)gr * K + k0 + c4]);
                As[c4 + 0][r] = v.x; As[c4 + 1][r] = v.y;
                As[c4 + 2][r] = v.z; As[c4 + 3][r] = v.w;
            }
            // W tile 32x64 (natural layout)
#pragma unroll
            for (int l = 0; l < 2; ++l) {
                int idx = tid + l * 256;
                int r = idx >> 4;
                int c4 = (idx & 15) * 4;
                *reinterpret_cast<float4*>(&Ws[r][c4]) = ld4(&W[(size_t)(k0 + r) * F + col0 + c4]);
            }
            __syncthreads();
#pragma unroll
            for (int kk = 0; kk < 32; ++kk) {
                float4 a = *reinterpret_cast<const float4*>(&As[kk][ty * 4]);
                float4 b = *reinterpret_cast<const float4*>(&Ws[kk][tx * 4]);
                acc[0][0] += a.x * b.x; acc[0][1] += a.x * b.y; acc[0][2] += a.x * b.z; acc[0][3] += a.x * b.w;
                acc[1][0] += a.y * b.x; acc[1][1] += a.y * b.y; acc[1][2] += a.y * b.z; acc[1][3] += a.y * b.w;
                acc[2][0] += a.z * b.x; acc[2][1] += a.z * b.y; acc[2][2] += a.z * b.z; acc[2][3] += a.z * b.w;
                acc[3][0] += a.w * b.x; acc[3][1] += a.w * b.y; acc[3][2] += a.w * b.z; acc[3][3] += a.w * b.w;
            }
        }
    }
    float4 bv = ld4(&bias[col0 + tx * 4]);
#pragma unroll
    for (int i = 0; i < 4; ++i) {
        int gr = row0 + ty * 4 + i;
        if (gr < N_NODES) {
            float4 o;
            o.x = acc[i][0] + bv.x; o.y = acc[i][1] + bv.y;
            o.z = acc[i][2] + bv.z; o.w = acc[i][3] + bv.w;
            if (RELU) {
                o.x = fmaxf(o.x, 0.f); o.y = fmaxf(o.y, 0.f);
                o.z = fmaxf(o.z, 0.f); o.w = fmaxf(o.w, 0.f);
            }
            *reinterpret_cast<float4*>(&out[(size_t)gr * F + col0 + tx * 4]) = o;
        }
    }
}

// ---------------- BatchNorm ----------------

template<int F>
__global__ void k_bn_stats(const float* __restrict__ h, float* __restrict__ sums) {
    int col = threadIdx.x;  // blockDim == F
    float s = 0.f, s2 = 0.f;
    for (int r = blockIdx.x; r < N_NODES; r += gridDim.x) {
        float v = h[(size_t)r * F + col];
        s += v; s2 += v * v;
    }
    atomicAdd(&sums[col], s);
    atomicAdd(&sums[F + col], s2);
}

template<int F>
__global__ void k_bn_final(const float* __restrict__ sums, const float* __restrict__ gamma,
                           const float* __restrict__ beta, float* __restrict__ scsh) {
    int c = threadIdx.x;
    if (c < F) {
        float mean = sums[c] * (1.0f / N_NODES);
        float var = sums[F + c] * (1.0f / N_NODES) - mean * mean;
        float sc = gamma[c] * rsqrtf(var + BN_EPS_F);
        scsh[c] = sc;
        scsh[F + c] = beta[c] - mean * sc;
    }
}

template<int F>
__global__ void k_bn_apply(float* __restrict__ h, const float* __restrict__ scsh) {
    int i = blockIdx.x * blockDim.x + threadIdx.x;   // float4 index
    int total = N_NODES * F / 4;
    if (i >= total) return;
    int c = (i * 4) % F;
    float4 v = ld4(&h[(size_t)i * 4]);
    float4 s = ld4(&scsh[c]);
    float4 b = ld4(&scsh[F + c]);
    v.x = v.x * s.x + b.x; v.y = v.y * s.y + b.y;
    v.z = v.z * s.z + b.z; v.w = v.w * s.w + b.w;
    *reinterpret_cast<float4*>(&h[(size_t)i * 4]) = v;
}

// ---------------- reparameterize ----------------

__global__ void k_reparam(const float* __restrict__ h3, const float* __restrict__ eps,
                          float* __restrict__ z) {
    int i = blockIdx.x * blockDim.x + threadIdx.x;   // float4 index over N*64
    int total = N_NODES * 64 / 4;
    if (i >= total) return;
    int r = i >> 4;             // 16 float4 per row
    int c4 = (i & 15) * 4;
    float4 m = ld4(&h3[(size_t)r * 128 + c4]);
    float4 ls = ld4(&h3[(size_t)r * 128 + 64 + c4]);
    float4 e = ld4(&eps[(size_t)r * 64 + c4]);
    float4 o;
    o.x = m.x + expf(ls.x) * e.x;
    o.y = m.y + expf(ls.y) * e.y;
    o.z = m.z + expf(ls.z) * e.z;
    o.w = m.w + expf(ls.w) * e.w;
    *reinterpret_cast<float4*>(&z[(size_t)r * 64 + c4]) = o;
}

// ---------------- launch ----------------

extern "C" void kernel_launch(void* const* d_in, const int* in_sizes, int n_in,
                              void* d_out, int out_size, void* d_ws, size_t ws_size,
                              hipStream_t stream) {
    (void)in_sizes; (void)n_in; (void)out_size; (void)ws_size;
    const float* x   = (const float*)d_in[0];
    const int*   src = (const int*)d_in[1];
    const int*   dst = (const int*)d_in[2];
    const float* eps = (const float*)d_in[3];
    const float* W1l = (const float*)d_in[4];
    const float* W1r = (const float*)d_in[5];
    const float* b1  = (const float*)d_in[6];
    const float* g1  = (const float*)d_in[7];
    const float* be1 = (const float*)d_in[8];
    const float* W2l = (const float*)d_in[9];
    const float* W2r = (const float*)d_in[10];
    const float* b2  = (const float*)d_in[11];
    const float* g2  = (const float*)d_in[12];
    const float* be2 = (const float*)d_in[13];
    const float* W3l = (const float*)d_in[14];
    const float* W3r = (const float*)d_in[15];
    const float* b3  = (const float*)d_in[16];
    float* z = (float*)d_out;

    char* ws = (char*)d_ws;
    size_t off = 0;
    auto alloc = [&](size_t bytes) -> char* {
        char* p = ws + off;
        off += (bytes + 255) & ~(size_t)255;
        return p;
    };
    // NOTE: deg, cursor, stats FIRST (one contiguous zero region)
    int*   deg    = (int*)alloc(N_NODES * 4);
    int*   cursor = (int*)alloc(N_NODES * 4);
    float* stats  = (float*)alloc(1536 * 4);
    size_t zero_bytes = off;
    int*   offs   = (int*)alloc(N_NODES * 4);
    int*   bsum   = (int*)alloc(128 * 4);
    int*   eids   = (int*)alloc((size_t)N_EDGES * 4);
    float* invd   = (float*)alloc(N_NODES * 4);
    float* aggr   = (float*)alloc((size_t)N_NODES * 256 * 4);
    float* h1     = (float*)alloc((size_t)N_NODES * 128 * 4);   // reused as h3
    float* h2     = (float*)alloc((size_t)N_NODES * 256 * 4);
    float* h3     = h1;  // h1 dead by layer 3

    float* sums1 = stats;            // 2*128
    float* scsh1 = stats + 256;      // 2*128
    float* sums2 = stats + 512;      // 2*256
    float* scsh2 = stats + 1024;     // 2*256

    // CSR build (per-call: graph replay must recompute everything)
    int zn = (int)(zero_bytes / 4);
    k_zero_i32<<<(zn + 255) / 256, 256, 0, stream>>>((int*)ws, zn);
    k_count<<<(N_EDGES + 255) / 256, 256, 0, stream>>>(dst, deg);
    k_scan1<<<SCAN_NB, SCAN_BS, 0, stream>>>(deg, offs, bsum);
    k_scan2<<<1, 128, 0, stream>>>(bsum, SCAN_NB);
    k_scan3<<<(N_NODES + 255) / 256, 256, 0, stream>>>(deg, offs, bsum, invd);
    k_fill<<<(N_EDGES + 255) / 256, 256, 0, stream>>>(src, dst, offs, cursor, eids);

    const int AGG_BLKS = (N_NODES + 3) / 4;   // 4 waves (nodes) per block

    // ---- Layer 1: SAGE(x) -> relu -> BN  (K=128, F=128)
    k_aggregate<128><<<AGG_BLKS, 256, 0, stream>>>(x, eids, offs, deg, invd, aggr);
    k_gemm_dual<1><<<dim3(782, 2), 256, 0, stream>>>(aggr, x, W1l, W1r, b1, h1, 128, 128);
    k_bn_stats<128><<<240, 128, 0, stream>>>(h1, sums1);
    k_bn_final<128><<<1, 128, 0, stream>>>(sums1, g1, be1, scsh1);
    k_bn_apply<128><<<(N_NODES * 128 / 4 + 255) / 256, 256, 0, stream>>>(h1, scsh1);

    // ---- Layer 2: SAGE(h1) -> relu -> BN  (K=128, F=256)
    k_aggregate<128><<<AGG_BLKS, 256, 0, stream>>>(h1, eids, offs, deg, invd, aggr);
    k_gemm_dual<1><<<dim3(782, 4), 256, 0, stream>>>(aggr, h1, W2l, W2r, b2, h2, 128, 256);
    k_bn_stats<256><<<240, 256, 0, stream>>>(h2, sums2);
    k_bn_final<256><<<1, 256, 0, stream>>>(sums2, g2, be2, scsh2);
    k_bn_apply<256><<<(N_NODES * 256 / 4 + 255) / 256, 256, 0, stream>>>(h2, scsh2);

    // ---- Layer 3: SAGE(h2), no relu/BN  (K=256, F=128)
    k_aggregate<256><<<AGG_BLKS, 256, 0, stream>>>(h2, eids, offs, deg, invd, aggr);
    k_gemm_dual<0><<<dim3(782, 2), 256, 0, stream>>>(aggr, h2, W3l, W3r, b3, h3, 256, 128);

    // ---- reparameterize
    k_reparam<<<(N_NODES * 64 / 4 + 255) / 256, 256, 0, stream>>>(h3, eps, z);
}

// Round 2
// 490.374 us; speedup vs baseline: 1.6821x; 1.6821x over previous
//
#include <hip/hip_runtime.h>
#include <math.h>

#define N_NODES 50000
#define N_EDGES 800000
#define BN_EPS_F 1e-5f
#define SCAN_BS 512
#define SCAN_NB 98   // ceil(50000/512)

typedef unsigned short ushort_t;
typedef unsigned int uint_t;
typedef __attribute__((ext_vector_type(8))) short bf16x8;
typedef __attribute__((ext_vector_type(4))) float f32x4;

static __device__ __forceinline__ float4 ld4(const float* p) {
    return *reinterpret_cast<const float4*>(p);
}
static __device__ __forceinline__ float bf2f(ushort_t u) {
    return __uint_as_float(((uint_t)u) << 16);
}
static __device__ __forceinline__ ushort_t f2b(float f) {
    uint_t u = __float_as_uint(f);
    u += 0x7fffu + ((u >> 16) & 1u);
    return (ushort_t)(u >> 16);
}
static __device__ __forceinline__ void gload16(const void* g, void* l) {
    __builtin_amdgcn_global_load_lds(
        (const __attribute__((address_space(1))) void*)g,
        (__attribute__((address_space(3))) void*)l, 16, 0, 0);
}

// ---------------- CSR build ----------------

__global__ void k_zero_i32(int* __restrict__ p, int n) {
    int i = blockIdx.x * blockDim.x + threadIdx.x;
    if (i < n) p[i] = 0;
}

__global__ void k_count(const int* __restrict__ dst, int* __restrict__ deg) {
    int e = blockIdx.x * blockDim.x + threadIdx.x;
    if (e < N_EDGES) atomicAdd(&deg[dst[e]], 1);
}

__global__ void k_scan1(const int* __restrict__ deg, int* __restrict__ offs, int* __restrict__ bsum) {
    __shared__ int sh[SCAN_BS];
    int t = threadIdx.x;
    int g = blockIdx.x * SCAN_BS + t;
    int v = (g < N_NODES) ? deg[g] : 0;
    sh[t] = v;
    __syncthreads();
    for (int off = 1; off < SCAN_BS; off <<= 1) {
        int add = (t >= off) ? sh[t - off] : 0;
        __syncthreads();
        sh[t] += add;
        __syncthreads();
    }
    if (g < N_NODES) offs[g] = sh[t] - v;
    if (t == SCAN_BS - 1) bsum[blockIdx.x] = sh[t];
}

__global__ void k_scan2(int* __restrict__ bsum, int nb) {
    __shared__ int sh[128];
    int t = threadIdx.x;
    int v = (t < nb) ? bsum[t] : 0;
    sh[t] = v;
    __syncthreads();
    for (int off = 1; off < 128; off <<= 1) {
        int add = (t >= off) ? sh[t - off] : 0;
        __syncthreads();
        sh[t] += add;
        __syncthreads();
    }
    if (t < nb) bsum[t] = sh[t] - v;
}

__global__ void k_scan3(const int* __restrict__ deg, int* __restrict__ offs,
                        const int* __restrict__ bsum, float* __restrict__ inv_deg) {
    int g = blockIdx.x * blockDim.x + threadIdx.x;
    if (g < N_NODES) {
        offs[g] += bsum[g / SCAN_BS];
        int d = deg[g];
        inv_deg[g] = 1.0f / (float)(d > 1 ? d : 1);
    }
}

__global__ void k_fill(const int* __restrict__ src, const int* __restrict__ dst,
                       const int* __restrict__ offs, int* __restrict__ cursor,
                       int* __restrict__ eids) {
    int e = blockIdx.x * blockDim.x + threadIdx.x;
    if (e < N_EDGES) {
        int d = dst[e];
        int p = atomicAdd(&cursor[d], 1);
        eids[offs[d] + p] = src[e];
    }
}

// ---------------- conversions ----------------

__global__ void k_f2b8(const float* __restrict__ in, ushort_t* __restrict__ out, int n8) {
    int i = blockIdx.x * blockDim.x + threadIdx.x;
    if (i >= n8) return;
    float4 a = ld4(in + (size_t)i * 8);
    float4 b = ld4(in + (size_t)i * 8 + 4);
    uint_t o0 = (uint_t)f2b(a.x) | ((uint_t)f2b(a.y) << 16);
    uint_t o1 = (uint_t)f2b(a.z) | ((uint_t)f2b(a.w) << 16);
    uint_t o2 = (uint_t)f2b(b.x) | ((uint_t)f2b(b.y) << 16);
    uint_t o3 = (uint_t)f2b(b.z) | ((uint_t)f2b(b.w) << 16);
    *reinterpret_cast<uint4*>(out + (size_t)i * 8) = make_uint4(o0, o1, o2, o3);
}

// WT[f][k] = bf16(W[k][f]);  W is [K][F] row-major
__global__ void k_wtrans(const float* __restrict__ W, ushort_t* __restrict__ WT, int K, int F) {
    int idx = blockIdx.x * blockDim.x + threadIdx.x;
    if (idx < K * F) {
        int f = idx / K, k = idx - f * K;
        WT[idx] = f2b(W[(size_t)k * F + f]);
    }
}

// ---------------- mean aggregation (bf16): one wave per node ----------------

template<int F>
__global__ __launch_bounds__(256) void k_aggregate_b(
        const ushort_t* __restrict__ h, const int* __restrict__ eids,
        const int* __restrict__ offs, const int* __restrict__ deg,
        const float* __restrict__ inv_deg, ushort_t* __restrict__ aggr) {
    int node = (blockIdx.x * 256 + threadIdx.x) >> 6;
    int lane = threadIdx.x & 63;
    if (node >= N_NODES) return;
    constexpr int V = F / 64;   // bf16 per lane: 2 (F=128) or 4 (F=256)
    float acc[V];
#pragma unroll
    for (int v = 0; v < V; ++v) acc[v] = 0.f;
    int beg = offs[node];
    int d = deg[node];
    const int c0 = lane * V;
    int j = 0;
    for (; j + 2 <= d; j += 2) {
        int s0 = eids[beg + j];
        int s1 = eids[beg + j + 1];
        if constexpr (V == 2) {
            uint_t a = *reinterpret_cast<const uint_t*>(h + (size_t)s0 * F + c0);
            uint_t b = *reinterpret_cast<const uint_t*>(h + (size_t)s1 * F + c0);
            acc[0] += bf2f((ushort_t)a) + bf2f((ushort_t)b);
            acc[1] += bf2f((ushort_t)(a >> 16)) + bf2f((ushort_t)(b >> 16));
        } else {
            uint2 a = *reinterpret_cast<const uint2*>(h + (size_t)s0 * F + c0);
            uint2 b = *reinterpret_cast<const uint2*>(h + (size_t)s1 * F + c0);
            acc[0] += bf2f((ushort_t)a.x) + bf2f((ushort_t)b.x);
            acc[1] += bf2f((ushort_t)(a.x >> 16)) + bf2f((ushort_t)(b.x >> 16));
            acc[2] += bf2f((ushort_t)a.y) + bf2f((ushort_t)b.y);
            acc[3] += bf2f((ushort_t)(a.y >> 16)) + bf2f((ushort_t)(b.y >> 16));
        }
    }
    if (j < d) {
        int s0 = eids[beg + j];
        if constexpr (V == 2) {
            uint_t a = *reinterpret_cast<const uint_t*>(h + (size_t)s0 * F + c0);
            acc[0] += bf2f((ushort_t)a);
            acc[1] += bf2f((ushort_t)(a >> 16));
        } else {
            uint2 a = *reinterpret_cast<const uint2*>(h + (size_t)s0 * F + c0);
            acc[0] += bf2f((ushort_t)a.x);
            acc[1] += bf2f((ushort_t)(a.x >> 16));
            acc[2] += bf2f((ushort_t)a.y);
            acc[3] += bf2f((ushort_t)(a.y >> 16));
        }
    }
    float sc = inv_deg[node];
    if constexpr (V == 2) {
        uint_t o = (uint_t)f2b(acc[0] * sc) | ((uint_t)f2b(acc[1] * sc) << 16);
        *reinterpret_cast<uint_t*>(aggr + (size_t)node * F + c0) = o;
    } else {
        uint2 o;
        o.x = (uint_t)f2b(acc[0] * sc) | ((uint_t)f2b(acc[1] * sc) << 16);
        o.y = (uint_t)f2b(acc[2] * sc) | ((uint_t)f2b(acc[3] * sc) << 16);
        *reinterpret_cast<uint2*>(aggr + (size_t)node * F + c0) = o;
    }
}

// ---------------- MFMA dual GEMM ----------------
// out[M][F] = A1@W1^T' + A2@W2^T' + b  where B args are WT [F][K] bf16.
// 128x128 block tile, BK=32, 4 waves (each 64x64), mfma_f32_16x16x32_bf16.
// LDS tiles [128 rows][32 bf16] with 16B-slot XOR swizzle: slot ^= (row>>1)&3.

template<int RELU, int OUTB>
__global__ __launch_bounds__(256) void k_gemm_mfma(
        const ushort_t* __restrict__ A1, const ushort_t* __restrict__ A2,
        const ushort_t* __restrict__ B1, const ushort_t* __restrict__ B2,
        const float* __restrict__ bias, void* __restrict__ out,
        int K, int F) {
    __shared__ __align__(16) short lds[8192];   // A: shorts [0,4096), B: [4096,8192)
    const int tid = threadIdx.x;
    const int lane = tid & 63;
    const int w = tid >> 6;
    const int row0 = blockIdx.x * 128;
    const int col0 = blockIdx.y * 128;
    const int wr = (w >> 1) * 64;
    const int wc = (w & 1) * 64;

    // staging: pass p, wave w, lane -> 16B chunk c; LDS is linear, source pre-swizzled
    int rowA[2], slA[2];
#pragma unroll
    for (int p = 0; p < 2; ++p) {
        int c = (p * 4 + w) * 64 + lane;
        int r = c >> 2, sp = c & 3;
        rowA[p] = r;
        slA[p] = sp ^ ((r >> 1) & 3);
    }
    // fragment read offsets (shorts), swizzled to match
    const int q = lane >> 4, lr = lane & 15;
    int aoff[4], boff[4];
#pragma unroll
    for (int f = 0; f < 4; ++f) {
        int ra = wr + f * 16 + lr;
        aoff[f] = ra * 32 + (q ^ ((ra >> 1) & 3)) * 8;
        int rb = wc + f * 16 + lr;
        boff[f] = 4096 + rb * 32 + (q ^ ((rb >> 1) & 3)) * 8;
    }

    f32x4 acc[4][4];
#pragma unroll
    for (int mf = 0; mf < 4; ++mf)
#pragma unroll
        for (int nf = 0; nf < 4; ++nf)
            acc[mf][nf] = (f32x4){0.f, 0.f, 0.f, 0.f};

    for (int m = 0; m < 2; ++m) {
        const ushort_t* __restrict__ A = m ? A2 : A1;
        const ushort_t* __restrict__ B = m ? B2 : B1;
        for (int k0 = 0; k0 < K; k0 += 32) {
            __syncthreads();   // previous tile's reads complete
#pragma unroll
            for (int p = 0; p < 2; ++p) {
                int gr = row0 + rowA[p];
                if (gr > N_NODES - 1) gr = N_NODES - 1;
                gload16(A + (size_t)gr * K + k0 + slA[p] * 8, &lds[(p * 4 + w) * 512]);
                int gc = col0 + rowA[p];
                gload16(B + (size_t)gc * K + k0 + slA[p] * 8, &lds[4096 + (p * 4 + w) * 512]);
            }
            asm volatile("s_waitcnt vmcnt(0)" ::: "memory");
            __syncthreads();
            bf16x8 av[4], bv[4];
#pragma unroll
            for (int f = 0; f < 4; ++f) {
                av[f] = *reinterpret_cast<const bf16x8*>(&lds[aoff[f]]);
                bv[f] = *reinterpret_cast<const bf16x8*>(&lds[boff[f]]);
            }
#pragma unroll
            for (int mf = 0; mf < 4; ++mf)
#pragma unroll
                for (int nf = 0; nf < 4; ++nf)
                    acc[mf][nf] = __builtin_amdgcn_mfma_f32_16x16x32_bf16(
                        av[mf], bv[nf], acc[mf][nf], 0, 0, 0);
        }
    }

    // epilogue: D lane map (m89): col = lane&15, row = (lane>>4)*4 + b
    const int orow = row0 + wr + q * 4;
    const int ocol = col0 + wc + lr;
#pragma unroll
    for (int nf = 0; nf < 4; ++nf) {
        int colg = ocol + nf * 16;
        float bvs = bias[colg];
#pragma unroll
        for (int mf = 0; mf < 4; ++mf) {
#pragma unroll
            for (int b = 0; b < 4; ++b) {
                int r = orow + mf * 16 + b;
                if (r < N_NODES) {
                    float v = acc[mf][nf][b] + bvs;
                    if (RELU) v = fmaxf(v, 0.f);
                    if (OUTB)
                        ((ushort_t*)out)[(size_t)r * F + colg] = f2b(v);
                    else
                        ((float*)out)[(size_t)r * F + colg] = v;
                }
            }
        }
    }
}

// ---------------- BatchNorm (bf16 h) ----------------

template<int F>
__global__ void k_bn_stats_b(const ushort_t* __restrict__ h, float* __restrict__ sums) {
    int col = threadIdx.x;  // blockDim == F
    float s = 0.f, s2 = 0.f;
    for (int r = blockIdx.x; r < N_NODES; r += gridDim.x) {
        float v = bf2f(h[(size_t)r * F + col]);
        s += v; s2 += v * v;
    }
    atomicAdd(&sums[col], s);
    atomicAdd(&sums[F + col], s2);
}

template<int F>
__global__ void k_bn_final(const float* __restrict__ sums, const float* __restrict__ gamma,
                           const float* __restrict__ beta, float* __restrict__ scsh) {
    int c = threadIdx.x;
    if (c < F) {
        float mean = sums[c] * (1.0f / N_NODES);
        float var = sums[F + c] * (1.0f / N_NODES) - mean * mean;
        float sc = gamma[c] * rsqrtf(var + BN_EPS_F);
        scsh[c] = sc;
        scsh[F + c] = beta[c] - mean * sc;
    }
}

template<int F>
__global__ void k_bn_apply_b(ushort_t* __restrict__ h, const float* __restrict__ scsh) {
    int i = blockIdx.x * blockDim.x + threadIdx.x;   // 8-col chunk index
    int total = N_NODES * F / 8;
    if (i >= total) return;
    int c = (i * 8) % F;
    uint4 v = *reinterpret_cast<const uint4*>(h + (size_t)i * 8);
    float4 s0 = ld4(&scsh[c]), s1 = ld4(&scsh[c + 4]);
    float4 b0 = ld4(&scsh[F + c]), b1 = ld4(&scsh[F + c + 4]);
    uint_t o0 = (uint_t)f2b(bf2f((ushort_t)v.x) * s0.x + b0.x)
              | ((uint_t)f2b(bf2f((ushort_t)(v.x >> 16)) * s0.y + b0.y) << 16);
    uint_t o1 = (uint_t)f2b(bf2f((ushort_t)v.y) * s0.z + b0.z)
              | ((uint_t)f2b(bf2f((ushort_t)(v.y >> 16)) * s0.w + b0.w) << 16);
    uint_t o2 = (uint_t)f2b(bf2f((ushort_t)v.z) * s1.x + b1.x)
              | ((uint_t)f2b(bf2f((ushort_t)(v.z >> 16)) * s1.y + b1.y) << 16);
    uint_t o3 = (uint_t)f2b(bf2f((ushort_t)v.w) * s1.z + b1.z)
              | ((uint_t)f2b(bf2f((ushort_t)(v.w >> 16)) * s1.w + b1.w) << 16);
    *reinterpret_cast<uint4*>(h + (size_t)i * 8) = make_uint4(o0, o1, o2, o3);
}

// ---------------- reparameterize ----------------

__global__ void k_reparam(const float* __restrict__ h3, const float* __restrict__ eps,
                          float* __restrict__ z) {
    int i = blockIdx.x * blockDim.x + threadIdx.x;   // float4 index over N*64
    int total = N_NODES * 64 / 4;
    if (i >= total) return;
    int r = i >> 4;
    int c4 = (i & 15) * 4;
    float4 m = ld4(&h3[(size_t)r * 128 + c4]);
    float4 ls = ld4(&h3[(size_t)r * 128 + 64 + c4]);
    float4 e = ld4(&eps[(size_t)r * 64 + c4]);
    float4 o;
    o.x = m.x + expf(ls.x) * e.x;
    o.y = m.y + expf(ls.y) * e.y;
    o.z = m.z + expf(ls.z) * e.z;
    o.w = m.w + expf(ls.w) * e.w;
    *reinterpret_cast<float4*>(&z[(size_t)r * 64 + c4]) = o;
}

// ---------------- launch ----------------

extern "C" void kernel_launch(void* const* d_in, const int* in_sizes, int n_in,
                              void* d_out, int out_size, void* d_ws, size_t ws_size,
                              hipStream_t stream) {
    (void)in_sizes; (void)n_in; (void)out_size; (void)ws_size;
    const float* x   = (const float*)d_in[0];
    const int*   src = (const int*)d_in[1];
    const int*   dst = (const int*)d_in[2];
    const float* eps = (const float*)d_in[3];
    const float* W1l = (const float*)d_in[4];
    const float* W1r = (const float*)d_in[5];
    const float* b1  = (const float*)d_in[6];
    const float* g1  = (const float*)d_in[7];
    const float* be1 = (const float*)d_in[8];
    const float* W2l = (const float*)d_in[9];
    const float* W2r = (const float*)d_in[10];
    const float* b2  = (const float*)d_in[11];
    const float* g2  = (const float*)d_in[12];
    const float* be2 = (const float*)d_in[13];
    const float* W3l = (const float*)d_in[14];
    const float* W3r = (const float*)d_in[15];
    const float* b3  = (const float*)d_in[16];
    float* z = (float*)d_out;

    char* ws = (char*)d_ws;
    size_t off = 0;
    auto alloc = [&](size_t bytes) -> char* {
        char* p = ws + off;
        off += (bytes + 255) & ~(size_t)255;
        return p;
    };
    int*      deg    = (int*)alloc(N_NODES * 4);
    int*      cursor = (int*)alloc(N_NODES * 4);
    float*    stats  = (float*)alloc(1536 * 4);
    size_t zero_bytes = off;
    int*      offs   = (int*)alloc(N_NODES * 4);
    int*      bsum   = (int*)alloc(128 * 4);
    int*      eids   = (int*)alloc((size_t)N_EDGES * 4);
    float*    invd   = (float*)alloc(N_NODES * 4);
    ushort_t* xb     = (ushort_t*)alloc((size_t)N_NODES * 128 * 2);
    ushort_t* h1b    = (ushort_t*)alloc((size_t)N_NODES * 128 * 2);
    ushort_t* h2b    = (ushort_t*)alloc((size_t)N_NODES * 256 * 2);
    ushort_t* aggrb  = (ushort_t*)alloc((size_t)N_NODES * 256 * 2);
    float*    h3f    = (float*)alloc((size_t)N_NODES * 128 * 4);
    ushort_t* wt1l   = (ushort_t*)alloc(128 * 128 * 2);
    ushort_t* wt1r   = (ushort_t*)alloc(128 * 128 * 2);
    ushort_t* wt2l   = (ushort_t*)alloc(256 * 128 * 2);
    ushort_t* wt2r   = (ushort_t*)alloc(256 * 128 * 2);
    ushort_t* wt3l   = (ushort_t*)alloc(128 * 256 * 2);
    ushort_t* wt3r   = (ushort_t*)alloc(128 * 256 * 2);

    float* sums1 = stats;            // 2*128
    float* scsh1 = stats + 256;      // 2*128
    float* sums2 = stats + 512;      // 2*256
    float* scsh2 = stats + 1024;     // 2*256

    // CSR build (recomputed per call — graph replay safe)
    int zn = (int)(zero_bytes / 4);
    k_zero_i32<<<(zn + 255) / 256, 256, 0, stream>>>((int*)ws, zn);
    k_count<<<(N_EDGES + 255) / 256, 256, 0, stream>>>(dst, deg);
    k_scan1<<<SCAN_NB, SCAN_BS, 0, stream>>>(deg, offs, bsum);
    k_scan2<<<1, 128, 0, stream>>>(bsum, SCAN_NB);
    k_scan3<<<(N_NODES + 255) / 256, 256, 0, stream>>>(deg, offs, bsum, invd);
    k_fill<<<(N_EDGES + 255) / 256, 256, 0, stream>>>(src, dst, offs, cursor, eids);

    // bf16 conversions
    k_f2b8<<<(N_NODES * 128 / 8 + 255) / 256, 256, 0, stream>>>(x, xb, N_NODES * 128 / 8);
    k_wtrans<<<(128 * 128 + 255) / 256, 256, 0, stream>>>(W1l, wt1l, 128, 128);
    k_wtrans<<<(128 * 128 + 255) / 256, 256, 0, stream>>>(W1r, wt1r, 128, 128);
    k_wtrans<<<(128 * 256 + 255) / 256, 256, 0, stream>>>(W2l, wt2l, 128, 256);
    k_wtrans<<<(128 * 256 + 255) / 256, 256, 0, stream>>>(W2r, wt2r, 128, 256);
    k_wtrans<<<(256 * 128 + 255) / 256, 256, 0, stream>>>(W3l, wt3l, 256, 128);
    k_wtrans<<<(256 * 128 + 255) / 256, 256, 0, stream>>>(W3r, wt3r, 256, 128);

    const int AGG_BLKS = (N_NODES + 3) / 4;
    const int GX = (N_NODES + 127) / 128;   // 391

    // ---- Layer 1: SAGE(x) -> relu -> BN  (K=128, F=128)
    k_aggregate_b<128><<<AGG_BLKS, 256, 0, stream>>>(xb, eids, offs, deg, invd, aggrb);
    k_gemm_mfma<1, 1><<<dim3(GX, 1), 256, 0, stream>>>(aggrb, xb, wt1l, wt1r, b1, h1b, 128, 128);
    k_bn_stats_b<128><<<240, 128, 0, stream>>>(h1b, sums1);
    k_bn_final<128><<<1, 128, 0, stream>>>(sums1, g1, be1, scsh1);
    k_bn_apply_b<128><<<(N_NODES * 128 / 8 + 255) / 256, 256, 0, stream>>>(h1b, scsh1);

    // ---- Layer 2: SAGE(h1) -> relu -> BN  (K=128, F=256)
    k_aggregate_b<128><<<AGG_BLKS, 256, 0, stream>>>(h1b, eids, offs, deg, invd, aggrb);
    k_gemm_mfma<1, 1><<<dim3(GX, 2), 256, 0, stream>>>(aggrb, h1b, wt2l, wt2r, b2, h2b, 128, 256);
    k_bn_stats_b<256><<<240, 256, 0, stream>>>(h2b, sums2);
    k_bn_final<256><<<1, 256, 0, stream>>>(sums2, g2, be2, scsh2);
    k_bn_apply_b<256><<<(N_NODES * 256 / 8 + 255) / 256, 256, 0, stream>>>(h2b, scsh2);

    // ---- Layer 3: SAGE(h2), no relu/BN  (K=256, F=128), fp32 out
    k_aggregate_b<256><<<AGG_BLKS, 256, 0, stream>>>(h2b, eids, offs, deg, invd, aggrb);
    k_gemm_mfma<0, 0><<<dim3(GX, 1), 256, 0, stream>>>(aggrb, h2b, wt3l, wt3r, b3, h3f, 256, 128);

    // ---- reparameterize
    k_reparam<<<(N_NODES * 64 / 4 + 255) / 256, 256, 0, stream>>>(h3f, eps, z);
}

// Round 3
// 430.631 us; speedup vs baseline: 1.9155x; 1.1387x over previous
//
#include <hip/hip_runtime.h>
#include <math.h>

#define N_NODES 50000
#define N_EDGES 800000
#define BN_EPS_F 1e-5f
#define SCAN_BS 512
#define SCAN_NB 98   // ceil(50000/512)

typedef unsigned short ushort_t;
typedef unsigned int uint_t;
typedef __attribute__((ext_vector_type(8))) short bf16x8;
typedef __attribute__((ext_vector_type(4))) float f32x4;

static __device__ __forceinline__ float4 ld4(const float* p) {
    return *reinterpret_cast<const float4*>(p);
}
static __device__ __forceinline__ float bf2f(ushort_t u) {
    return __uint_as_float(((uint_t)u) << 16);
}
static __device__ __forceinline__ ushort_t f2b(float f) {
    uint_t u = __float_as_uint(f);
    u += 0x7fffu + ((u >> 16) & 1u);
    return (ushort_t)(u >> 16);
}
static __device__ __forceinline__ void gload16(const void* g, void* l) {
    __builtin_amdgcn_global_load_lds(
        (const __attribute__((address_space(1))) void*)g,
        (__attribute__((address_space(3))) void*)l, 16, 0, 0);
}

// ---------------- CSR build ----------------

__global__ void k_zero_i32(int* __restrict__ p, int n) {
    int i = blockIdx.x * blockDim.x + threadIdx.x;
    if (i < n) p[i] = 0;
}

__global__ void k_count(const int* __restrict__ dst, int* __restrict__ deg) {
    int e = blockIdx.x * blockDim.x + threadIdx.x;
    if (e < N_EDGES) atomicAdd(&deg[dst[e]], 1);
}

__global__ void k_scan1(const int* __restrict__ deg, int* __restrict__ offs, int* __restrict__ bsum) {
    __shared__ int sh[SCAN_BS];
    int t = threadIdx.x;
    int g = blockIdx.x * SCAN_BS + t;
    int v = (g < N_NODES) ? deg[g] : 0;
    sh[t] = v;
    __syncthreads();
    for (int off = 1; off < SCAN_BS; off <<= 1) {
        int add = (t >= off) ? sh[t - off] : 0;
        __syncthreads();
        sh[t] += add;
        __syncthreads();
    }
    if (g < N_NODES) offs[g] = sh[t] - v;
    if (t == SCAN_BS - 1) bsum[blockIdx.x] = sh[t];
}

__global__ void k_scan2(int* __restrict__ bsum, int nb) {
    __shared__ int sh[128];
    int t = threadIdx.x;
    int v = (t < nb) ? bsum[t] : 0;
    sh[t] = v;
    __syncthreads();
    for (int off = 1; off < 128; off <<= 1) {
        int add = (t >= off) ? sh[t - off] : 0;
        __syncthreads();
        sh[t] += add;
        __syncthreads();
    }
    if (t < nb) bsum[t] = sh[t] - v;
}

__global__ void k_scan3(const int* __restrict__ deg, int* __restrict__ offs,
                        const int* __restrict__ bsum, float* __restrict__ inv_deg) {
    int g = blockIdx.x * blockDim.x + threadIdx.x;
    if (g < N_NODES) {
        offs[g] += bsum[g / SCAN_BS];
        int d = deg[g];
        inv_deg[g] = 1.0f / (float)(d > 1 ? d : 1);
    }
}

__global__ void k_fill(const int* __restrict__ src, const int* __restrict__ dst,
                       const int* __restrict__ offs, int* __restrict__ cursor,
                       int* __restrict__ eids) {
    int e = blockIdx.x * blockDim.x + threadIdx.x;
    if (e < N_EDGES) {
        int d = dst[e];
        int p = atomicAdd(&cursor[d], 1);
        eids[offs[d] + p] = src[e];
    }
}

// ---------------- conversions ----------------

__global__ void k_f2b8(const float* __restrict__ in, ushort_t* __restrict__ out, int n8) {
    int i = blockIdx.x * blockDim.x + threadIdx.x;
    if (i >= n8) return;
    float4 a = ld4(in + (size_t)i * 8);
    float4 b = ld4(in + (size_t)i * 8 + 4);
    uint_t o0 = (uint_t)f2b(a.x) | ((uint_t)f2b(a.y) << 16);
    uint_t o1 = (uint_t)f2b(a.z) | ((uint_t)f2b(a.w) << 16);
    uint_t o2 = (uint_t)f2b(b.x) | ((uint_t)f2b(b.y) << 16);
    uint_t o3 = (uint_t)f2b(b.z) | ((uint_t)f2b(b.w) << 16);
    *reinterpret_cast<uint4*>(out + (size_t)i * 8) = make_uint4(o0, o1, o2, o3);
}

// WT[f][k] = bf16(W[k][f]);  W is [K][F] row-major
__global__ void k_wtrans(const float* __restrict__ W, ushort_t* __restrict__ WT, int K, int F) {
    int idx = blockIdx.x * blockDim.x + threadIdx.x;
    if (idx < K * F) {
        int f = idx / K, k = idx - f * K;
        WT[idx] = f2b(W[(size_t)k * F + f]);
    }
}

// ---------------- mean aggregation, 16B gathers ----------------
// F=128 bf16 rows (256B): 16 lanes x 16B per row, 4 edges across lane-groups,
// unrolled x2 -> 8 edges (2KB) in flight per wave. One wave per node.

template<int OUTF>   // 1 = fp32 out, 0 = bf16 out
__global__ __launch_bounds__(256) void k_agg16(
        const ushort_t* __restrict__ h, const int* __restrict__ eids,
        const int* __restrict__ offs, const int* __restrict__ deg,
        const float* __restrict__ inv_deg, void* __restrict__ out) {
    constexpr int F = 128;
    constexpr int LPR = 16;     // lanes per row
    constexpr int EPW = 4;      // edges per wave-pass
    int node = (blockIdx.x * 256 + threadIdx.x) >> 6;
    int lane = threadIdx.x & 63;
    if (node >= N_NODES) return;
    const int g = lane >> 4;          // edge slot 0..3
    const int lr = lane & 15;         // 16B chunk in row
    float acc[8];
#pragma unroll
    for (int v = 0; v < 8; ++v) acc[v] = 0.f;
    const int beg = offs[node];
    const int d = deg[node];
    const size_t coff = (size_t)lr * 8;

    auto accum = [&](uint4 a) {
        acc[0] += bf2f((ushort_t)a.x); acc[1] += bf2f((ushort_t)(a.x >> 16));
        acc[2] += bf2f((ushort_t)a.y); acc[3] += bf2f((ushort_t)(a.y >> 16));
        acc[4] += bf2f((ushort_t)a.z); acc[5] += bf2f((ushort_t)(a.z >> 16));
        acc[6] += bf2f((ushort_t)a.w); acc[7] += bf2f((ushort_t)(a.w >> 16));
    };

    int j = 0;
    for (; j + 2 * EPW <= d; j += 2 * EPW) {
        int s0 = eids[beg + j + g];
        int s1 = eids[beg + j + EPW + g];
        uint4 a = *reinterpret_cast<const uint4*>(h + (size_t)s0 * F + coff);
        uint4 b = *reinterpret_cast<const uint4*>(h + (size_t)s1 * F + coff);
        accum(a);
        accum(b);
    }
    for (; j < d; j += EPW) {
        int e = j + g;
        if (e < d) {
            int s0 = eids[beg + e];
            uint4 a = *reinterpret_cast<const uint4*>(h + (size_t)s0 * F + coff);
            accum(a);
        }
    }
    // combine the 4 edge-groups
#pragma unroll
    for (int v = 0; v < 8; ++v) acc[v] += __shfl_xor(acc[v], 16);
#pragma unroll
    for (int v = 0; v < 8; ++v) acc[v] += __shfl_xor(acc[v], 32);

    if (g == 0) {
        float sc = inv_deg[node];
#pragma unroll
        for (int v = 0; v < 8; ++v) acc[v] *= sc;
        if (OUTF) {
            float* o = (float*)out + (size_t)node * F + coff;
            *reinterpret_cast<float4*>(o) = make_float4(acc[0], acc[1], acc[2], acc[3]);
            *reinterpret_cast<float4*>(o + 4) = make_float4(acc[4], acc[5], acc[6], acc[7]);
        } else {
            uint4 o;
            o.x = (uint_t)f2b(acc[0]) | ((uint_t)f2b(acc[1]) << 16);
            o.y = (uint_t)f2b(acc[2]) | ((uint_t)f2b(acc[3]) << 16);
            o.z = (uint_t)f2b(acc[4]) | ((uint_t)f2b(acc[5]) << 16);
            o.w = (uint_t)f2b(acc[6]) | ((uint_t)f2b(acc[7]) << 16);
            *reinterpret_cast<uint4*>((ushort_t*)out + (size_t)node * F + coff) = o;
        }
    }
}

// ---------------- MFMA GEMM ----------------
// out[M][F] = A1@B1' (+ A2@B2') (+ bias); B args are WT [F][K] bf16.
// 128x128 block tile, BK=32, 4 waves (each 64x64), mfma_f32_16x16x32_bf16.
// LDS tiles [128 rows][32 bf16] with 16B-slot XOR swizzle: slot ^= (row>>1)&3.

template<int RELU, int OUTB, int DUAL, int BIAS>
__global__ __launch_bounds__(256) void k_gemm_mfma(
        const ushort_t* __restrict__ A1, const ushort_t* __restrict__ A2,
        const ushort_t* __restrict__ B1, const ushort_t* __restrict__ B2,
        const float* __restrict__ bias, void* __restrict__ out,
        int K, int F) {
    __shared__ __align__(16) short lds[8192];   // A: shorts [0,4096), B: [4096,8192)
    const int tid = threadIdx.x;
    const int lane = tid & 63;
    const int w = tid >> 6;
    const int row0 = blockIdx.x * 128;
    const int col0 = blockIdx.y * 128;
    const int wr = (w >> 1) * 64;
    const int wc = (w & 1) * 64;

    int rowA[2], slA[2];
#pragma unroll
    for (int p = 0; p < 2; ++p) {
        int c = (p * 4 + w) * 64 + lane;
        int r = c >> 2, sp = c & 3;
        rowA[p] = r;
        slA[p] = sp ^ ((r >> 1) & 3);
    }
    const int q = lane >> 4, lr = lane & 15;
    int aoff[4], boff[4];
#pragma unroll
    for (int f = 0; f < 4; ++f) {
        int ra = wr + f * 16 + lr;
        aoff[f] = ra * 32 + (q ^ ((ra >> 1) & 3)) * 8;
        int rb = wc + f * 16 + lr;
        boff[f] = 4096 + rb * 32 + (q ^ ((rb >> 1) & 3)) * 8;
    }

    f32x4 acc[4][4];
#pragma unroll
    for (int mf = 0; mf < 4; ++mf)
#pragma unroll
        for (int nf = 0; nf < 4; ++nf)
            acc[mf][nf] = (f32x4){0.f, 0.f, 0.f, 0.f};

    for (int m = 0; m < (DUAL ? 2 : 1); ++m) {
        const ushort_t* __restrict__ A = m ? A2 : A1;
        const ushort_t* __restrict__ B = m ? B2 : B1;
        for (int k0 = 0; k0 < K; k0 += 32) {
            __syncthreads();
#pragma unroll
            for (int p = 0; p < 2; ++p) {
                int gr = row0 + rowA[p];
                if (gr > N_NODES - 1) gr = N_NODES - 1;
                gload16(A + (size_t)gr * K + k0 + slA[p] * 8, &lds[(p * 4 + w) * 512]);
                int gc = col0 + rowA[p];
                gload16(B + (size_t)gc * K + k0 + slA[p] * 8, &lds[4096 + (p * 4 + w) * 512]);
            }
            asm volatile("s_waitcnt vmcnt(0)" ::: "memory");
            __syncthreads();
            bf16x8 av[4], bv[4];
#pragma unroll
            for (int f = 0; f < 4; ++f) {
                av[f] = *reinterpret_cast<const bf16x8*>(&lds[aoff[f]]);
                bv[f] = *reinterpret_cast<const bf16x8*>(&lds[boff[f]]);
            }
#pragma unroll
            for (int mf = 0; mf < 4; ++mf)
#pragma unroll
                for (int nf = 0; nf < 4; ++nf)
                    acc[mf][nf] = __builtin_amdgcn_mfma_f32_16x16x32_bf16(
                        av[mf], bv[nf], acc[mf][nf], 0, 0, 0);
        }
    }

    // epilogue: D lane map (m89): col = lane&15, row = (lane>>4)*4 + b
    const int orow = row0 + wr + q * 4;
    const int ocol = col0 + wc + lr;
#pragma unroll
    for (int nf = 0; nf < 4; ++nf) {
        int colg = ocol + nf * 16;
        float bvs = BIAS ? bias[colg] : 0.f;
#pragma unroll
        for (int mf = 0; mf < 4; ++mf) {
#pragma unroll
            for (int b = 0; b < 4; ++b) {
                int r = orow + mf * 16 + b;
                if (r < N_NODES) {
                    float v = acc[mf][nf][b] + bvs;
                    if (RELU) v = fmaxf(v, 0.f);
                    if (OUTB)
                        ((ushort_t*)out)[(size_t)r * F + colg] = f2b(v);
                    else
                        ((float*)out)[(size_t)r * F + colg] = v;
                }
            }
        }
    }
}

// ---------------- BatchNorm (bf16 h) ----------------

template<int F>
__global__ void k_bn_stats_b(const ushort_t* __restrict__ h, float* __restrict__ sums) {
    int col = threadIdx.x;  // blockDim == F
    float s = 0.f, s2 = 0.f;
    for (int r = blockIdx.x; r < N_NODES; r += gridDim.x) {
        float v = bf2f(h[(size_t)r * F + col]);
        s += v; s2 += v * v;
    }
    atomicAdd(&sums[col], s);
    atomicAdd(&sums[F + col], s2);
}

template<int F>
__global__ void k_bn_final(const float* __restrict__ sums, const float* __restrict__ gamma,
                           const float* __restrict__ beta, float* __restrict__ scsh) {
    int c = threadIdx.x;
    if (c < F) {
        float mean = sums[c] * (1.0f / N_NODES);
        float var = sums[F + c] * (1.0f / N_NODES) - mean * mean;
        float sc = gamma[c] * rsqrtf(var + BN_EPS_F);
        scsh[c] = sc;
        scsh[F + c] = beta[c] - mean * sc;
    }
}

template<int F>
__global__ void k_bn_apply_b(ushort_t* __restrict__ h, const float* __restrict__ scsh) {
    int i = blockIdx.x * blockDim.x + threadIdx.x;   // 8-col chunk index
    int total = N_NODES * F / 8;
    if (i >= total) return;
    int c = (i * 8) % F;
    uint4 v = *reinterpret_cast<const uint4*>(h + (size_t)i * 8);
    float4 s0 = ld4(&scsh[c]), s1 = ld4(&scsh[c + 4]);
    float4 b0 = ld4(&scsh[F + c]), b1 = ld4(&scsh[F + c + 4]);
    uint_t o0 = (uint_t)f2b(bf2f((ushort_t)v.x) * s0.x + b0.x)
              | ((uint_t)f2b(bf2f((ushort_t)(v.x >> 16)) * s0.y + b0.y) << 16);
    uint_t o1 = (uint_t)f2b(bf2f((ushort_t)v.y) * s0.z + b0.z)
              | ((uint_t)f2b(bf2f((ushort_t)(v.y >> 16)) * s0.w + b0.w) << 16);
    uint_t o2 = (uint_t)f2b(bf2f((ushort_t)v.z) * s1.x + b1.x)
              | ((uint_t)f2b(bf2f((ushort_t)(v.z >> 16)) * s1.y + b1.y) << 16);
    uint_t o3 = (uint_t)f2b(bf2f((ushort_t)v.w) * s1.z + b1.z)
              | ((uint_t)f2b(bf2f((ushort_t)(v.w >> 16)) * s1.w + b1.w) << 16);
    *reinterpret_cast<uint4*>(h + (size_t)i * 8) = make_uint4(o0, o1, o2, o3);
}

// ---------------- reparameterize: z = (a+u)_mean + exp((a+u)_logstd)*eps ----------------

__global__ void k_reparam2(const float* __restrict__ agg, const float* __restrict__ u,
                           const float* __restrict__ eps, float* __restrict__ z) {
    int i = blockIdx.x * blockDim.x + threadIdx.x;   // float4 index over N*64
    int total = N_NODES * 64 / 4;
    if (i >= total) return;
    int r = i >> 4;
    int c4 = (i & 15) * 4;
    float4 m1 = ld4(&agg[(size_t)r * 128 + c4]);
    float4 m2 = ld4(&u[(size_t)r * 128 + c4]);
    float4 l1 = ld4(&agg[(size_t)r * 128 + 64 + c4]);
    float4 l2 = ld4(&u[(size_t)r * 128 + 64 + c4]);
    float4 e = ld4(&eps[(size_t)r * 64 + c4]);
    float4 o;
    o.x = (m1.x + m2.x) + expf(l1.x + l2.x) * e.x;
    o.y = (m1.y + m2.y) + expf(l1.y + l2.y) * e.y;
    o.z = (m1.z + m2.z) + expf(l1.z + l2.z) * e.z;
    o.w = (m1.w + m2.w) + expf(l1.w + l2.w) * e.w;
    *reinterpret_cast<float4*>(&z[(size_t)r * 64 + c4]) = o;
}

// ---------------- launch ----------------

extern "C" void kernel_launch(void* const* d_in, const int* in_sizes, int n_in,
                              void* d_out, int out_size, void* d_ws, size_t ws_size,
                              hipStream_t stream) {
    (void)in_sizes; (void)n_in; (void)out_size; (void)ws_size;
    const float* x   = (const float*)d_in[0];
    const int*   src = (const int*)d_in[1];
    const int*   dst = (const int*)d_in[2];
    const float* eps = (const float*)d_in[3];
    const float* W1l = (const float*)d_in[4];
    const float* W1r = (const float*)d_in[5];
    const float* b1  = (const float*)d_in[6];
    const float* g1  = (const float*)d_in[7];
    const float* be1 = (const float*)d_in[8];
    const float* W2l = (const float*)d_in[9];
    const float* W2r = (const float*)d_in[10];
    const float* b2  = (const float*)d_in[11];
    const float* g2  = (const float*)d_in[12];
    const float* be2 = (const float*)d_in[13];
    const float* W3l = (const float*)d_in[14];
    const float* W3r = (const float*)d_in[15];
    const float* b3  = (const float*)d_in[16];
    float* z = (float*)d_out;

    char* ws = (char*)d_ws;
    size_t off = 0;
    auto alloc = [&](size_t bytes) -> char* {
        char* p = ws + off;
        off += (bytes + 255) & ~(size_t)255;
        return p;
    };
    int*      deg    = (int*)alloc(N_NODES * 4);
    int*      cursor = (int*)alloc(N_NODES * 4);
    float*    stats  = (float*)alloc(1536 * 4);
    size_t zero_bytes = off;
    int*      offs   = (int*)alloc(N_NODES * 4);
    int*      bsum   = (int*)alloc(128 * 4);
    int*      eids   = (int*)alloc((size_t)N_EDGES * 4);
    float*    invd   = (float*)alloc(N_NODES * 4);
    ushort_t* xb     = (ushort_t*)alloc((size_t)N_NODES * 128 * 2);
    ushort_t* h1b    = (ushort_t*)alloc((size_t)N_NODES * 128 * 2);
    ushort_t* h2b    = (ushort_t*)alloc((size_t)N_NODES * 256 * 2);
    ushort_t* aggrb  = (ushort_t*)alloc((size_t)N_NODES * 256 * 2);   // layer-1/2 aggr; reused as t3 (bf16 [N,128])
    float*    u3f    = (float*)alloc((size_t)N_NODES * 128 * 4);
    float*    agg3f  = (float*)alloc((size_t)N_NODES * 128 * 4);
    ushort_t* wt1l   = (ushort_t*)alloc(128 * 128 * 2);
    ushort_t* wt1r   = (ushort_t*)alloc(128 * 128 * 2);
    ushort_t* wt2l   = (ushort_t*)alloc(256 * 128 * 2);
    ushort_t* wt2r   = (ushort_t*)alloc(256 * 128 * 2);
    ushort_t* wt3l   = (ushort_t*)alloc(128 * 256 * 2);
    ushort_t* wt3r   = (ushort_t*)alloc(128 * 256 * 2);
    ushort_t* t3b    = aggrb;   // layer-3: t3 = h2@W3l (bf16 [N,128]); aggrb is free by then

    float* sums1 = stats;            // 2*128
    float* scsh1 = stats + 256;      // 2*128
    float* sums2 = stats + 512;      // 2*256
    float* scsh2 = stats + 1024;     // 2*256

    // CSR build (recomputed per call — graph replay safe)
    int zn = (int)(zero_bytes / 4);
    k_zero_i32<<<(zn + 255) / 256, 256, 0, stream>>>((int*)ws, zn);
    k_count<<<(N_EDGES + 255) / 256, 256, 0, stream>>>(dst, deg);
    k_scan1<<<SCAN_NB, SCAN_BS, 0, stream>>>(deg, offs, bsum);
    k_scan2<<<1, 128, 0, stream>>>(bsum, SCAN_NB);
    k_scan3<<<(N_NODES + 255) / 256, 256, 0, stream>>>(deg, offs, bsum, invd);
    k_fill<<<(N_EDGES + 255) / 256, 256, 0, stream>>>(src, dst, offs, cursor, eids);

    // bf16 conversions
    k_f2b8<<<(N_NODES * 128 / 8 + 255) / 256, 256, 0, stream>>>(x, xb, N_NODES * 128 / 8);
    k_wtrans<<<(128 * 128 + 255) / 256, 256, 0, stream>>>(W1l, wt1l, 128, 128);
    k_wtrans<<<(128 * 128 + 255) / 256, 256, 0, stream>>>(W1r, wt1r, 128, 128);
    k_wtrans<<<(128 * 256 + 255) / 256, 256, 0, stream>>>(W2l, wt2l, 128, 256);
    k_wtrans<<<(128 * 256 + 255) / 256, 256, 0, stream>>>(W2r, wt2r, 128, 256);
    k_wtrans<<<(256 * 128 + 255) / 256, 256, 0, stream>>>(W3l, wt3l, 256, 128);
    k_wtrans<<<(256 * 128 + 255) / 256, 256, 0, stream>>>(W3r, wt3r, 256, 128);

    const int AGG_BLKS = (N_NODES + 3) / 4;   // one wave per node, 4 waves/block
    const int GX = (N_NODES + 127) / 128;     // 391

    // ---- Layer 1: SAGE(x) -> relu -> BN  (K=128, F=128)
    k_agg16<0><<<AGG_BLKS, 256, 0, stream>>>(xb, eids, offs, deg, invd, aggrb);
    k_gemm_mfma<1, 1, 1, 1><<<dim3(GX, 1), 256, 0, stream>>>(aggrb, xb, wt1l, wt1r, b1, h1b, 128, 128);
    k_bn_stats_b<128><<<240, 128, 0, stream>>>(h1b, sums1);
    k_bn_final<128><<<1, 128, 0, stream>>>(sums1, g1, be1, scsh1);
    k_bn_apply_b<128><<<(N_NODES * 128 / 8 + 255) / 256, 256, 0, stream>>>(h1b, scsh1);

    // ---- Layer 2: SAGE(h1) -> relu -> BN  (K=128, F=256)
    k_agg16<0><<<AGG_BLKS, 256, 0, stream>>>(h1b, eids, offs, deg, invd, aggrb);
    k_gemm_mfma<1, 1, 1, 1><<<dim3(GX, 2), 256, 0, stream>>>(aggrb, h1b, wt2l, wt2r, b2, h2b, 128, 256);
    k_bn_stats_b<256><<<240, 256, 0, stream>>>(h2b, sums2);
    k_bn_final<256><<<1, 256, 0, stream>>>(sums2, g2, be2, scsh2);
    k_bn_apply_b<256><<<(N_NODES * 256 / 8 + 255) / 256, 256, 0, stream>>>(h2b, scsh2);

    // ---- Layer 3 (commuted): t3 = h2@W3l (bf16); u3 = h2@W3r + b3 (fp32);
    //      agg3 = mean-agg(t3) (fp32); z = (agg3+u3)_m + exp((agg3+u3)_ls)*eps
    k_gemm_mfma<0, 1, 0, 0><<<dim3(GX, 1), 256, 0, stream>>>(h2b, nullptr, wt3l, nullptr, nullptr, t3b, 256, 128);
    k_gemm_mfma<0, 0, 0, 1><<<dim3(GX, 1), 256, 0, stream>>>(h2b, nullptr, wt3r, nullptr, b3, u3f, 256, 128);
    k_agg16<1><<<AGG_BLKS, 256, 0, stream>>>(t3b, eids, offs, deg, invd, agg3f);
    k_reparam2<<<(N_NODES * 64 / 4 + 255) / 256, 256, 0, stream>>>(agg3f, u3f, eps, z);
}

// Round 4
// 418.213 us; speedup vs baseline: 1.9724x; 1.0297x over previous
//
#include <hip/hip_runtime.h>
#include <math.h>

#define N_NODES 50000
#define N_EDGES 800000
#define BN_EPS_F 1e-5f
#define SCAN_BS 512
#define SCAN_NB 98   // ceil(50000/512)

typedef unsigned short ushort_t;
typedef unsigned int uint_t;
typedef __attribute__((ext_vector_type(8))) short bf16x8;
typedef __attribute__((ext_vector_type(4))) float f32x4;

static __device__ __forceinline__ float4 ld4(const float* p) {
    return *reinterpret_cast<const float4*>(p);
}
static __device__ __forceinline__ float bf2f(ushort_t u) {
    return __uint_as_float(((uint_t)u) << 16);
}
static __device__ __forceinline__ ushort_t f2b(float f) {
    uint_t u = __float_as_uint(f);
    u += 0x7fffu + ((u >> 16) & 1u);
    return (ushort_t)(u >> 16);
}
static __device__ __forceinline__ void gload16(const void* g, void* l) {
    __builtin_amdgcn_global_load_lds(
        (const __attribute__((address_space(1))) void*)g,
        (__attribute__((address_space(3))) void*)l, 16, 0, 0);
}

// ---------------- CSR build ----------------

__global__ void k_zero_i32(int* __restrict__ p, int n) {
    int i = blockIdx.x * blockDim.x + threadIdx.x;
    if (i < n) p[i] = 0;
}

__global__ void k_count(const int* __restrict__ dst, int* __restrict__ deg) {
    int e = blockIdx.x * blockDim.x + threadIdx.x;
    if (e < N_EDGES) atomicAdd(&deg[dst[e]], 1);
}

__global__ void k_scan1(const int* __restrict__ deg, int* __restrict__ offs, int* __restrict__ bsum) {
    __shared__ int sh[SCAN_BS];
    int t = threadIdx.x;
    int g = blockIdx.x * SCAN_BS + t;
    int v = (g < N_NODES) ? deg[g] : 0;
    sh[t] = v;
    __syncthreads();
    for (int off = 1; off < SCAN_BS; off <<= 1) {
        int add = (t >= off) ? sh[t - off] : 0;
        __syncthreads();
        sh[t] += add;
        __syncthreads();
    }
    if (g < N_NODES) offs[g] = sh[t] - v;
    if (t == SCAN_BS - 1) bsum[blockIdx.x] = sh[t];
}

__global__ void k_scan2(int* __restrict__ bsum, int nb) {
    __shared__ int sh[128];
    int t = threadIdx.x;
    int v = (t < nb) ? bsum[t] : 0;
    sh[t] = v;
    __syncthreads();
    for (int off = 1; off < 128; off <<= 1) {
        int add = (t >= off) ? sh[t - off] : 0;
        __syncthreads();
        sh[t] += add;
        __syncthreads();
    }
    if (t < nb) bsum[t] = sh[t] - v;
}

__global__ void k_scan3(const int* __restrict__ deg, int* __restrict__ offs,
                        const int* __restrict__ bsum, float* __restrict__ inv_deg) {
    int g = blockIdx.x * blockDim.x + threadIdx.x;
    if (g < N_NODES) {
        offs[g] += bsum[g / SCAN_BS];
        int d = deg[g];
        inv_deg[g] = 1.0f / (float)(d > 1 ? d : 1);
    }
}

__global__ void k_fill(const int* __restrict__ src, const int* __restrict__ dst,
                       const int* __restrict__ offs, int* __restrict__ cursor,
                       int* __restrict__ eids) {
    int e = blockIdx.x * blockDim.x + threadIdx.x;
    if (e < N_EDGES) {
        int d = dst[e];
        int p = atomicAdd(&cursor[d], 1);
        eids[offs[d] + p] = src[e];
    }
}

// ---------------- conversions ----------------

__global__ void k_f2b8(const float* __restrict__ in, ushort_t* __restrict__ out, int n8) {
    int i = blockIdx.x * blockDim.x + threadIdx.x;
    if (i >= n8) return;
    float4 a = ld4(in + (size_t)i * 8);
    float4 b = ld4(in + (size_t)i * 8 + 4);
    uint_t o0 = (uint_t)f2b(a.x) | ((uint_t)f2b(a.y) << 16);
    uint_t o1 = (uint_t)f2b(a.z) | ((uint_t)f2b(a.w) << 16);
    uint_t o2 = (uint_t)f2b(b.x) | ((uint_t)f2b(b.y) << 16);
    uint_t o3 = (uint_t)f2b(b.z) | ((uint_t)f2b(b.w) << 16);
    *reinterpret_cast<uint4*>(out + (size_t)i * 8) = make_uint4(o0, o1, o2, o3);
}

// WT[f][k] = bf16(W[k][f]);  W is [K][F] row-major
__global__ void k_wtrans(const float* __restrict__ W, ushort_t* __restrict__ WT, int K, int F) {
    int idx = blockIdx.x * blockDim.x + threadIdx.x;
    if (idx < K * F) {
        int f = idx / K, k = idx - f * K;
        WT[idx] = f2b(W[(size_t)k * F + f]);
    }
}

// ---------------- mean aggregation, 16B gathers, one wave per node ----------------
// F=128 bf16 rows (256B): 16 lanes x 16B per row, 4 edges across lane-groups,
// unrolled x4 -> 16 edges (4KB) in flight per wave.

#define ACCUM8(a) do { \
    acc[0] += bf2f((ushort_t)(a).x); acc[1] += bf2f((ushort_t)((a).x >> 16)); \
    acc[2] += bf2f((ushort_t)(a).y); acc[3] += bf2f((ushort_t)((a).y >> 16)); \
    acc[4] += bf2f((ushort_t)(a).z); acc[5] += bf2f((ushort_t)((a).z >> 16)); \
    acc[6] += bf2f((ushort_t)(a).w); acc[7] += bf2f((ushort_t)((a).w >> 16)); } while (0)

template<int OUTF>   // 1 = fp32 out, 0 = bf16 out
__global__ __launch_bounds__(256) void k_agg16(
        const ushort_t* __restrict__ h, const int* __restrict__ eids,
        const int* __restrict__ offs, const int* __restrict__ deg,
        const float* __restrict__ inv_deg, void* __restrict__ out) {
    constexpr int F = 128;
    constexpr int EPW = 4;      // edges per wave-pass
    int node = (blockIdx.x * 256 + threadIdx.x) >> 6;
    int lane = threadIdx.x & 63;
    if (node >= N_NODES) return;
    const int g = lane >> 4;
    const int lr = lane & 15;
    float acc[8];
#pragma unroll
    for (int v = 0; v < 8; ++v) acc[v] = 0.f;
    const int beg = offs[node];
    const int d = deg[node];
    const size_t coff = (size_t)lr * 8;

    int j = 0;
    for (; j + 4 * EPW <= d; j += 4 * EPW) {
        int s0 = eids[beg + j + g];
        int s1 = eids[beg + j + EPW + g];
        int s2 = eids[beg + j + 2 * EPW + g];
        int s3 = eids[beg + j + 3 * EPW + g];
        uint4 a = *reinterpret_cast<const uint4*>(h + (size_t)s0 * F + coff);
        uint4 b = *reinterpret_cast<const uint4*>(h + (size_t)s1 * F + coff);
        uint4 c = *reinterpret_cast<const uint4*>(h + (size_t)s2 * F + coff);
        uint4 e = *reinterpret_cast<const uint4*>(h + (size_t)s3 * F + coff);
        ACCUM8(a); ACCUM8(b); ACCUM8(c); ACCUM8(e);
    }
    for (; j + 2 * EPW <= d; j += 2 * EPW) {
        int s0 = eids[beg + j + g];
        int s1 = eids[beg + j + EPW + g];
        uint4 a = *reinterpret_cast<const uint4*>(h + (size_t)s0 * F + coff);
        uint4 b = *reinterpret_cast<const uint4*>(h + (size_t)s1 * F + coff);
        ACCUM8(a); ACCUM8(b);
    }
    for (; j < d; j += EPW) {
        int e = j + g;
        if (e < d) {
            int s0 = eids[beg + e];
            uint4 a = *reinterpret_cast<const uint4*>(h + (size_t)s0 * F + coff);
            ACCUM8(a);
        }
    }
#pragma unroll
    for (int v = 0; v < 8; ++v) acc[v] += __shfl_xor(acc[v], 16);
#pragma unroll
    for (int v = 0; v < 8; ++v) acc[v] += __shfl_xor(acc[v], 32);

    if (g == 0) {
        float sc = inv_deg[node];
#pragma unroll
        for (int v = 0; v < 8; ++v) acc[v] *= sc;
        if (OUTF) {
            float* o = (float*)out + (size_t)node * F + coff;
            *reinterpret_cast<float4*>(o) = make_float4(acc[0], acc[1], acc[2], acc[3]);
            *reinterpret_cast<float4*>(o + 4) = make_float4(acc[4], acc[5], acc[6], acc[7]);
        } else {
            uint4 o;
            o.x = (uint_t)f2b(acc[0]) | ((uint_t)f2b(acc[1]) << 16);
            o.y = (uint_t)f2b(acc[2]) | ((uint_t)f2b(acc[3]) << 16);
            o.z = (uint_t)f2b(acc[4]) | ((uint_t)f2b(acc[5]) << 16);
            o.w = (uint_t)f2b(acc[6]) | ((uint_t)f2b(acc[7]) << 16);
            *reinterpret_cast<uint4*>((ushort_t*)out + (size_t)node * F + coff) = o;
        }
    }
}

// ---------------- fused layer-3 aggregate + reparameterize ----------------
// agg = mean-agg(t3)[node]; z = (agg_m + u_m) + exp(agg_ls + u_ls) * eps
__global__ __launch_bounds__(256) void k_agg_reparam(
        const ushort_t* __restrict__ t3, const int* __restrict__ eids,
        const int* __restrict__ offs, const int* __restrict__ deg,
        const float* __restrict__ inv_deg, const float* __restrict__ u,
        const float* __restrict__ eps, float* __restrict__ z) {
    constexpr int F = 128;
    constexpr int EPW = 4;
    int node = (blockIdx.x * 256 + threadIdx.x) >> 6;
    int lane = threadIdx.x & 63;
    if (node >= N_NODES) return;
    const int g = lane >> 4;
    const int lr = lane & 15;
    float acc[8];
#pragma unroll
    for (int v = 0; v < 8; ++v) acc[v] = 0.f;
    const int beg = offs[node];
    const int d = deg[node];
    const size_t coff = (size_t)lr * 8;

    int j = 0;
    for (; j + 4 * EPW <= d; j += 4 * EPW) {
        int s0 = eids[beg + j + g];
        int s1 = eids[beg + j + EPW + g];
        int s2 = eids[beg + j + 2 * EPW + g];
        int s3 = eids[beg + j + 3 * EPW + g];
        uint4 a = *reinterpret_cast<const uint4*>(t3 + (size_t)s0 * F + coff);
        uint4 b = *reinterpret_cast<const uint4*>(t3 + (size_t)s1 * F + coff);
        uint4 c = *reinterpret_cast<const uint4*>(t3 + (size_t)s2 * F + coff);
        uint4 e = *reinterpret_cast<const uint4*>(t3 + (size_t)s3 * F + coff);
        ACCUM8(a); ACCUM8(b); ACCUM8(c); ACCUM8(e);
    }
    for (; j + 2 * EPW <= d; j += 2 * EPW) {
        int s0 = eids[beg + j + g];
        int s1 = eids[beg + j + EPW + g];
        uint4 a = *reinterpret_cast<const uint4*>(t3 + (size_t)s0 * F + coff);
        uint4 b = *reinterpret_cast<const uint4*>(t3 + (size_t)s1 * F + coff);
        ACCUM8(a); ACCUM8(b);
    }
    for (; j < d; j += EPW) {
        int e = j + g;
        if (e < d) {
            int s0 = eids[beg + e];
            uint4 a = *reinterpret_cast<const uint4*>(t3 + (size_t)s0 * F + coff);
            ACCUM8(a);
        }
    }
#pragma unroll
    for (int v = 0; v < 8; ++v) acc[v] += __shfl_xor(acc[v], 16);
#pragma unroll
    for (int v = 0; v < 8; ++v) acc[v] += __shfl_xor(acc[v], 32);
    // all lanes hold full column sums for cols lr*8..lr*8+7.
    // mean half = lr 0..7; logstd half = lr 8..15: pull partner's values.
    float ls[8];
#pragma unroll
    for (int v = 0; v < 8; ++v) ls[v] = __shfl_down(acc[v], 8);

    if (g == 0 && lr < 8) {
        float sc = inv_deg[node];
        const float* um = u + (size_t)node * 128 + lr * 8;
        const float* ul = u + (size_t)node * 128 + 64 + lr * 8;
        const float* ep = eps + (size_t)node * 64 + lr * 8;
        float4 um0 = ld4(um), um1 = ld4(um + 4);
        float4 ul0 = ld4(ul), ul1 = ld4(ul + 4);
        float4 e0 = ld4(ep), e1 = ld4(ep + 4);
        float4 o0, o1;
        o0.x = (acc[0] * sc + um0.x) + expf(ls[0] * sc + ul0.x) * e0.x;
        o0.y = (acc[1] * sc + um0.y) + expf(ls[1] * sc + ul0.y) * e0.y;
        o0.z = (acc[2] * sc + um0.z) + expf(ls[2] * sc + ul0.z) * e0.z;
        o0.w = (acc[3] * sc + um0.w) + expf(ls[3] * sc + ul0.w) * e0.w;
        o1.x = (acc[4] * sc + um1.x) + expf(ls[4] * sc + ul1.x) * e1.x;
        o1.y = (acc[5] * sc + um1.y) + expf(ls[5] * sc + ul1.y) * e1.y;
        o1.z = (acc[6] * sc + um1.z) + expf(ls[6] * sc + ul1.z) * e1.z;
        o1.w = (acc[7] * sc + um1.w) + expf(ls[7] * sc + ul1.w) * e1.w;
        float* zp = z + (size_t)node * 64 + lr * 8;
        *reinterpret_cast<float4*>(zp) = o0;
        *reinterpret_cast<float4*>(zp + 4) = o1;
    }
}

// ---------------- MFMA GEMM ----------------
// out[M][F] = A1@B1' (+ A2@B2') (+ bias); B args are WT [F][K] bf16.
// 128x128 block tile, BK=32, 4 waves (each 64x64), mfma_f32_16x16x32_bf16.

template<int RELU, int OUTB, int DUAL, int BIAS>
__global__ __launch_bounds__(256) void k_gemm_mfma(
        const ushort_t* __restrict__ A1, const ushort_t* __restrict__ A2,
        const ushort_t* __restrict__ B1, const ushort_t* __restrict__ B2,
        const float* __restrict__ bias, void* __restrict__ out,
        int K, int F) {
    __shared__ __align__(16) short lds[8192];   // A: [0,4096), B: [4096,8192)
    const int tid = threadIdx.x;
    const int lane = tid & 63;
    const int w = tid >> 6;
    const int row0 = blockIdx.x * 128;
    const int col0 = blockIdx.y * 128;
    const int wr = (w >> 1) * 64;
    const int wc = (w & 1) * 64;

    int rowA[2], slA[2];
#pragma unroll
    for (int p = 0; p < 2; ++p) {
        int c = (p * 4 + w) * 64 + lane;
        int r = c >> 2, sp = c & 3;
        rowA[p] = r;
        slA[p] = sp ^ ((r >> 1) & 3);
    }
    const int q = lane >> 4, lr = lane & 15;
    int aoff[4], boff[4];
#pragma unroll
    for (int f = 0; f < 4; ++f) {
        int ra = wr + f * 16 + lr;
        aoff[f] = ra * 32 + (q ^ ((ra >> 1) & 3)) * 8;
        int rb = wc + f * 16 + lr;
        boff[f] = 4096 + rb * 32 + (q ^ ((rb >> 1) & 3)) * 8;
    }

    f32x4 acc[4][4];
#pragma unroll
    for (int mf = 0; mf < 4; ++mf)
#pragma unroll
        for (int nf = 0; nf < 4; ++nf)
            acc[mf][nf] = (f32x4){0.f, 0.f, 0.f, 0.f};

    for (int m = 0; m < (DUAL ? 2 : 1); ++m) {
        const ushort_t* __restrict__ A = m ? A2 : A1;
        const ushort_t* __restrict__ B = m ? B2 : B1;
        for (int k0 = 0; k0 < K; k0 += 32) {
            __syncthreads();
#pragma unroll
            for (int p = 0; p < 2; ++p) {
                int gr = row0 + rowA[p];
                if (gr > N_NODES - 1) gr = N_NODES - 1;
                gload16(A + (size_t)gr * K + k0 + slA[p] * 8, &lds[(p * 4 + w) * 512]);
                int gc = col0 + rowA[p];
                gload16(B + (size_t)gc * K + k0 + slA[p] * 8, &lds[4096 + (p * 4 + w) * 512]);
            }
            asm volatile("s_waitcnt vmcnt(0)" ::: "memory");
            __syncthreads();
            bf16x8 av[4], bv[4];
#pragma unroll
            for (int f = 0; f < 4; ++f) {
                av[f] = *reinterpret_cast<const bf16x8*>(&lds[aoff[f]]);
                bv[f] = *reinterpret_cast<const bf16x8*>(&lds[boff[f]]);
            }
#pragma unroll
            for (int mf = 0; mf < 4; ++mf)
#pragma unroll
                for (int nf = 0; nf < 4; ++nf)
                    acc[mf][nf] = __builtin_amdgcn_mfma_f32_16x16x32_bf16(
                        av[mf], bv[nf], acc[mf][nf], 0, 0, 0);
        }
    }

    // epilogue: D lane map (m89): col = lane&15, row = (lane>>4)*4 + b
    const int orow = row0 + wr + q * 4;
    const int ocol = col0 + wc + lr;
#pragma unroll
    for (int nf = 0; nf < 4; ++nf) {
        int colg = ocol + nf * 16;
        float bvs = BIAS ? bias[colg] : 0.f;
#pragma unroll
        for (int mf = 0; mf < 4; ++mf) {
#pragma unroll
            for (int b = 0; b < 4; ++b) {
                int r = orow + mf * 16 + b;
                if (r < N_NODES) {
                    float v = acc[mf][nf][b] + bvs;
                    if (RELU) v = fmaxf(v, 0.f);
                    if (OUTB)
                        ((ushort_t*)out)[(size_t)r * F + colg] = f2b(v);
                    else
                        ((float*)out)[(size_t)r * F + colg] = v;
                }
            }
        }
    }
}

// ---------------- BatchNorm ----------------
// stats: vectorized 16B loads, register accumulate, LDS cross-row reduce.

template<int F>
__global__ __launch_bounds__(256) void k_bn_stats_v(const ushort_t* __restrict__ h,
                                                    float* __restrict__ sums) {
    constexpr int CPR = F / 8;        // threads per row: 16 (F=128) / 32 (F=256)
    constexpr int RPB = 256 / CPR;    // rows in flight per block: 16 / 8
    const int t = threadIdx.x;
    const int cg = t % CPR;           // 8-col group
    const int rr = t / CPR;
    float s[8], s2[8];
#pragma unroll
    for (int j = 0; j < 8; ++j) { s[j] = 0.f; s2[j] = 0.f; }
    const size_t coff = (size_t)cg * 8;
    const int stride = gridDim.x * RPB;
    int r = blockIdx.x * RPB + rr;
    for (; r + stride < N_NODES; r += 2 * stride) {
        uint4 a = *reinterpret_cast<const uint4*>(h + (size_t)r * F + coff);
        uint4 b = *reinterpret_cast<const uint4*>(h + (size_t)(r + stride) * F + coff);
        const uint_t wa[4] = {a.x, a.y, a.z, a.w};
        const uint_t wb[4] = {b.x, b.y, b.z, b.w};
#pragma unroll
        for (int j = 0; j < 4; ++j) {
            float v0 = bf2f((ushort_t)wa[j]), v1 = bf2f((ushort_t)(wa[j] >> 16));
            float u0 = bf2f((ushort_t)wb[j]), u1 = bf2f((ushort_t)(wb[j] >> 16));
            s[2 * j] += v0 + u0; s[2 * j + 1] += v1 + u1;
            s2[2 * j] += v0 * v0 + u0 * u0; s2[2 * j + 1] += v1 * v1 + u1 * u1;
        }
    }
    for (; r < N_NODES; r += stride) {
        uint4 a = *reinterpret_cast<const uint4*>(h + (size_t)r * F + coff);
        const uint_t wa[4] = {a.x, a.y, a.z, a.w};
#pragma unroll
        for (int j = 0; j < 4; ++j) {
            float v0 = bf2f((ushort_t)wa[j]), v1 = bf2f((ushort_t)(wa[j] >> 16));
            s[2 * j] += v0; s[2 * j + 1] += v1;
            s2[2 * j] += v0 * v0; s2[2 * j + 1] += v1 * v1;
        }
    }
    __shared__ float sd[256 * 16];
#pragma unroll
    for (int j = 0; j < 8; ++j) { sd[t * 16 + j] = s[j]; sd[t * 16 + 8 + j] = s2[j]; }
    __syncthreads();
    if (t < CPR) {
        float as[8], as2[8];
#pragma unroll
        for (int j = 0; j < 8; ++j) { as[j] = 0.f; as2[j] = 0.f; }
        for (int k = 0; k < RPB; ++k) {
            int bt = k * CPR + t;
#pragma unroll
            for (int j = 0; j < 8; ++j) {
                as[j] += sd[bt * 16 + j];
                as2[j] += sd[bt * 16 + 8 + j];
            }
        }
#pragma unroll
        for (int j = 0; j < 8; ++j) {
            atomicAdd(&sums[t * 8 + j], as[j]);
            atomicAdd(&sums[F + t * 8 + j], as2[j]);
        }
    }
}

template<int F>
__global__ void k_bn_final(const float* __restrict__ sums, const float* __restrict__ gamma,
                           const float* __restrict__ beta, float* __restrict__ scsh) {
    int c = threadIdx.x;
    if (c < F) {
        float mean = sums[c] * (1.0f / N_NODES);
        float var = sums[F + c] * (1.0f / N_NODES) - mean * mean;
        float sc = gamma[c] * rsqrtf(var + BN_EPS_F);
        scsh[c] = sc;
        scsh[F + c] = beta[c] - mean * sc;
    }
}

template<int F>
__global__ void k_bn_apply_b(ushort_t* __restrict__ h, const float* __restrict__ scsh) {
    int i = blockIdx.x * blockDim.x + threadIdx.x;   // 8-col chunk index
    int total = N_NODES * F / 8;
    if (i >= total) return;
    int c = (i * 8) % F;
    uint4 v = *reinterpret_cast<const uint4*>(h + (size_t)i * 8);
    float4 s0 = ld4(&scsh[c]), s1 = ld4(&scsh[c + 4]);
    float4 b0 = ld4(&scsh[F + c]), b1 = ld4(&scsh[F + c + 4]);
    uint_t o0 = (uint_t)f2b(bf2f((ushort_t)v.x) * s0.x + b0.x)
              | ((uint_t)f2b(bf2f((ushort_t)(v.x >> 16)) * s0.y + b0.y) << 16);
    uint_t o1 = (uint_t)f2b(bf2f((ushort_t)v.y) * s0.z + b0.z)
              | ((uint_t)f2b(bf2f((ushort_t)(v.y >> 16)) * s0.w + b0.w) << 16);
    uint_t o2 = (uint_t)f2b(bf2f((ushort_t)v.z) * s1.x + b1.x)
              | ((uint_t)f2b(bf2f((ushort_t)(v.z >> 16)) * s1.y + b1.y) << 16);
    uint_t o3 = (uint_t)f2b(bf2f((ushort_t)v.w) * s1.z + b1.z)
              | ((uint_t)f2b(bf2f((ushort_t)(v.w >> 16)) * s1.w + b1.w) << 16);
    *reinterpret_cast<uint4*>(h + (size_t)i * 8) = make_uint4(o0, o1, o2, o3);
}

// ---------------- launch ----------------

extern "C" void kernel_launch(void* const* d_in, const int* in_sizes, int n_in,
                              void* d_out, int out_size, void* d_ws, size_t ws_size,
                              hipStream_t stream) {
    (void)in_sizes; (void)n_in; (void)out_size; (void)ws_size;
    const float* x   = (const float*)d_in[0];
    const int*   src = (const int*)d_in[1];
    const int*   dst = (const int*)d_in[2];
    const float* eps = (const float*)d_in[3];
    const float* W1l = (const float*)d_in[4];
    const float* W1r = (const float*)d_in[5];
    const float* b1  = (const float*)d_in[6];
    const float* g1  = (const float*)d_in[7];
    const float* be1 = (const float*)d_in[8];
    const float* W2l = (const float*)d_in[9];
    const float* W2r = (const float*)d_in[10];
    const float* b2  = (const float*)d_in[11];
    const float* g2  = (const float*)d_in[12];
    const float* be2 = (const float*)d_in[13];
    const float* W3l = (const float*)d_in[14];
    const float* W3r = (const float*)d_in[15];
    const float* b3  = (const float*)d_in[16];
    float* z = (float*)d_out;

    char* ws = (char*)d_ws;
    size_t off = 0;
    auto alloc = [&](size_t bytes) -> char* {
        char* p = ws + off;
        off += (bytes + 255) & ~(size_t)255;
        return p;
    };
    int*      deg    = (int*)alloc(N_NODES * 4);
    int*      cursor = (int*)alloc(N_NODES * 4);
    float*    stats  = (float*)alloc(1536 * 4);
    size_t zero_bytes = off;
    int*      offs   = (int*)alloc(N_NODES * 4);
    int*      bsum   = (int*)alloc(128 * 4);
    int*      eids   = (int*)alloc((size_t)N_EDGES * 4);
    float*    invd   = (float*)alloc(N_NODES * 4);
    ushort_t* xb     = (ushort_t*)alloc((size_t)N_NODES * 128 * 2);
    ushort_t* h1b    = (ushort_t*)alloc((size_t)N_NODES * 128 * 2);
    ushort_t* h2b    = (ushort_t*)alloc((size_t)N_NODES * 256 * 2);
    ushort_t* aggrb  = (ushort_t*)alloc((size_t)N_NODES * 256 * 2);   // layer-1/2 aggr; reused as t3
    float*    u3f    = (float*)alloc((size_t)N_NODES * 128 * 4);
    ushort_t* wt1l   = (ushort_t*)alloc(128 * 128 * 2);
    ushort_t* wt1r   = (ushort_t*)alloc(128 * 128 * 2);
    ushort_t* wt2l   = (ushort_t*)alloc(256 * 128 * 2);
    ushort_t* wt2r   = (ushort_t*)alloc(256 * 128 * 2);
    ushort_t* wt3l   = (ushort_t*)alloc(128 * 256 * 2);
    ushort_t* wt3r   = (ushort_t*)alloc(128 * 256 * 2);
    ushort_t* t3b    = aggrb;   // layer-3: t3 = h2@W3l (bf16 [N,128])

    float* sums1 = stats;            // 2*128
    float* scsh1 = stats + 256;      // 2*128
    float* sums2 = stats + 512;      // 2*256
    float* scsh2 = stats + 1024;     // 2*256

    // CSR build (recomputed per call — graph replay safe)
    int zn = (int)(zero_bytes / 4);
    k_zero_i32<<<(zn + 255) / 256, 256, 0, stream>>>((int*)ws, zn);
    k_count<<<(N_EDGES + 255) / 256, 256, 0, stream>>>(dst, deg);
    k_scan1<<<SCAN_NB, SCAN_BS, 0, stream>>>(deg, offs, bsum);
    k_scan2<<<1, 128, 0, stream>>>(bsum, SCAN_NB);
    k_scan3<<<(N_NODES + 255) / 256, 256, 0, stream>>>(deg, offs, bsum, invd);
    k_fill<<<(N_EDGES + 255) / 256, 256, 0, stream>>>(src, dst, offs, cursor, eids);

    // bf16 conversions
    k_f2b8<<<(N_NODES * 128 / 8 + 255) / 256, 256, 0, stream>>>(x, xb, N_NODES * 128 / 8);
    k_wtrans<<<(128 * 128 + 255) / 256, 256, 0, stream>>>(W1l, wt1l, 128, 128);
    k_wtrans<<<(128 * 128 + 255) / 256, 256, 0, stream>>>(W1r, wt1r, 128, 128);
    k_wtrans<<<(128 * 256 + 255) / 256, 256, 0, stream>>>(W2l, wt2l, 128, 256);
    k_wtrans<<<(128 * 256 + 255) / 256, 256, 0, stream>>>(W2r, wt2r, 128, 256);
    k_wtrans<<<(256 * 128 + 255) / 256, 256, 0, stream>>>(W3l, wt3l, 256, 128);
    k_wtrans<<<(256 * 128 + 255) / 256, 256, 0, stream>>>(W3r, wt3r, 256, 128);

    const int AGG_BLKS = (N_NODES + 3) / 4;   // one wave per node, 4 waves/block
    const int GX = (N_NODES + 127) / 128;     // 391

    // ---- Layer 1: SAGE(x) -> relu -> BN  (K=128, F=128)
    k_agg16<0><<<AGG_BLKS, 256, 0, stream>>>(xb, eids, offs, deg, invd, aggrb);
    k_gemm_mfma<1, 1, 1, 1><<<dim3(GX, 1), 256, 0, stream>>>(aggrb, xb, wt1l, wt1r, b1, h1b, 128, 128);
    k_bn_stats_v<128><<<256, 256, 0, stream>>>(h1b, sums1);
    k_bn_final<128><<<1, 128, 0, stream>>>(sums1, g1, be1, scsh1);
    k_bn_apply_b<128><<<(N_NODES * 128 / 8 + 255) / 256, 256, 0, stream>>>(h1b, scsh1);

    // ---- Layer 2: SAGE(h1) -> relu -> BN  (K=128, F=256)
    k_agg16<0><<<AGG_BLKS, 256, 0, stream>>>(h1b, eids, offs, deg, invd, aggrb);
    k_gemm_mfma<1, 1, 1, 1><<<dim3(GX, 2), 256, 0, stream>>>(aggrb, h1b, wt2l, wt2r, b2, h2b, 128, 256);
    k_bn_stats_v<256><<<256, 256, 0, stream>>>(h2b, sums2);
    k_bn_final<256><<<1, 256, 0, stream>>>(sums2, g2, be2, scsh2);
    k_bn_apply_b<256><<<(N_NODES * 256 / 8 + 255) / 256, 256, 0, stream>>>(h2b, scsh2);

    // ---- Layer 3 (commuted): t3 = h2@W3l (bf16); u3 = h2@W3r + b3 (fp32);
    //      fused: z = (agg(t3)+u3)_m + exp((agg(t3)+u3)_ls)*eps
    k_gemm_mfma<0, 1, 0, 0><<<dim3(GX, 1), 256, 0, stream>>>(h2b, nullptr, wt3l, nullptr, nullptr, t3b, 256, 128);
    k_gemm_mfma<0, 0, 0, 1><<<dim3(GX, 1), 256, 0, stream>>>(h2b, nullptr, wt3r, nullptr, b3, u3f, 256, 128);
    k_agg_reparam<<<AGG_BLKS, 256, 0, stream>>>(t3b, eids, offs, deg, invd, u3f, eps, z);
}

// Round 5
// 318.541 us; speedup vs baseline: 2.5895x; 1.3129x over previous
//
#include <hip/hip_runtime.h>
#include <math.h>

#define N_NODES 50000
#define N_EDGES 800000
#define BN_EPS_F 1e-5f
#define SCAN_BS 512
#define SCAN_NB 98   // ceil(50000/512)
#define GXP 392      // padded partials stride (>= GX=391)

typedef unsigned short ushort_t;
typedef unsigned int uint_t;
typedef __attribute__((ext_vector_type(8))) short bf16x8;
typedef __attribute__((ext_vector_type(4))) float f32x4;

static __device__ __forceinline__ float4 ld4(const float* p) {
    return *reinterpret_cast<const float4*>(p);
}
static __device__ __forceinline__ float bf2f(ushort_t u) {
    return __uint_as_float(((uint_t)u) << 16);
}
static __device__ __forceinline__ ushort_t f2b(float f) {
    uint_t u = __float_as_uint(f);
    u += 0x7fffu + ((u >> 16) & 1u);
    return (ushort_t)(u >> 16);
}
static __device__ __forceinline__ void gload16(const void* g, void* l) {
    __builtin_amdgcn_global_load_lds(
        (const __attribute__((address_space(1))) void*)g,
        (__attribute__((address_space(3))) void*)l, 16, 0, 0);
}

// ---------------- CSR build ----------------

__global__ void k_zero_i32(int* __restrict__ p, int n) {
    int i = blockIdx.x * blockDim.x + threadIdx.x;
    if (i < n) p[i] = 0;
}

__global__ void k_count(const int* __restrict__ dst, int* __restrict__ deg) {
    int e = blockIdx.x * blockDim.x + threadIdx.x;
    if (e < N_EDGES) atomicAdd(&deg[dst[e]], 1);
}

__global__ void k_scan1(const int* __restrict__ deg, int* __restrict__ offs, int* __restrict__ bsum) {
    __shared__ int sh[SCAN_BS];
    int t = threadIdx.x;
    int g = blockIdx.x * SCAN_BS + t;
    int v = (g < N_NODES) ? deg[g] : 0;
    sh[t] = v;
    __syncthreads();
    for (int off = 1; off < SCAN_BS; off <<= 1) {
        int add = (t >= off) ? sh[t - off] : 0;
        __syncthreads();
        sh[t] += add;
        __syncthreads();
    }
    if (g < N_NODES) offs[g] = sh[t] - v;
    if (t == SCAN_BS - 1) bsum[blockIdx.x] = sh[t];
}

__global__ void k_scan2(int* __restrict__ bsum, int nb) {
    __shared__ int sh[128];
    int t = threadIdx.x;
    int v = (t < nb) ? bsum[t] : 0;
    sh[t] = v;
    __syncthreads();
    for (int off = 1; off < 128; off <<= 1) {
        int add = (t >= off) ? sh[t - off] : 0;
        __syncthreads();
        sh[t] += add;
        __syncthreads();
    }
    if (t < nb) bsum[t] = sh[t] - v;
}

__global__ void k_scan3(const int* __restrict__ deg, int* __restrict__ offs,
                        const int* __restrict__ bsum, float* __restrict__ inv_deg) {
    int g = blockIdx.x * blockDim.x + threadIdx.x;
    if (g < N_NODES) {
        offs[g] += bsum[g / SCAN_BS];
        int d = deg[g];
        inv_deg[g] = 1.0f / (float)(d > 1 ? d : 1);
    }
}

__global__ void k_fill(const int* __restrict__ src, const int* __restrict__ dst,
                       const int* __restrict__ offs, int* __restrict__ cursor,
                       int* __restrict__ eids) {
    int e = blockIdx.x * blockDim.x + threadIdx.x;
    if (e < N_EDGES) {
        int d = dst[e];
        int p = atomicAdd(&cursor[d], 1);
        eids[offs[d] + p] = src[e];
    }
}

// ---------------- conversions ----------------

__global__ void k_f2b8(const float* __restrict__ in, ushort_t* __restrict__ out, int n8) {
    int i = blockIdx.x * blockDim.x + threadIdx.x;
    if (i >= n8) return;
    float4 a = ld4(in + (size_t)i * 8);
    float4 b = ld4(in + (size_t)i * 8 + 4);
    uint_t o0 = (uint_t)f2b(a.x) | ((uint_t)f2b(a.y) << 16);
    uint_t o1 = (uint_t)f2b(a.z) | ((uint_t)f2b(a.w) << 16);
    uint_t o2 = (uint_t)f2b(b.x) | ((uint_t)f2b(b.y) << 16);
    uint_t o3 = (uint_t)f2b(b.z) | ((uint_t)f2b(b.w) << 16);
    *reinterpret_cast<uint4*>(out + (size_t)i * 8) = make_uint4(o0, o1, o2, o3);
}

// WT[f][k] = bf16(W[k][f]);  W is [K][F] row-major
__global__ void k_wtrans(const float* __restrict__ W, ushort_t* __restrict__ WT, int K, int F) {
    int idx = blockIdx.x * blockDim.x + threadIdx.x;
    if (idx < K * F) {
        int f = idx / K, k = idx - f * K;
        WT[idx] = f2b(W[(size_t)k * F + f]);
    }
}

// ---------------- mean aggregation, 16B gathers, one wave per node ----------------

#define ACCUM8(a) do { \
    acc[0] += bf2f((ushort_t)(a).x); acc[1] += bf2f((ushort_t)((a).x >> 16)); \
    acc[2] += bf2f((ushort_t)(a).y); acc[3] += bf2f((ushort_t)((a).y >> 16)); \
    acc[4] += bf2f((ushort_t)(a).z); acc[5] += bf2f((ushort_t)((a).z >> 16)); \
    acc[6] += bf2f((ushort_t)(a).w); acc[7] += bf2f((ushort_t)((a).w >> 16)); } while (0)

template<int OUTF>   // 1 = fp32 out, 0 = bf16 out
__global__ __launch_bounds__(256) void k_agg16(
        const ushort_t* __restrict__ h, const int* __restrict__ eids,
        const int* __restrict__ offs, const int* __restrict__ deg,
        const float* __restrict__ inv_deg, void* __restrict__ out) {
    constexpr int F = 128;
    constexpr int EPW = 4;      // edges per wave-pass
    int node = (blockIdx.x * 256 + threadIdx.x) >> 6;
    int lane = threadIdx.x & 63;
    if (node >= N_NODES) return;
    const int g = lane >> 4;
    const int lr = lane & 15;
    float acc[8];
#pragma unroll
    for (int v = 0; v < 8; ++v) acc[v] = 0.f;
    const int beg = offs[node];
    const int d = deg[node];
    const size_t coff = (size_t)lr * 8;

    int j = 0;
    for (; j + 4 * EPW <= d; j += 4 * EPW) {
        int s0 = eids[beg + j + g];
        int s1 = eids[beg + j + EPW + g];
        int s2 = eids[beg + j + 2 * EPW + g];
        int s3 = eids[beg + j + 3 * EPW + g];
        uint4 a = *reinterpret_cast<const uint4*>(h + (size_t)s0 * F + coff);
        uint4 b = *reinterpret_cast<const uint4*>(h + (size_t)s1 * F + coff);
        uint4 c = *reinterpret_cast<const uint4*>(h + (size_t)s2 * F + coff);
        uint4 e = *reinterpret_cast<const uint4*>(h + (size_t)s3 * F + coff);
        ACCUM8(a); ACCUM8(b); ACCUM8(c); ACCUM8(e);
    }
    for (; j + 2 * EPW <= d; j += 2 * EPW) {
        int s0 = eids[beg + j + g];
        int s1 = eids[beg + j + EPW + g];
        uint4 a = *reinterpret_cast<const uint4*>(h + (size_t)s0 * F + coff);
        uint4 b = *reinterpret_cast<const uint4*>(h + (size_t)s1 * F + coff);
        ACCUM8(a); ACCUM8(b);
    }
    for (; j < d; j += EPW) {
        int e = j + g;
        if (e < d) {
            int s0 = eids[beg + e];
            uint4 a = *reinterpret_cast<const uint4*>(h + (size_t)s0 * F + coff);
            ACCUM8(a);
        }
    }
#pragma unroll
    for (int v = 0; v < 8; ++v) acc[v] += __shfl_xor(acc[v], 16);
#pragma unroll
    for (int v = 0; v < 8; ++v) acc[v] += __shfl_xor(acc[v], 32);

    if (g == 0) {
        float sc = inv_deg[node];
#pragma unroll
        for (int v = 0; v < 8; ++v) acc[v] *= sc;
        if (OUTF) {
            float* o = (float*)out + (size_t)node * F + coff;
            *reinterpret_cast<float4*>(o) = make_float4(acc[0], acc[1], acc[2], acc[3]);
            *reinterpret_cast<float4*>(o + 4) = make_float4(acc[4], acc[5], acc[6], acc[7]);
        } else {
            uint4 o;
            o.x = (uint_t)f2b(acc[0]) | ((uint_t)f2b(acc[1]) << 16);
            o.y = (uint_t)f2b(acc[2]) | ((uint_t)f2b(acc[3]) << 16);
            o.z = (uint_t)f2b(acc[4]) | ((uint_t)f2b(acc[5]) << 16);
            o.w = (uint_t)f2b(acc[6]) | ((uint_t)f2b(acc[7]) << 16);
            *reinterpret_cast<uint4*>((ushort_t*)out + (size_t)node * F + coff) = o;
        }
    }
}

// ---------------- fused layer-3 aggregate + reparameterize ----------------
__global__ __launch_bounds__(256) void k_agg_reparam(
        const ushort_t* __restrict__ t3, const int* __restrict__ eids,
        const int* __restrict__ offs, const int* __restrict__ deg,
        const float* __restrict__ inv_deg, const float* __restrict__ u,
        const float* __restrict__ eps, float* __restrict__ z) {
    constexpr int F = 128;
    constexpr int EPW = 4;
    int node = (blockIdx.x * 256 + threadIdx.x) >> 6;
    int lane = threadIdx.x & 63;
    if (node >= N_NODES) return;
    const int g = lane >> 4;
    const int lr = lane & 15;
    float acc[8];
#pragma unroll
    for (int v = 0; v < 8; ++v) acc[v] = 0.f;
    const int beg = offs[node];
    const int d = deg[node];
    const size_t coff = (size_t)lr * 8;

    int j = 0;
    for (; j + 4 * EPW <= d; j += 4 * EPW) {
        int s0 = eids[beg + j + g];
        int s1 = eids[beg + j + EPW + g];
        int s2 = eids[beg + j + 2 * EPW + g];
        int s3 = eids[beg + j + 3 * EPW + g];
        uint4 a = *reinterpret_cast<const uint4*>(t3 + (size_t)s0 * F + coff);
        uint4 b = *reinterpret_cast<const uint4*>(t3 + (size_t)s1 * F + coff);
        uint4 c = *reinterpret_cast<const uint4*>(t3 + (size_t)s2 * F + coff);
        uint4 e = *reinterpret_cast<const uint4*>(t3 + (size_t)s3 * F + coff);
        ACCUM8(a); ACCUM8(b); ACCUM8(c); ACCUM8(e);
    }
    for (; j + 2 * EPW <= d; j += 2 * EPW) {
        int s0 = eids[beg + j + g];
        int s1 = eids[beg + j + EPW + g];
        uint4 a = *reinterpret_cast<const uint4*>(t3 + (size_t)s0 * F + coff);
        uint4 b = *reinterpret_cast<const uint4*>(t3 + (size_t)s1 * F + coff);
        ACCUM8(a); ACCUM8(b);
    }
    for (; j < d; j += EPW) {
        int e = j + g;
        if (e < d) {
            int s0 = eids[beg + e];
            uint4 a = *reinterpret_cast<const uint4*>(t3 + (size_t)s0 * F + coff);
            ACCUM8(a);
        }
    }
#pragma unroll
    for (int v = 0; v < 8; ++v) acc[v] += __shfl_xor(acc[v], 16);
#pragma unroll
    for (int v = 0; v < 8; ++v) acc[v] += __shfl_xor(acc[v], 32);
    float ls[8];
#pragma unroll
    for (int v = 0; v < 8; ++v) ls[v] = __shfl_down(acc[v], 8);

    if (g == 0 && lr < 8) {
        float sc = inv_deg[node];
        const float* um = u + (size_t)node * 128 + lr * 8;
        const float* ul = u + (size_t)node * 128 + 64 + lr * 8;
        const float* ep = eps + (size_t)node * 64 + lr * 8;
        float4 um0 = ld4(um), um1 = ld4(um + 4);
        float4 ul0 = ld4(ul), ul1 = ld4(ul + 4);
        float4 e0 = ld4(ep), e1 = ld4(ep + 4);
        float4 o0, o1;
        o0.x = (acc[0] * sc + um0.x) + expf(ls[0] * sc + ul0.x) * e0.x;
        o0.y = (acc[1] * sc + um0.y) + expf(ls[1] * sc + ul0.y) * e0.y;
        o0.z = (acc[2] * sc + um0.z) + expf(ls[2] * sc + ul0.z) * e0.z;
        o0.w = (acc[3] * sc + um0.w) + expf(ls[3] * sc + ul0.w) * e0.w;
        o1.x = (acc[4] * sc + um1.x) + expf(ls[4] * sc + ul1.x) * e1.x;
        o1.y = (acc[5] * sc + um1.y) + expf(ls[5] * sc + ul1.y) * e1.y;
        o1.z = (acc[6] * sc + um1.z) + expf(ls[6] * sc + ul1.z) * e1.z;
        o1.w = (acc[7] * sc + um1.w) + expf(ls[7] * sc + ul1.w) * e1.w;
        float* zp = z + (size_t)node * 64 + lr * 8;
        *reinterpret_cast<float4*>(zp) = o0;
        *reinterpret_cast<float4*>(zp + 4) = o1;
    }
}

// ---------------- MFMA GEMM (+ optional fused BN column stats) ----------------
// out[M][F] = A1@B1' (+ A2@B2') (+ bias); B args are WT [F][K] bf16.
// 128x128 block tile, BK=32, 4 waves (each 64x64), mfma_f32_16x16x32_bf16.
// STATS: per-block column partial sums/sumsq written to partials[2F][GXP]
// (atomic-free; reduced by k_bn_scsh). Stats use pre-rounding fp32 values.

template<int RELU, int OUTB, int DUAL, int BIAS, int STATS>
__global__ __launch_bounds__(256) void k_gemm_mfma(
        const ushort_t* __restrict__ A1, const ushort_t* __restrict__ A2,
        const ushort_t* __restrict__ B1, const ushort_t* __restrict__ B2,
        const float* __restrict__ bias, void* __restrict__ out,
        int K, int F, float* __restrict__ partials) {
    __shared__ __align__(16) short lds[8192];   // A: [0,4096), B: [4096,8192)
    const int tid = threadIdx.x;
    const int lane = tid & 63;
    const int w = tid >> 6;
    const int row0 = blockIdx.x * 128;
    const int col0 = blockIdx.y * 128;
    const int wr = (w >> 1) * 64;
    const int wc = (w & 1) * 64;

    int rowA[2], slA[2];
#pragma unroll
    for (int p = 0; p < 2; ++p) {
        int c = (p * 4 + w) * 64 + lane;
        int r = c >> 2, sp = c & 3;
        rowA[p] = r;
        slA[p] = sp ^ ((r >> 1) & 3);
    }
    const int q = lane >> 4, lr = lane & 15;
    int aoff[4], boff[4];
#pragma unroll
    for (int f = 0; f < 4; ++f) {
        int ra = wr + f * 16 + lr;
        aoff[f] = ra * 32 + (q ^ ((ra >> 1) & 3)) * 8;
        int rb = wc + f * 16 + lr;
        boff[f] = 4096 + rb * 32 + (q ^ ((rb >> 1) & 3)) * 8;
    }

    f32x4 acc[4][4];
#pragma unroll
    for (int mf = 0; mf < 4; ++mf)
#pragma unroll
        for (int nf = 0; nf < 4; ++nf)
            acc[mf][nf] = (f32x4){0.f, 0.f, 0.f, 0.f};

    for (int m = 0; m < (DUAL ? 2 : 1); ++m) {
        const ushort_t* __restrict__ A = m ? A2 : A1;
        const ushort_t* __restrict__ B = m ? B2 : B1;
        for (int k0 = 0; k0 < K; k0 += 32) {
            __syncthreads();
#pragma unroll
            for (int p = 0; p < 2; ++p) {
                int gr = row0 + rowA[p];
                if (gr > N_NODES - 1) gr = N_NODES - 1;
                gload16(A + (size_t)gr * K + k0 + slA[p] * 8, &lds[(p * 4 + w) * 512]);
                int gc = col0 + rowA[p];
                gload16(B + (size_t)gc * K + k0 + slA[p] * 8, &lds[4096 + (p * 4 + w) * 512]);
            }
            asm volatile("s_waitcnt vmcnt(0)" ::: "memory");
            __syncthreads();
            bf16x8 av[4], bv[4];
#pragma unroll
            for (int f = 0; f < 4; ++f) {
                av[f] = *reinterpret_cast<const bf16x8*>(&lds[aoff[f]]);
                bv[f] = *reinterpret_cast<const bf16x8*>(&lds[boff[f]]);
            }
#pragma unroll
            for (int mf = 0; mf < 4; ++mf)
#pragma unroll
                for (int nf = 0; nf < 4; ++nf)
                    acc[mf][nf] = __builtin_amdgcn_mfma_f32_16x16x32_bf16(
                        av[mf], bv[nf], acc[mf][nf], 0, 0, 0);
        }
    }

    // epilogue: D lane map (m89): col = lane&15, row = (lane>>4)*4 + b
    const int orow = row0 + wr + q * 4;
    const int ocol = col0 + wc + lr;
    float s[4], s2[4];
#pragma unroll
    for (int nf = 0; nf < 4; ++nf) { s[nf] = 0.f; s2[nf] = 0.f; }
#pragma unroll
    for (int nf = 0; nf < 4; ++nf) {
        int colg = ocol + nf * 16;
        float bvs = BIAS ? bias[colg] : 0.f;
#pragma unroll
        for (int mf = 0; mf < 4; ++mf) {
#pragma unroll
            for (int b = 0; b < 4; ++b) {
                int r = orow + mf * 16 + b;
                if (r < N_NODES) {
                    float v = acc[mf][nf][b] + bvs;
                    if (RELU) v = fmaxf(v, 0.f);
                    if (STATS) { s[nf] += v; s2[nf] += v * v; }
                    if (OUTB)
                        ((ushort_t*)out)[(size_t)r * F + colg] = f2b(v);
                    else
                        ((float*)out)[(size_t)r * F + colg] = v;
                }
            }
        }
    }

    if constexpr (STATS) {
        // reuse staging LDS (dead after last MFMA reads) for the column reduce
        __syncthreads();
        float* sdf = (float*)lds;               // 2048 floats < 16 KB
        const int u = (w >> 1) * 4 + q;         // 8 contributors per column
#pragma unroll
        for (int nf = 0; nf < 4; ++nf) {
            int cb = wc + nf * 16 + lr;         // 0..127 within block
            sdf[u * 128 + cb] = s[nf];
            sdf[1024 + u * 128 + cb] = s2[nf];
        }
        __syncthreads();
        if (tid < 128) {
            float ss = 0.f, qq = 0.f;
#pragma unroll
            for (int u2 = 0; u2 < 8; ++u2) {
                ss += sdf[u2 * 128 + tid];
                qq += sdf[1024 + u2 * 128 + tid];
            }
            int cg = col0 + tid;
            partials[(size_t)cg * GXP + blockIdx.x] = ss;
            partials[(size_t)(F + cg) * GXP + blockIdx.x] = qq;
        }
    }
}

// ---------------- BN: reduce partials -> scale/shift ----------------
// one wave per column; reads partials[c][0..GX) and partials[F+c][0..GX)

template<int F>
__global__ __launch_bounds__(64) void k_bn_scsh(
        const float* __restrict__ partials, const float* __restrict__ gamma,
        const float* __restrict__ beta, float* __restrict__ scsh, int GX) {
    const int c = blockIdx.x;
    const int l = threadIdx.x;
    float s = 0.f, q2 = 0.f;
    for (int g = l; g < GX; g += 64) {
        s += partials[(size_t)c * GXP + g];
        q2 += partials[(size_t)(F + c) * GXP + g];
    }
#pragma unroll
    for (int off = 1; off < 64; off <<= 1) {
        s += __shfl_xor(s, off);
        q2 += __shfl_xor(q2, off);
    }
    if (l == 0) {
        float mean = s * (1.0f / N_NODES);
        float var = q2 * (1.0f / N_NODES) - mean * mean;
        float sc = gamma[c] * rsqrtf(var + BN_EPS_F);
        scsh[c] = sc;
        scsh[F + c] = beta[c] - mean * sc;
    }
}

template<int F>
__global__ void k_bn_apply_b(ushort_t* __restrict__ h, const float* __restrict__ scsh) {
    int i = blockIdx.x * blockDim.x + threadIdx.x;   // 8-col chunk index
    int total = N_NODES * F / 8;
    if (i >= total) return;
    int c = (i * 8) % F;
    uint4 v = *reinterpret_cast<const uint4*>(h + (size_t)i * 8);
    float4 s0 = ld4(&scsh[c]), s1 = ld4(&scsh[c + 4]);
    float4 b0 = ld4(&scsh[F + c]), b1 = ld4(&scsh[F + c + 4]);
    uint_t o0 = (uint_t)f2b(bf2f((ushort_t)v.x) * s0.x + b0.x)
              | ((uint_t)f2b(bf2f((ushort_t)(v.x >> 16)) * s0.y + b0.y) << 16);
    uint_t o1 = (uint_t)f2b(bf2f((ushort_t)v.y) * s0.z + b0.z)
              | ((uint_t)f2b(bf2f((ushort_t)(v.y >> 16)) * s0.w + b0.w) << 16);
    uint_t o2 = (uint_t)f2b(bf2f((ushort_t)v.z) * s1.x + b1.x)
              | ((uint_t)f2b(bf2f((ushort_t)(v.z >> 16)) * s1.y + b1.y) << 16);
    uint_t o3 = (uint_t)f2b(bf2f((ushort_t)v.w) * s1.z + b1.z)
              | ((uint_t)f2b(bf2f((ushort_t)(v.w >> 16)) * s1.w + b1.w) << 16);
    *reinterpret_cast<uint4*>(h + (size_t)i * 8) = make_uint4(o0, o1, o2, o3);
}

// ---------------- launch ----------------

extern "C" void kernel_launch(void* const* d_in, const int* in_sizes, int n_in,
                              void* d_out, int out_size, void* d_ws, size_t ws_size,
                              hipStream_t stream) {
    (void)in_sizes; (void)n_in; (void)out_size; (void)ws_size;
    const float* x   = (const float*)d_in[0];
    const int*   src = (const int*)d_in[1];
    const int*   dst = (const int*)d_in[2];
    const float* eps = (const float*)d_in[3];
    const float* W1l = (const float*)d_in[4];
    const float* W1r = (const float*)d_in[5];
    const float* b1  = (const float*)d_in[6];
    const float* g1  = (const float*)d_in[7];
    const float* be1 = (const float*)d_in[8];
    const float* W2l = (const float*)d_in[9];
    const float* W2r = (const float*)d_in[10];
    const float* b2  = (const float*)d_in[11];
    const float* g2  = (const float*)d_in[12];
    const float* be2 = (const float*)d_in[13];
    const float* W3l = (const float*)d_in[14];
    const float* W3r = (const float*)d_in[15];
    const float* b3  = (const float*)d_in[16];
    float* z = (float*)d_out;

    char* ws = (char*)d_ws;
    size_t off = 0;
    auto alloc = [&](size_t bytes) -> char* {
        char* p = ws + off;
        off += (bytes + 255) & ~(size_t)255;
        return p;
    };
    int*      deg    = (int*)alloc(N_NODES * 4);
    int*      cursor = (int*)alloc(N_NODES * 4);
    size_t zero_bytes = off;
    float*    scshs  = (float*)alloc(1024 * 4);    // scsh1 (256) + scsh2 (512)
    int*      offs   = (int*)alloc(N_NODES * 4);
    int*      bsum   = (int*)alloc(128 * 4);
    int*      eids   = (int*)alloc((size_t)N_EDGES * 4);
    float*    invd   = (float*)alloc(N_NODES * 4);
    ushort_t* xb     = (ushort_t*)alloc((size_t)N_NODES * 128 * 2);
    ushort_t* h1b    = (ushort_t*)alloc((size_t)N_NODES * 128 * 2);
    ushort_t* h2b    = (ushort_t*)alloc((size_t)N_NODES * 256 * 2);
    ushort_t* aggrb  = (ushort_t*)alloc((size_t)N_NODES * 256 * 2);   // layer-1/2 aggr; reused as t3
    float*    u3f    = (float*)alloc((size_t)N_NODES * 128 * 4);
    float*    parts  = (float*)alloc((size_t)512 * GXP * 4);          // [2F][GXP], F<=256
    ushort_t* wt1l   = (ushort_t*)alloc(128 * 128 * 2);
    ushort_t* wt1r   = (ushort_t*)alloc(128 * 128 * 2);
    ushort_t* wt2l   = (ushort_t*)alloc(256 * 128 * 2);
    ushort_t* wt2r   = (ushort_t*)alloc(256 * 128 * 2);
    ushort_t* wt3l   = (ushort_t*)alloc(128 * 256 * 2);
    ushort_t* wt3r   = (ushort_t*)alloc(128 * 256 * 2);
    ushort_t* t3b    = aggrb;   // layer-3: t3 = h2@W3l (bf16 [N,128])

    float* scsh1 = scshs;            // 2*128
    float* scsh2 = scshs + 256;      // 2*256

    // CSR build (recomputed per call — graph replay safe)
    int zn = (int)(zero_bytes / 4);
    k_zero_i32<<<(zn + 255) / 256, 256, 0, stream>>>((int*)ws, zn);
    k_count<<<(N_EDGES + 255) / 256, 256, 0, stream>>>(dst, deg);
    k_scan1<<<SCAN_NB, SCAN_BS, 0, stream>>>(deg, offs, bsum);
    k_scan2<<<1, 128, 0, stream>>>(bsum, SCAN_NB);
    k_scan3<<<(N_NODES + 255) / 256, 256, 0, stream>>>(deg, offs, bsum, invd);
    k_fill<<<(N_EDGES + 255) / 256, 256, 0, stream>>>(src, dst, offs, cursor, eids);

    // bf16 conversions
    k_f2b8<<<(N_NODES * 128 / 8 + 255) / 256, 256, 0, stream>>>(x, xb, N_NODES * 128 / 8);
    k_wtrans<<<(128 * 128 + 255) / 256, 256, 0, stream>>>(W1l, wt1l, 128, 128);
    k_wtrans<<<(128 * 128 + 255) / 256, 256, 0, stream>>>(W1r, wt1r, 128, 128);
    k_wtrans<<<(128 * 256 + 255) / 256, 256, 0, stream>>>(W2l, wt2l, 128, 256);
    k_wtrans<<<(128 * 256 + 255) / 256, 256, 0, stream>>>(W2r, wt2r, 128, 256);
    k_wtrans<<<(256 * 128 + 255) / 256, 256, 0, stream>>>(W3l, wt3l, 256, 128);
    k_wtrans<<<(256 * 128 + 255) / 256, 256, 0, stream>>>(W3r, wt3r, 256, 128);

    const int AGG_BLKS = (N_NODES + 3) / 4;   // one wave per node, 4 waves/block
    const int GX = (N_NODES + 127) / 128;     // 391

    // ---- Layer 1: SAGE(x) -> relu (+fused BN stats) -> BN apply  (K=128, F=128)
    k_agg16<0><<<AGG_BLKS, 256, 0, stream>>>(xb, eids, offs, deg, invd, aggrb);
    k_gemm_mfma<1, 1, 1, 1, 1><<<dim3(GX, 1), 256, 0, stream>>>(aggrb, xb, wt1l, wt1r, b1, h1b, 128, 128, parts);
    k_bn_scsh<128><<<128, 64, 0, stream>>>(parts, g1, be1, scsh1, GX);
    k_bn_apply_b<128><<<(N_NODES * 128 / 8 + 255) / 256, 256, 0, stream>>>(h1b, scsh1);

    // ---- Layer 2: SAGE(h1) -> relu (+fused BN stats) -> BN apply  (K=128, F=256)
    k_agg16<0><<<AGG_BLKS, 256, 0, stream>>>(h1b, eids, offs, deg, invd, aggrb);
    k_gemm_mfma<1, 1, 1, 1, 1><<<dim3(GX, 2), 256, 0, stream>>>(aggrb, h1b, wt2l, wt2r, b2, h2b, 128, 256, parts);
    k_bn_scsh<256><<<256, 64, 0, stream>>>(parts, g2, be2, scsh2, GX);
    k_bn_apply_b<256><<<(N_NODES * 256 / 8 + 255) / 256, 256, 0, stream>>>(h2b, scsh2);

    // ---- Layer 3 (commuted): t3 = h2@W3l (bf16); u3 = h2@W3r + b3 (fp32);
    //      fused: z = (agg(t3)+u3)_m + exp((agg(t3)+u3)_ls)*eps
    k_gemm_mfma<0, 1, 0, 0, 0><<<dim3(GX, 1), 256, 0, stream>>>(h2b, nullptr, wt3l, nullptr, nullptr, t3b, 256, 128, nullptr);
    k_gemm_mfma<0, 0, 0, 1, 0><<<dim3(GX, 1), 256, 0, stream>>>(h2b, nullptr, wt3r, nullptr, b3, u3f, 256, 128, nullptr);
    k_agg_reparam<<<AGG_BLKS, 256, 0, stream>>>(t3b, eids, offs, deg, invd, u3f, eps, z);
}

// Round 6
// 299.478 us; speedup vs baseline: 2.7543x; 1.0637x over previous
//
#include <hip/hip_runtime.h>
#include <math.h>

#define N_NODES 50000
#define N_EDGES 800000
#define BN_EPS_F 1e-5f
#define SCAN_BS 512
#define SCAN_NB 98   // ceil(50000/512)
#define GXP 392      // padded partials stride (>= GX=391)

typedef unsigned short ushort_t;
typedef unsigned int uint_t;
typedef __attribute__((ext_vector_type(8))) short bf16x8;
typedef __attribute__((ext_vector_type(4))) float f32x4;

static __device__ __forceinline__ float4 ld4(const float* p) {
    return *reinterpret_cast<const float4*>(p);
}
static __device__ __forceinline__ float bf2f(ushort_t u) {
    return __uint_as_float(((uint_t)u) << 16);
}
static __device__ __forceinline__ ushort_t f2b(float f) {
    uint_t u = __float_as_uint(f);
    u += 0x7fffu + ((u >> 16) & 1u);
    return (ushort_t)(u >> 16);
}
static __device__ __forceinline__ void gload16(const void* g, void* l) {
    __builtin_amdgcn_global_load_lds(
        (const __attribute__((address_space(1))) void*)g,
        (__attribute__((address_space(3))) void*)l, 16, 0, 0);
}

// ---------------- CSR build ----------------

__global__ void k_zero_i32(int* __restrict__ p, int n) {
    int i = blockIdx.x * blockDim.x + threadIdx.x;
    if (i < n) p[i] = 0;
}

// single atomic pass: degree count + per-edge rank (coalesced store)
__global__ void k_countrank(const int* __restrict__ dst, int* __restrict__ deg,
                            int* __restrict__ rank) {
    int e = blockIdx.x * blockDim.x + threadIdx.x;
    if (e < N_EDGES) rank[e] = atomicAdd(&deg[dst[e]], 1);
}

__global__ void k_scan1(const int* __restrict__ deg, int* __restrict__ offs, int* __restrict__ bsum) {
    __shared__ int sh[SCAN_BS];
    int t = threadIdx.x;
    int g = blockIdx.x * SCAN_BS + t;
    int v = (g < N_NODES) ? deg[g] : 0;
    sh[t] = v;
    __syncthreads();
    for (int off = 1; off < SCAN_BS; off <<= 1) {
        int add = (t >= off) ? sh[t - off] : 0;
        __syncthreads();
        sh[t] += add;
        __syncthreads();
    }
    if (g < N_NODES) offs[g] = sh[t] - v;
    if (t == SCAN_BS - 1) bsum[blockIdx.x] = sh[t];
}

__global__ void k_scan2(int* __restrict__ bsum, int nb) {
    __shared__ int sh[128];
    int t = threadIdx.x;
    int v = (t < nb) ? bsum[t] : 0;
    sh[t] = v;
    __syncthreads();
    for (int off = 1; off < 128; off <<= 1) {
        int add = (t >= off) ? sh[t - off] : 0;
        __syncthreads();
        sh[t] += add;
        __syncthreads();
    }
    if (t < nb) bsum[t] = sh[t] - v;
}

__global__ void k_scan3(const int* __restrict__ deg, int* __restrict__ offs,
                        const int* __restrict__ bsum, float* __restrict__ inv_deg) {
    int g = blockIdx.x * blockDim.x + threadIdx.x;
    if (g < N_NODES) {
        offs[g] += bsum[g / SCAN_BS];
        int d = deg[g];
        inv_deg[g] = 1.0f / (float)(d > 1 ? d : 1);
    }
}

// atomic-free scatter: pure fire-and-forget stores
__global__ void k_fill2(const int* __restrict__ src, const int* __restrict__ dst,
                        const int* __restrict__ offs, const int* __restrict__ rank,
                        int* __restrict__ eids) {
    int e = blockIdx.x * blockDim.x + threadIdx.x;
    if (e < N_EDGES) eids[offs[dst[e]] + rank[e]] = src[e];
}

// ---------------- conversions / weight prep ----------------

__global__ void k_f2b8(const float* __restrict__ in, ushort_t* __restrict__ out, int n8) {
    int i = blockIdx.x * blockDim.x + threadIdx.x;
    if (i >= n8) return;
    float4 a = ld4(in + (size_t)i * 8);
    float4 b = ld4(in + (size_t)i * 8 + 4);
    uint_t o0 = (uint_t)f2b(a.x) | ((uint_t)f2b(a.y) << 16);
    uint_t o1 = (uint_t)f2b(a.z) | ((uint_t)f2b(a.w) << 16);
    uint_t o2 = (uint_t)f2b(b.x) | ((uint_t)f2b(b.y) << 16);
    uint_t o3 = (uint_t)f2b(b.z) | ((uint_t)f2b(b.w) << 16);
    *reinterpret_cast<uint4*>(out + (size_t)i * 8) = make_uint4(o0, o1, o2, o3);
}

// upfront transposes (unscaled): wt1l, wt1r (128x128), wt2l (128x256)
__global__ void k_prep1(const float* __restrict__ W1l, const float* __restrict__ W1r,
                        const float* __restrict__ W2l, ushort_t* __restrict__ wt1l,
                        ushort_t* __restrict__ wt1r, ushort_t* __restrict__ wt2l) {
    int idx = blockIdx.x * 256 + threadIdx.x;   // 0..65535
    if (idx < 16384) {
        int f = idx >> 7, k = idx & 127;
        wt1l[idx] = f2b(W1l[(size_t)k * 128 + f]);
    } else if (idx < 32768) {
        int j = idx - 16384;
        int f = j >> 7, k = j & 127;
        wt1r[j] = f2b(W1r[(size_t)k * 128 + f]);
    } else {
        int j = idx - 32768;                    // 0..32767, F=256 K=128
        int f = j >> 7, k = j & 127;
        wt2l[j] = f2b(W2l[(size_t)k * 256 + f]);
    }
}

// layer-2 prep (after scsh1): wt2r[f*128+k] = sc1[k]*W2r[k][f]; bias2[f] = b2[f] + sum_k sh1[k]*W2r[k][f]
__global__ void k_prep2(const float* __restrict__ W2r, const float* __restrict__ b2,
                        const float* __restrict__ scsh1, ushort_t* __restrict__ wt2r,
                        float* __restrict__ bias2) {
    int bid = blockIdx.x;
    if (bid < 128) {
        int idx = bid * 256 + threadIdx.x;      // 0..32767, F=256 K=128
        int f = idx >> 7, k = idx & 127;
        wt2r[idx] = f2b(scsh1[k] * W2r[(size_t)k * 256 + f]);
    } else {
        int f = threadIdx.x;                    // 256 cols
        float s = b2[f];
        for (int k = 0; k < 128; ++k) s += scsh1[128 + k] * W2r[(size_t)k * 256 + f];
        bias2[f] = s;
    }
}

// layer-3 prep (after scsh2): scaled transposes of W3l/W3r (256x128) + effective biases
__global__ void k_prep3(const float* __restrict__ W3l, const float* __restrict__ W3r,
                        const float* __restrict__ b3, const float* __restrict__ scsh2,
                        ushort_t* __restrict__ wt3l, ushort_t* __restrict__ wt3r,
                        float* __restrict__ bias3l, float* __restrict__ bias3r) {
    int bid = blockIdx.x;
    if (bid < 256) {
        int half = bid >> 7;                    // 0: W3l, 1: W3r
        int idx = (bid & 127) * 256 + threadIdx.x;   // 0..32767, F=128 K=256
        int f = idx >> 8, k = idx & 255;
        const float* W = half ? W3r : W3l;
        ushort_t* WT = half ? wt3r : wt3l;
        WT[idx] = f2b(scsh2[k] * W[(size_t)k * 128 + f]);
    } else {
        int t = threadIdx.x;
        int f = t & 127;
        const float* W = (t < 128) ? W3l : W3r;
        float s = (t < 128) ? 0.f : b3[f];
        for (int k = 0; k < 256; ++k) s += scsh2[256 + k] * W[(size_t)k * 128 + f];
        float* out = (t < 128) ? bias3l : bias3r;
        out[f] = s;
    }
}

// ---------------- gather core: F=128 bf16 rows, 16 lanes x 16B, 4 edge groups ----------------

#define ACCUM8(a) do { \
    acc[0] += bf2f((ushort_t)(a).x); acc[1] += bf2f((ushort_t)((a).x >> 16)); \
    acc[2] += bf2f((ushort_t)(a).y); acc[3] += bf2f((ushort_t)((a).y >> 16)); \
    acc[4] += bf2f((ushort_t)(a).z); acc[5] += bf2f((ushort_t)((a).z >> 16)); \
    acc[6] += bf2f((ushort_t)(a).w); acc[7] += bf2f((ushort_t)((a).w >> 16)); } while (0)

static __device__ __forceinline__ void gather_rows(
        const ushort_t* __restrict__ h, const int* __restrict__ eids,
        int beg, int d, int g, size_t coff, float* acc) {
    int j = 0;
    for (; j + 32 <= d; j += 32) {              // 8 edges per group in flight
        int s[8];
#pragma unroll
        for (int k = 0; k < 8; ++k) s[k] = eids[beg + j + k * 4 + g];
        uint4 a[8];
#pragma unroll
        for (int k = 0; k < 8; ++k) a[k] = *reinterpret_cast<const uint4*>(h + (size_t)s[k] * 128 + coff);
#pragma unroll
        for (int k = 0; k < 8; ++k) ACCUM8(a[k]);
    }
    for (; j + 16 <= d; j += 16) {
        int s[4];
#pragma unroll
        for (int k = 0; k < 4; ++k) s[k] = eids[beg + j + k * 4 + g];
        uint4 a[4];
#pragma unroll
        for (int k = 0; k < 4; ++k) a[k] = *reinterpret_cast<const uint4*>(h + (size_t)s[k] * 128 + coff);
#pragma unroll
        for (int k = 0; k < 4; ++k) ACCUM8(a[k]);
    }
    for (; j + 8 <= d; j += 8) {
        int s0 = eids[beg + j + g];
        int s1 = eids[beg + j + 4 + g];
        uint4 a = *reinterpret_cast<const uint4*>(h + (size_t)s0 * 128 + coff);
        uint4 b = *reinterpret_cast<const uint4*>(h + (size_t)s1 * 128 + coff);
        ACCUM8(a); ACCUM8(b);
    }
    for (; j < d; j += 4) {
        int e = j + g;
        if (e < d) {
            int s0 = eids[beg + e];
            uint4 a = *reinterpret_cast<const uint4*>(h + (size_t)s0 * 128 + coff);
            ACCUM8(a);
        }
    }
}

// mean aggregation, one wave per node. BN=1: fused y = d>0 ? mean*sc+sh : 0
template<int BN>
__global__ __launch_bounds__(256) void k_agg16(
        const ushort_t* __restrict__ h, const int* __restrict__ eids,
        const int* __restrict__ offs, const int* __restrict__ deg,
        const float* __restrict__ inv_deg, const float* __restrict__ scsh,
        ushort_t* __restrict__ out) {
    int node = (blockIdx.x * 256 + threadIdx.x) >> 6;
    int lane = threadIdx.x & 63;
    if (node >= N_NODES) return;
    const int g = lane >> 4;
    const int lr = lane & 15;
    float acc[8];
#pragma unroll
    for (int v = 0; v < 8; ++v) acc[v] = 0.f;
    const int beg = offs[node];
    const int d = deg[node];
    const size_t coff = (size_t)lr * 8;
    gather_rows(h, eids, beg, d, g, coff, acc);
#pragma unroll
    for (int v = 0; v < 8; ++v) acc[v] += __shfl_xor(acc[v], 16);
#pragma unroll
    for (int v = 0; v < 8; ++v) acc[v] += __shfl_xor(acc[v], 32);

    if (g == 0) {
        float sc = inv_deg[node];
        if (BN) {
            float4 sa0 = ld4(&scsh[lr * 8]), sa1 = ld4(&scsh[lr * 8 + 4]);
            float4 sb0 = ld4(&scsh[128 + lr * 8]), sb1 = ld4(&scsh[128 + lr * 8 + 4]);
            if (d > 0) {
                acc[0] = acc[0] * sc * sa0.x + sb0.x; acc[1] = acc[1] * sc * sa0.y + sb0.y;
                acc[2] = acc[2] * sc * sa0.z + sb0.z; acc[3] = acc[3] * sc * sa0.w + sb0.w;
                acc[4] = acc[4] * sc * sa1.x + sb1.x; acc[5] = acc[5] * sc * sa1.y + sb1.y;
                acc[6] = acc[6] * sc * sa1.z + sb1.z; acc[7] = acc[7] * sc * sa1.w + sb1.w;
            } else {
#pragma unroll
                for (int v = 0; v < 8; ++v) acc[v] = 0.f;
            }
        } else {
#pragma unroll
            for (int v = 0; v < 8; ++v) acc[v] *= sc;
        }
        uint4 o;
        o.x = (uint_t)f2b(acc[0]) | ((uint_t)f2b(acc[1]) << 16);
        o.y = (uint_t)f2b(acc[2]) | ((uint_t)f2b(acc[3]) << 16);
        o.z = (uint_t)f2b(acc[4]) | ((uint_t)f2b(acc[5]) << 16);
        o.w = (uint_t)f2b(acc[6]) | ((uint_t)f2b(acc[7]) << 16);
        *reinterpret_cast<uint4*>(out + (size_t)node * 128 + coff) = o;
    }
}

// fused layer-3 aggregate + reparameterize
__global__ __launch_bounds__(256) void k_agg_reparam(
        const ushort_t* __restrict__ t3, const int* __restrict__ eids,
        const int* __restrict__ offs, const int* __restrict__ deg,
        const float* __restrict__ inv_deg, const float* __restrict__ u,
        const float* __restrict__ eps, float* __restrict__ z) {
    int node = (blockIdx.x * 256 + threadIdx.x) >> 6;
    int lane = threadIdx.x & 63;
    if (node >= N_NODES) return;
    const int g = lane >> 4;
    const int lr = lane & 15;
    float acc[8];
#pragma unroll
    for (int v = 0; v < 8; ++v) acc[v] = 0.f;
    const int beg = offs[node];
    const int d = deg[node];
    const size_t coff = (size_t)lr * 8;
    gather_rows(t3, eids, beg, d, g, coff, acc);
#pragma unroll
    for (int v = 0; v < 8; ++v) acc[v] += __shfl_xor(acc[v], 16);
#pragma unroll
    for (int v = 0; v < 8; ++v) acc[v] += __shfl_xor(acc[v], 32);
    float ls[8];
#pragma unroll
    for (int v = 0; v < 8; ++v) ls[v] = __shfl_down(acc[v], 8);

    if (g == 0 && lr < 8) {
        float sc = inv_deg[node];
        const float* um = u + (size_t)node * 128 + lr * 8;
        const float* ul = u + (size_t)node * 128 + 64 + lr * 8;
        const float* ep = eps + (size_t)node * 64 + lr * 8;
        float4 um0 = ld4(um), um1 = ld4(um + 4);
        float4 ul0 = ld4(ul), ul1 = ld4(ul + 4);
        float4 e0 = ld4(ep), e1 = ld4(ep + 4);
        float4 o0, o1;
        o0.x = (acc[0] * sc + um0.x) + expf(ls[0] * sc + ul0.x) * e0.x;
        o0.y = (acc[1] * sc + um0.y) + expf(ls[1] * sc + ul0.y) * e0.y;
        o0.z = (acc[2] * sc + um0.z) + expf(ls[2] * sc + ul0.z) * e0.z;
        o0.w = (acc[3] * sc + um0.w) + expf(ls[3] * sc + ul0.w) * e0.w;
        o1.x = (acc[4] * sc + um1.x) + expf(ls[4] * sc + ul1.x) * e1.x;
        o1.y = (acc[5] * sc + um1.y) + expf(ls[5] * sc + ul1.y) * e1.y;
        o1.z = (acc[6] * sc + um1.z) + expf(ls[6] * sc + ul1.z) * e1.z;
        o1.w = (acc[7] * sc + um1.w) + expf(ls[7] * sc + ul1.w) * e1.w;
        float* zp = z + (size_t)node * 64 + lr * 8;
        *reinterpret_cast<float4*>(zp) = o0;
        *reinterpret_cast<float4*>(zp + 4) = o1;
    }
}

// ---------------- MFMA GEMM (+ optional fused BN column stats) ----------------
// out[M][F] = A1@B1' (+ A2@B2') (+ bias); B args are WT [F][K] bf16.
// 128x128 block tile, BK=32, 4 waves (each 64x64), mfma_f32_16x16x32_bf16.

template<int RELU, int OUTB, int DUAL, int BIAS, int STATS>
__global__ __launch_bounds__(256) void k_gemm_mfma(
        const ushort_t* __restrict__ A1, const ushort_t* __restrict__ A2,
        const ushort_t* __restrict__ B1, const ushort_t* __restrict__ B2,
        const float* __restrict__ bias, void* __restrict__ out,
        int K, int F, float* __restrict__ partials) {
    __shared__ __align__(16) short lds[8192];   // A: [0,4096), B: [4096,8192)
    const int tid = threadIdx.x;
    const int lane = tid & 63;
    const int w = tid >> 6;
    const int row0 = blockIdx.x * 128;
    const int col0 = blockIdx.y * 128;
    const int wr = (w >> 1) * 64;
    const int wc = (w & 1) * 64;

    int rowA[2], slA[2];
#pragma unroll
    for (int p = 0; p < 2; ++p) {
        int c = (p * 4 + w) * 64 + lane;
        int r = c >> 2, sp = c & 3;
        rowA[p] = r;
        slA[p] = sp ^ ((r >> 1) & 3);
    }
    const int q = lane >> 4, lr = lane & 15;
    int aoff[4], boff[4];
#pragma unroll
    for (int f = 0; f < 4; ++f) {
        int ra = wr + f * 16 + lr;
        aoff[f] = ra * 32 + (q ^ ((ra >> 1) & 3)) * 8;
        int rb = wc + f * 16 + lr;
        boff[f] = 4096 + rb * 32 + (q ^ ((rb >> 1) & 3)) * 8;
    }

    f32x4 acc[4][4];
#pragma unroll
    for (int mf = 0; mf < 4; ++mf)
#pragma unroll
        for (int nf = 0; nf < 4; ++nf)
            acc[mf][nf] = (f32x4){0.f, 0.f, 0.f, 0.f};

    for (int m = 0; m < (DUAL ? 2 : 1); ++m) {
        const ushort_t* __restrict__ A = m ? A2 : A1;
        const ushort_t* __restrict__ B = m ? B2 : B1;
        for (int k0 = 0; k0 < K; k0 += 32) {
            __syncthreads();
#pragma unroll
            for (int p = 0; p < 2; ++p) {
                int gr = row0 + rowA[p];
                if (gr > N_NODES - 1) gr = N_NODES - 1;
                gload16(A + (size_t)gr * K + k0 + slA[p] * 8, &lds[(p * 4 + w) * 512]);
                int gc = col0 + rowA[p];
                gload16(B + (size_t)gc * K + k0 + slA[p] * 8, &lds[4096 + (p * 4 + w) * 512]);
            }
            asm volatile("s_waitcnt vmcnt(0)" ::: "memory");
            __syncthreads();
            bf16x8 av[4], bv[4];
#pragma unroll
            for (int f = 0; f < 4; ++f) {
                av[f] = *reinterpret_cast<const bf16x8*>(&lds[aoff[f]]);
                bv[f] = *reinterpret_cast<const bf16x8*>(&lds[boff[f]]);
            }
#pragma unroll
            for (int mf = 0; mf < 4; ++mf)
#pragma unroll
                for (int nf = 0; nf < 4; ++nf)
                    acc[mf][nf] = __builtin_amdgcn_mfma_f32_16x16x32_bf16(
                        av[mf], bv[nf], acc[mf][nf], 0, 0, 0);
        }
    }

    // epilogue: D lane map (m89): col = lane&15, row = (lane>>4)*4 + b
    const int orow = row0 + wr + q * 4;
    const int ocol = col0 + wc + lr;
    float s[4], s2[4];
#pragma unroll
    for (int nf = 0; nf < 4; ++nf) { s[nf] = 0.f; s2[nf] = 0.f; }
#pragma unroll
    for (int nf = 0; nf < 4; ++nf) {
        int colg = ocol + nf * 16;
        float bvs = BIAS ? bias[colg] : 0.f;
#pragma unroll
        for (int mf = 0; mf < 4; ++mf) {
#pragma unroll
            for (int b = 0; b < 4; ++b) {
                int r = orow + mf * 16 + b;
                if (r < N_NODES) {
                    float v = acc[mf][nf][b] + bvs;
                    if (RELU) v = fmaxf(v, 0.f);
                    if (STATS) { s[nf] += v; s2[nf] += v * v; }
                    if (OUTB)
                        ((ushort_t*)out)[(size_t)r * F + colg] = f2b(v);
                    else
                        ((float*)out)[(size_t)r * F + colg] = v;
                }
            }
        }
    }

    if constexpr (STATS) {
        __syncthreads();
        float* sdf = (float*)lds;
        const int u = (w >> 1) * 4 + q;         // 8 contributors per column
#pragma unroll
        for (int nf = 0; nf < 4; ++nf) {
            int cb = wc + nf * 16 + lr;
            sdf[u * 128 + cb] = s[nf];
            sdf[1024 + u * 128 + cb] = s2[nf];
        }
        __syncthreads();
        if (tid < 128) {
            float ss = 0.f, qq = 0.f;
#pragma unroll
            for (int u2 = 0; u2 < 8; ++u2) {
                ss += sdf[u2 * 128 + tid];
                qq += sdf[1024 + u2 * 128 + tid];
            }
            int cg = col0 + tid;
            partials[(size_t)cg * GXP + blockIdx.x] = ss;
            partials[(size_t)(F + cg) * GXP + blockIdx.x] = qq;
        }
    }
}

// ---------------- BN: reduce partials -> scale/shift ----------------

template<int F>
__global__ __launch_bounds__(64) void k_bn_scsh(
        const float* __restrict__ partials, const float* __restrict__ gamma,
        const float* __restrict__ beta, float* __restrict__ scsh, int GX) {
    const int c = blockIdx.x;
    const int l = threadIdx.x;
    float s = 0.f, q2 = 0.f;
    for (int g = l; g < GX; g += 64) {
        s += partials[(size_t)c * GXP + g];
        q2 += partials[(size_t)(F + c) * GXP + g];
    }
#pragma unroll
    for (int off = 1; off < 64; off <<= 1) {
        s += __shfl_xor(s, off);
        q2 += __shfl_xor(q2, off);
    }
    if (l == 0) {
        float mean = s * (1.0f / N_NODES);
        float var = q2 * (1.0f / N_NODES) - mean * mean;
        float sc = gamma[c] * rsqrtf(var + BN_EPS_F);
        scsh[c] = sc;
        scsh[F + c] = beta[c] - mean * sc;
    }
}

// ---------------- launch ----------------

extern "C" void kernel_launch(void* const* d_in, const int* in_sizes, int n_in,
                              void* d_out, int out_size, void* d_ws, size_t ws_size,
                              hipStream_t stream) {
    (void)in_sizes; (void)n_in; (void)out_size; (void)ws_size;
    const float* x   = (const float*)d_in[0];
    const int*   src = (const int*)d_in[1];
    const int*   dst = (const int*)d_in[2];
    const float* eps = (const float*)d_in[3];
    const float* W1l = (const float*)d_in[4];
    const float* W1r = (const float*)d_in[5];
    const float* b1  = (const float*)d_in[6];
    const float* g1  = (const float*)d_in[7];
    const float* be1 = (const float*)d_in[8];
    const float* W2l = (const float*)d_in[9];
    const float* W2r = (const float*)d_in[10];
    const float* b2  = (const float*)d_in[11];
    const float* g2  = (const float*)d_in[12];
    const float* be2 = (const float*)d_in[13];
    const float* W3l = (const float*)d_in[14];
    const float* W3r = (const float*)d_in[15];
    const float* b3  = (const float*)d_in[16];
    float* z = (float*)d_out;

    char* ws = (char*)d_ws;
    size_t off = 0;
    auto alloc = [&](size_t bytes) -> char* {
        char* p = ws + off;
        off += (bytes + 255) & ~(size_t)255;
        return p;
    };
    int*      deg    = (int*)alloc(N_NODES * 4);        // zeroed per call
    size_t zero_bytes = off;
    int*      rank   = (int*)alloc((size_t)N_EDGES * 4);
    float*    scshs  = (float*)alloc(1024 * 4);         // scsh1 (256) + scsh2 (512)
    float*    biases = (float*)alloc(512 * 4);          // bias2 (256) + bias3l (128) + bias3r (128)
    int*      offs   = (int*)alloc(N_NODES * 4);
    int*      bsum   = (int*)alloc(128 * 4);
    int*      eids   = (int*)alloc((size_t)N_EDGES * 4);
    float*    invd   = (float*)alloc(N_NODES * 4);
    ushort_t* xb     = (ushort_t*)alloc((size_t)N_NODES * 128 * 2);
    ushort_t* h1b    = (ushort_t*)alloc((size_t)N_NODES * 128 * 2);
    ushort_t* h2b    = (ushort_t*)alloc((size_t)N_NODES * 256 * 2);
    ushort_t* aggrb  = (ushort_t*)alloc((size_t)N_NODES * 256 * 2);   // layer-1/2 aggr; reused as t3
    float*    u3f    = (float*)alloc((size_t)N_NODES * 128 * 4);
    float*    parts  = (float*)alloc((size_t)512 * GXP * 4);          // [2F][GXP], F<=256
    ushort_t* wt1l   = (ushort_t*)alloc(128 * 128 * 2);
    ushort_t* wt1r   = (ushort_t*)alloc(128 * 128 * 2);
    ushort_t* wt2l   = (ushort_t*)alloc(256 * 128 * 2);
    ushort_t* wt2r   = (ushort_t*)alloc(256 * 128 * 2);
    ushort_t* wt3l   = (ushort_t*)alloc(128 * 256 * 2);
    ushort_t* wt3r   = (ushort_t*)alloc(128 * 256 * 2);
    ushort_t* t3b    = aggrb;   // layer-3: t3 (bf16 [N,128]); aggrb free by then

    float* scsh1  = scshs;            // [sc1(128) | sh1(128)]
    float* scsh2  = scshs + 256;      // [sc2(256) | sh2(256)]
    float* bias2  = biases;           // 256
    float* bias3l = biases + 256;     // 128
    float* bias3r = biases + 384;     // 128

    // CSR build: ONE atomic pass (countrank), then atomic-free scatter
    k_zero_i32<<<((int)(zero_bytes / 4) + 255) / 256, 256, 0, stream>>>((int*)ws, (int)(zero_bytes / 4));
    k_countrank<<<(N_EDGES + 255) / 256, 256, 0, stream>>>(dst, deg, rank);
    k_scan1<<<SCAN_NB, SCAN_BS, 0, stream>>>(deg, offs, bsum);
    k_scan2<<<1, 128, 0, stream>>>(bsum, SCAN_NB);
    k_scan3<<<(N_NODES + 255) / 256, 256, 0, stream>>>(deg, offs, bsum, invd);
    k_fill2<<<(N_EDGES + 255) / 256, 256, 0, stream>>>(src, dst, offs, rank, eids);

    // bf16 conversions + upfront weight transposes
    k_f2b8<<<(N_NODES * 128 / 8 + 255) / 256, 256, 0, stream>>>(x, xb, N_NODES * 128 / 8);
    k_prep1<<<256, 256, 0, stream>>>(W1l, W1r, W2l, wt1l, wt1r, wt2l);

    const int AGG_BLKS = (N_NODES + 3) / 4;   // one wave per node
    const int GX = (N_NODES + 127) / 128;     // 391

    // ---- Layer 1: SAGE(x) -> relu (+fused BN stats)  (K=128, F=128)
    k_agg16<0><<<AGG_BLKS, 256, 0, stream>>>(xb, eids, offs, deg, invd, nullptr, aggrb);
    k_gemm_mfma<1, 1, 1, 1, 1><<<dim3(GX, 1), 256, 0, stream>>>(aggrb, xb, wt1l, wt1r, b1, h1b, 128, 128, parts);
    k_bn_scsh<128><<<128, 64, 0, stream>>>(parts, g1, be1, scsh1, GX);

    // ---- Layer 2: BN1 absorbed (agg-side fused, self-side in wt2r/bias2)  (K=128, F=256)
    k_prep2<<<129, 256, 0, stream>>>(W2r, b2, scsh1, wt2r, bias2);
    k_agg16<1><<<AGG_BLKS, 256, 0, stream>>>(h1b, eids, offs, deg, invd, scsh1, aggrb);
    k_gemm_mfma<1, 1, 1, 1, 1><<<dim3(GX, 2), 256, 0, stream>>>(aggrb, h1b, wt2l, wt2r, bias2, h2b, 128, 256, parts);
    k_bn_scsh<256><<<256, 64, 0, stream>>>(parts, g2, be2, scsh2, GX);

    // ---- Layer 3 (commuted, BN2 absorbed into scaled weights + biases):
    //      t3 = h2raw@wt3l' + bias3l (bf16); u3 = h2raw@wt3r' + bias3r (fp32)
    //      z = (agg(t3)+u3)_m + exp((agg(t3)+u3)_ls)*eps
    k_prep3<<<257, 256, 0, stream>>>(W3l, W3r, b3, scsh2, wt3l, wt3r, bias3l, bias3r);
    k_gemm_mfma<0, 1, 0, 1, 0><<<dim3(GX, 1), 256, 0, stream>>>(h2b, nullptr, wt3l, nullptr, bias3l, t3b, 256, 128, nullptr);
    k_gemm_mfma<0, 0, 0, 1, 0><<<dim3(GX, 1), 256, 0, stream>>>(h2b, nullptr, wt3r, nullptr, bias3r, u3f, 256, 128, nullptr);
    k_agg_reparam<<<AGG_BLKS, 256, 0, stream>>>(t3b, eids, offs, deg, invd, u3f, eps, z);
}

// Round 7
// 269.863 us; speedup vs baseline: 3.0566x; 1.1097x over previous
//
#include <hip/hip_runtime.h>
#include <math.h>

#define N_NODES 50000
#define N_EDGES 800000
#define BN_EPS_F 1e-5f
#define SCAN_BS 512
#define SCAN_NB 98   // ceil(50000/512)
#define GXP 392      // padded partials stride (>= GX=391)

typedef unsigned short ushort_t;
typedef unsigned int uint_t;
typedef __attribute__((ext_vector_type(8))) short bf16x8;
typedef __attribute__((ext_vector_type(4))) float f32x4;

static __device__ __forceinline__ float4 ld4(const float* p) {
    return *reinterpret_cast<const float4*>(p);
}
static __device__ __forceinline__ float bf2f(ushort_t u) {
    return __uint_as_float(((uint_t)u) << 16);
}
static __device__ __forceinline__ ushort_t f2b(float f) {
    uint_t u = __float_as_uint(f);
    u += 0x7fffu + ((u >> 16) & 1u);
    return (ushort_t)(u >> 16);
}
static __device__ __forceinline__ void gload16(const void* g, void* l) {
    __builtin_amdgcn_global_load_lds(
        (const __attribute__((address_space(1))) void*)g,
        (__attribute__((address_space(3))) void*)l, 16, 0, 0);
}

// ---------------- CSR build ----------------

__global__ void k_zero_i32(int* __restrict__ p, int n) {
    int i = blockIdx.x * blockDim.x + threadIdx.x;
    if (i < n) p[i] = 0;
}

// fused: countrank (even blocks) + x->bf16 (odd blocks) + weight transposes (tail)
__global__ void k_pre(const int* __restrict__ dst, int* __restrict__ deg,
                      ushort_t* __restrict__ rank,
                      const float* __restrict__ x, ushort_t* __restrict__ xb,
                      const float* __restrict__ W1l, const float* __restrict__ W1r,
                      const float* __restrict__ W2l, ushort_t* __restrict__ wt1l,
                      ushort_t* __restrict__ wt1r, ushort_t* __restrict__ wt2l) {
    int b = blockIdx.x;
    if (b < 6250) {
        int role = b & 1;
        int id = (b >> 1) * 256 + threadIdx.x;   // < 800000 exact
        if (role == 0) {
            rank[id] = (ushort_t)atomicAdd(&deg[dst[id]], 1);
        } else {
            float4 a = ld4(x + (size_t)id * 8);
            float4 c = ld4(x + (size_t)id * 8 + 4);
            uint_t o0 = (uint_t)f2b(a.x) | ((uint_t)f2b(a.y) << 16);
            uint_t o1 = (uint_t)f2b(a.z) | ((uint_t)f2b(a.w) << 16);
            uint_t o2 = (uint_t)f2b(c.x) | ((uint_t)f2b(c.y) << 16);
            uint_t o3 = (uint_t)f2b(c.z) | ((uint_t)f2b(c.w) << 16);
            *reinterpret_cast<uint4*>(xb + (size_t)id * 8) = make_uint4(o0, o1, o2, o3);
        }
    } else {
        int idx = (b - 6250) * 256 + threadIdx.x;   // 0..65535
        if (idx < 16384) {
            int f = idx >> 7, k = idx & 127;
            wt1l[idx] = f2b(W1l[(size_t)k * 128 + f]);
        } else if (idx < 32768) {
            int j = idx - 16384;
            int f = j >> 7, k = j & 127;
            wt1r[j] = f2b(W1r[(size_t)k * 128 + f]);
        } else {
            int j = idx - 32768;                    // F=256 K=128
            int f = j >> 7, k = j & 127;
            wt2l[j] = f2b(W2l[(size_t)k * 256 + f]);
        }
    }
}

__global__ void k_scan1(const int* __restrict__ deg, int* __restrict__ offs, int* __restrict__ bsum) {
    __shared__ int sh[SCAN_BS];
    int t = threadIdx.x;
    int g = blockIdx.x * SCAN_BS + t;
    int v = (g < N_NODES) ? deg[g] : 0;
    sh[t] = v;
    __syncthreads();
    for (int off = 1; off < SCAN_BS; off <<= 1) {
        int add = (t >= off) ? sh[t - off] : 0;
        __syncthreads();
        sh[t] += add;
        __syncthreads();
    }
    if (g < N_NODES) offs[g] = sh[t] - v;
    if (t == SCAN_BS - 1) bsum[blockIdx.x] = sh[t];
}

__global__ void k_scan2(int* __restrict__ bsum, int nb) {
    __shared__ int sh[128];
    int t = threadIdx.x;
    int v = (t < nb) ? bsum[t] : 0;
    sh[t] = v;
    __syncthreads();
    for (int off = 1; off < 128; off <<= 1) {
        int add = (t >= off) ? sh[t - off] : 0;
        __syncthreads();
        sh[t] += add;
        __syncthreads();
    }
    if (t < nb) bsum[t] = sh[t] - v;
}

__global__ void k_scan3(const int* __restrict__ deg, int* __restrict__ offs,
                        const int* __restrict__ bsum, float* __restrict__ inv_deg) {
    int g = blockIdx.x * blockDim.x + threadIdx.x;
    if (g < N_NODES) {
        offs[g] += bsum[g / SCAN_BS];
        int d = deg[g];
        inv_deg[g] = 1.0f / (float)(d > 1 ? d : 1);
    }
}

// atomic-free scatter, ushort payload (halves writeback amplification)
__global__ void k_fill2(const int* __restrict__ src, const int* __restrict__ dst,
                        const int* __restrict__ offs, const ushort_t* __restrict__ rank,
                        ushort_t* __restrict__ eids) {
    int e = blockIdx.x * blockDim.x + threadIdx.x;
    if (e < N_EDGES) eids[offs[dst[e]] + (int)rank[e]] = (ushort_t)src[e];
}

// ---------------- late weight prep (need BN scsh) ----------------

// layer-2: wt2r[f*128+k] = sc1[k]*W2r[k][f]; bias2[f] = b2[f] + sum_k sh1[k]*W2r[k][f]
__global__ void k_prep2(const float* __restrict__ W2r, const float* __restrict__ b2,
                        const float* __restrict__ scsh1, ushort_t* __restrict__ wt2r,
                        float* __restrict__ bias2) {
    int bid = blockIdx.x;
    if (bid < 128) {
        int idx = bid * 256 + threadIdx.x;      // F=256 K=128
        int f = idx >> 7, k = idx & 127;
        wt2r[idx] = f2b(scsh1[k] * W2r[(size_t)k * 256 + f]);
    } else {
        int f = threadIdx.x;
        float s = b2[f];
        for (int k = 0; k < 128; ++k) s += scsh1[128 + k] * W2r[(size_t)k * 256 + f];
        bias2[f] = s;
    }
}

// layer-3: scaled transposes of W3l/W3r (256x128) + effective biases
__global__ void k_prep3(const float* __restrict__ W3l, const float* __restrict__ W3r,
                        const float* __restrict__ b3, const float* __restrict__ scsh2,
                        ushort_t* __restrict__ wt3l, ushort_t* __restrict__ wt3r,
                        float* __restrict__ bias3l, float* __restrict__ bias3r) {
    int bid = blockIdx.x;
    if (bid < 256) {
        int half = bid >> 7;
        int idx = (bid & 127) * 256 + threadIdx.x;   // F=128 K=256
        int f = idx >> 8, k = idx & 255;
        const float* W = half ? W3r : W3l;
        ushort_t* WT = half ? wt3r : wt3l;
        WT[idx] = f2b(scsh2[k] * W[(size_t)k * 128 + f]);
    } else {
        int t = threadIdx.x;
        int f = t & 127;
        const float* W = (t < 128) ? W3l : W3r;
        float s = (t < 128) ? 0.f : b3[f];
        for (int k = 0; k < 256; ++k) s += scsh2[256 + k] * W[(size_t)k * 128 + f];
        float* out = (t < 128) ? bias3l : bias3r;
        out[f] = s;
    }
}

// ---------------- gather core: F=128 bf16 rows, 16 lanes x 16B, 4 edge groups ----------------

#define ACCUM8(a) do { \
    acc[0] += bf2f((ushort_t)(a).x); acc[1] += bf2f((ushort_t)((a).x >> 16)); \
    acc[2] += bf2f((ushort_t)(a).y); acc[3] += bf2f((ushort_t)((a).y >> 16)); \
    acc[4] += bf2f((ushort_t)(a).z); acc[5] += bf2f((ushort_t)((a).z >> 16)); \
    acc[6] += bf2f((ushort_t)(a).w); acc[7] += bf2f((ushort_t)((a).w >> 16)); } while (0)

static __device__ __forceinline__ void gather_rows(
        const ushort_t* __restrict__ h, const ushort_t* __restrict__ eids,
        int beg, int d, int g, size_t coff, float* acc) {
    int j = 0;
    for (; j + 32 <= d; j += 32) {              // 8 edges per group in flight
        int s[8];
#pragma unroll
        for (int k = 0; k < 8; ++k) s[k] = eids[beg + j + k * 4 + g];
        uint4 a[8];
#pragma unroll
        for (int k = 0; k < 8; ++k) a[k] = *reinterpret_cast<const uint4*>(h + (size_t)s[k] * 128 + coff);
#pragma unroll
        for (int k = 0; k < 8; ++k) ACCUM8(a[k]);
    }
    for (; j + 16 <= d; j += 16) {
        int s[4];
#pragma unroll
        for (int k = 0; k < 4; ++k) s[k] = eids[beg + j + k * 4 + g];
        uint4 a[4];
#pragma unroll
        for (int k = 0; k < 4; ++k) a[k] = *reinterpret_cast<const uint4*>(h + (size_t)s[k] * 128 + coff);
#pragma unroll
        for (int k = 0; k < 4; ++k) ACCUM8(a[k]);
    }
    for (; j + 8 <= d; j += 8) {
        int s0 = eids[beg + j + g];
        int s1 = eids[beg + j + 4 + g];
        uint4 a = *reinterpret_cast<const uint4*>(h + (size_t)s0 * 128 + coff);
        uint4 b = *reinterpret_cast<const uint4*>(h + (size_t)s1 * 128 + coff);
        ACCUM8(a); ACCUM8(b);
    }
    for (; j < d; j += 4) {
        int e = j + g;
        if (e < d) {
            int s0 = eids[beg + e];
            uint4 a = *reinterpret_cast<const uint4*>(h + (size_t)s0 * 128 + coff);
            ACCUM8(a);
        }
    }
}

// mean aggregation, one wave per node. BN=1: fused y = d>0 ? mean*sc+sh : 0
template<int BN>
__global__ __launch_bounds__(256) void k_agg16(
        const ushort_t* __restrict__ h, const ushort_t* __restrict__ eids,
        const int* __restrict__ offs, const int* __restrict__ deg,
        const float* __restrict__ inv_deg, const float* __restrict__ scsh,
        ushort_t* __restrict__ out) {
    int node = (blockIdx.x * 256 + threadIdx.x) >> 6;
    int lane = threadIdx.x & 63;
    if (node >= N_NODES) return;
    const int g = lane >> 4;
    const int lr = lane & 15;
    float acc[8];
#pragma unroll
    for (int v = 0; v < 8; ++v) acc[v] = 0.f;
    const int beg = offs[node];
    const int d = deg[node];
    const size_t coff = (size_t)lr * 8;
    gather_rows(h, eids, beg, d, g, coff, acc);
#pragma unroll
    for (int v = 0; v < 8; ++v) acc[v] += __shfl_xor(acc[v], 16);
#pragma unroll
    for (int v = 0; v < 8; ++v) acc[v] += __shfl_xor(acc[v], 32);

    if (g == 0) {
        float sc = inv_deg[node];
        if (BN) {
            float4 sa0 = ld4(&scsh[lr * 8]), sa1 = ld4(&scsh[lr * 8 + 4]);
            float4 sb0 = ld4(&scsh[128 + lr * 8]), sb1 = ld4(&scsh[128 + lr * 8 + 4]);
            if (d > 0) {
                acc[0] = acc[0] * sc * sa0.x + sb0.x; acc[1] = acc[1] * sc * sa0.y + sb0.y;
                acc[2] = acc[2] * sc * sa0.z + sb0.z; acc[3] = acc[3] * sc * sa0.w + sb0.w;
                acc[4] = acc[4] * sc * sa1.x + sb1.x; acc[5] = acc[5] * sc * sa1.y + sb1.y;
                acc[6] = acc[6] * sc * sa1.z + sb1.z; acc[7] = acc[7] * sc * sa1.w + sb1.w;
            } else {
#pragma unroll
                for (int v = 0; v < 8; ++v) acc[v] = 0.f;
            }
        } else {
#pragma unroll
            for (int v = 0; v < 8; ++v) acc[v] *= sc;
        }
        uint4 o;
        o.x = (uint_t)f2b(acc[0]) | ((uint_t)f2b(acc[1]) << 16);
        o.y = (uint_t)f2b(acc[2]) | ((uint_t)f2b(acc[3]) << 16);
        o.z = (uint_t)f2b(acc[4]) | ((uint_t)f2b(acc[5]) << 16);
        o.w = (uint_t)f2b(acc[6]) | ((uint_t)f2b(acc[7]) << 16);
        *reinterpret_cast<uint4*>(out + (size_t)node * 128 + coff) = o;
    }
}

// fused layer-3 aggregate + reparameterize
__global__ __launch_bounds__(256) void k_agg_reparam(
        const ushort_t* __restrict__ t3, const ushort_t* __restrict__ eids,
        const int* __restrict__ offs, const int* __restrict__ deg,
        const float* __restrict__ inv_deg, const float* __restrict__ u,
        const float* __restrict__ eps, float* __restrict__ z) {
    int node = (blockIdx.x * 256 + threadIdx.x) >> 6;
    int lane = threadIdx.x & 63;
    if (node >= N_NODES) return;
    const int g = lane >> 4;
    const int lr = lane & 15;
    float acc[8];
#pragma unroll
    for (int v = 0; v < 8; ++v) acc[v] = 0.f;
    const int beg = offs[node];
    const int d = deg[node];
    const size_t coff = (size_t)lr * 8;
    gather_rows(t3, eids, beg, d, g, coff, acc);
#pragma unroll
    for (int v = 0; v < 8; ++v) acc[v] += __shfl_xor(acc[v], 16);
#pragma unroll
    for (int v = 0; v < 8; ++v) acc[v] += __shfl_xor(acc[v], 32);
    float ls[8];
#pragma unroll
    for (int v = 0; v < 8; ++v) ls[v] = __shfl_down(acc[v], 8);

    if (g == 0 && lr < 8) {
        float sc = inv_deg[node];
        const float* um = u + (size_t)node * 128 + lr * 8;
        const float* ul = u + (size_t)node * 128 + 64 + lr * 8;
        const float* ep = eps + (size_t)node * 64 + lr * 8;
        float4 um0 = ld4(um), um1 = ld4(um + 4);
        float4 ul0 = ld4(ul), ul1 = ld4(ul + 4);
        float4 e0 = ld4(ep), e1 = ld4(ep + 4);
        float4 o0, o1;
        o0.x = (acc[0] * sc + um0.x) + expf(ls[0] * sc + ul0.x) * e0.x;
        o0.y = (acc[1] * sc + um0.y) + expf(ls[1] * sc + ul0.y) * e0.y;
        o0.z = (acc[2] * sc + um0.z) + expf(ls[2] * sc + ul0.z) * e0.z;
        o0.w = (acc[3] * sc + um0.w) + expf(ls[3] * sc + ul0.w) * e0.w;
        o1.x = (acc[4] * sc + um1.x) + expf(ls[4] * sc + ul1.x) * e1.x;
        o1.y = (acc[5] * sc + um1.y) + expf(ls[5] * sc + ul1.y) * e1.y;
        o1.z = (acc[6] * sc + um1.z) + expf(ls[6] * sc + ul1.z) * e1.z;
        o1.w = (acc[7] * sc + um1.w) + expf(ls[7] * sc + ul1.w) * e1.w;
        float* zp = z + (size_t)node * 64 + lr * 8;
        *reinterpret_cast<float4*>(zp) = o0;
        *reinterpret_cast<float4*>(zp + 4) = o1;
    }
}

// ---------------- MFMA GEMM (+ fused BN stats / +SELY dual-output mode) ----------------
// out[M][F] = A1@B1' (+ A2@B2') (+ bias); B args are WT [F][K] bf16.
// SELY: blockIdx.y selects {B1,bias,out,bf16} (y=0) vs {B2,bias2,out2,fp32} (y=1), col0=0.

template<int RELU, int OUTB, int DUAL, int BIAS, int STATS, int SELY>
__global__ __launch_bounds__(256) void k_gemm_mfma(
        const ushort_t* __restrict__ A1, const ushort_t* __restrict__ A2,
        const ushort_t* __restrict__ B1, const ushort_t* __restrict__ B2,
        const float* __restrict__ bias, void* __restrict__ out,
        int K, int F, float* __restrict__ partials,
        const float* __restrict__ bias2, void* __restrict__ out2) {
    __shared__ __align__(16) short lds[8192];   // A: [0,4096), B: [4096,8192)
    const int tid = threadIdx.x;
    const int lane = tid & 63;
    const int w = tid >> 6;
    const int row0 = blockIdx.x * 128;
    const int col0 = SELY ? 0 : blockIdx.y * 128;
    const int wr = (w >> 1) * 64;
    const int wc = (w & 1) * 64;

    const ushort_t* __restrict__ B0 = (SELY && blockIdx.y) ? B2 : B1;
    const float* __restrict__ biasp = (SELY && blockIdx.y) ? bias2 : bias;
    void* __restrict__ outp = (SELY && blockIdx.y) ? out2 : out;
    const bool outb = SELY ? (blockIdx.y == 0) : (OUTB != 0);

    int rowA[2], slA[2];
#pragma unroll
    for (int p = 0; p < 2; ++p) {
        int c = (p * 4 + w) * 64 + lane;
        int r = c >> 2, sp = c & 3;
        rowA[p] = r;
        slA[p] = sp ^ ((r >> 1) & 3);
    }
    const int q = lane >> 4, lr = lane & 15;
    int aoff[4], boff[4];
#pragma unroll
    for (int f = 0; f < 4; ++f) {
        int ra = wr + f * 16 + lr;
        aoff[f] = ra * 32 + (q ^ ((ra >> 1) & 3)) * 8;
        int rb = wc + f * 16 + lr;
        boff[f] = 4096 + rb * 32 + (q ^ ((rb >> 1) & 3)) * 8;
    }

    f32x4 acc[4][4];
#pragma unroll
    for (int mf = 0; mf < 4; ++mf)
#pragma unroll
        for (int nf = 0; nf < 4; ++nf)
            acc[mf][nf] = (f32x4){0.f, 0.f, 0.f, 0.f};

    for (int m = 0; m < (DUAL ? 2 : 1); ++m) {
        const ushort_t* __restrict__ A = m ? A2 : A1;
        const ushort_t* __restrict__ B = m ? B2 : B0;
        for (int k0 = 0; k0 < K; k0 += 32) {
            __syncthreads();
#pragma unroll
            for (int p = 0; p < 2; ++p) {
                int gr = row0 + rowA[p];
                if (gr > N_NODES - 1) gr = N_NODES - 1;
                gload16(A + (size_t)gr * K + k0 + slA[p] * 8, &lds[(p * 4 + w) * 512]);
                int gc = col0 + rowA[p];
                gload16(B + (size_t)gc * K + k0 + slA[p] * 8, &lds[4096 + (p * 4 + w) * 512]);
            }
            asm volatile("s_waitcnt vmcnt(0)" ::: "memory");
            __syncthreads();
            bf16x8 av[4], bv[4];
#pragma unroll
            for (int f = 0; f < 4; ++f) {
                av[f] = *reinterpret_cast<const bf16x8*>(&lds[aoff[f]]);
                bv[f] = *reinterpret_cast<const bf16x8*>(&lds[boff[f]]);
            }
#pragma unroll
            for (int mf = 0; mf < 4; ++mf)
#pragma unroll
                for (int nf = 0; nf < 4; ++nf)
                    acc[mf][nf] = __builtin_amdgcn_mfma_f32_16x16x32_bf16(
                        av[mf], bv[nf], acc[mf][nf], 0, 0, 0);
        }
    }

    // epilogue: D lane map (m89): col = lane&15, row = (lane>>4)*4 + b
    const int orow = row0 + wr + q * 4;
    const int ocol = col0 + wc + lr;
    float s[4], s2[4];
#pragma unroll
    for (int nf = 0; nf < 4; ++nf) { s[nf] = 0.f; s2[nf] = 0.f; }
#pragma unroll
    for (int nf = 0; nf < 4; ++nf) {
        int colg = ocol + nf * 16;
        float bvs = BIAS ? biasp[colg] : 0.f;
#pragma unroll
        for (int mf = 0; mf < 4; ++mf) {
#pragma unroll
            for (int b = 0; b < 4; ++b) {
                int r = orow + mf * 16 + b;
                if (r < N_NODES) {
                    float v = acc[mf][nf][b] + bvs;
                    if (RELU) v = fmaxf(v, 0.f);
                    if (STATS) { s[nf] += v; s2[nf] += v * v; }
                    if (outb)
                        ((ushort_t*)outp)[(size_t)r * F + colg] = f2b(v);
                    else
                        ((float*)outp)[(size_t)r * F + colg] = v;
                }
            }
        }
    }

    if constexpr (STATS) {
        __syncthreads();
        float* sdf = (float*)lds;
        const int u = (w >> 1) * 4 + q;         // 8 contributors per column
#pragma unroll
        for (int nf = 0; nf < 4; ++nf) {
            int cb = wc + nf * 16 + lr;
            sdf[u * 128 + cb] = s[nf];
            sdf[1024 + u * 128 + cb] = s2[nf];
        }
        __syncthreads();
        if (tid < 128) {
            float ss = 0.f, qq = 0.f;
#pragma unroll
            for (int u2 = 0; u2 < 8; ++u2) {
                ss += sdf[u2 * 128 + tid];
                qq += sdf[1024 + u2 * 128 + tid];
            }
            int cg = col0 + tid;
            partials[(size_t)cg * GXP + blockIdx.x] = ss;
            partials[(size_t)(F + cg) * GXP + blockIdx.x] = qq;
        }
    }
}

// ---------------- BN: reduce partials -> scale/shift ----------------

template<int F>
__global__ __launch_bounds__(64) void k_bn_scsh(
        const float* __restrict__ partials, const float* __restrict__ gamma,
        const float* __restrict__ beta, float* __restrict__ scsh, int GX) {
    const int c = blockIdx.x;
    const int l = threadIdx.x;
    float s = 0.f, q2 = 0.f;
    for (int g = l; g < GX; g += 64) {
        s += partials[(size_t)c * GXP + g];
        q2 += partials[(size_t)(F + c) * GXP + g];
    }
#pragma unroll
    for (int off = 1; off < 64; off <<= 1) {
        s += __shfl_xor(s, off);
        q2 += __shfl_xor(q2, off);
    }
    if (l == 0) {
        float mean = s * (1.0f / N_NODES);
        float var = q2 * (1.0f / N_NODES) - mean * mean;
        float sc = gamma[c] * rsqrtf(var + BN_EPS_F);
        scsh[c] = sc;
        scsh[F + c] = beta[c] - mean * sc;
    }
}

// ---------------- launch ----------------

extern "C" void kernel_launch(void* const* d_in, const int* in_sizes, int n_in,
                              void* d_out, int out_size, void* d_ws, size_t ws_size,
                              hipStream_t stream) {
    (void)in_sizes; (void)n_in; (void)out_size; (void)ws_size;
    const float* x   = (const float*)d_in[0];
    const int*   src = (const int*)d_in[1];
    const int*   dst = (const int*)d_in[2];
    const float* eps = (const float*)d_in[3];
    const float* W1l = (const float*)d_in[4];
    const float* W1r = (const float*)d_in[5];
    const float* b1  = (const float*)d_in[6];
    const float* g1  = (const float*)d_in[7];
    const float* be1 = (const float*)d_in[8];
    const float* W2l = (const float*)d_in[9];
    const float* W2r = (const float*)d_in[10];
    const float* b2  = (const float*)d_in[11];
    const float* g2  = (const float*)d_in[12];
    const float* be2 = (const float*)d_in[13];
    const float* W3l = (const float*)d_in[14];
    const float* W3r = (const float*)d_in[15];
    const float* b3  = (const float*)d_in[16];
    float* z = (float*)d_out;

    char* ws = (char*)d_ws;
    size_t off = 0;
    auto alloc = [&](size_t bytes) -> char* {
        char* p = ws + off;
        off += (bytes + 255) & ~(size_t)255;
        return p;
    };
    int*      deg    = (int*)alloc(N_NODES * 4);        // zeroed per call
    size_t zero_bytes = off;
    ushort_t* rank   = (ushort_t*)alloc((size_t)N_EDGES * 2);
    ushort_t* eids   = (ushort_t*)alloc((size_t)N_EDGES * 2);
    float*    scshs  = (float*)alloc(1024 * 4);         // scsh1 (256) + scsh2 (512)
    float*    biases = (float*)alloc(512 * 4);          // bias2 (256) + bias3l (128) + bias3r (128)
    int*      offs   = (int*)alloc(N_NODES * 4);
    int*      bsum   = (int*)alloc(128 * 4);
    float*    invd   = (float*)alloc(N_NODES * 4);
    ushort_t* xb     = (ushort_t*)alloc((size_t)N_NODES * 128 * 2);
    ushort_t* h1b    = (ushort_t*)alloc((size_t)N_NODES * 128 * 2);
    ushort_t* h2b    = (ushort_t*)alloc((size_t)N_NODES * 256 * 2);
    ushort_t* aggrb  = (ushort_t*)alloc((size_t)N_NODES * 256 * 2);   // layer-1/2 aggr; reused as t3
    float*    u3f    = (float*)alloc((size_t)N_NODES * 128 * 4);
    float*    parts  = (float*)alloc((size_t)512 * GXP * 4);          // [2F][GXP], F<=256
    ushort_t* wt1l   = (ushort_t*)alloc(128 * 128 * 2);
    ushort_t* wt1r   = (ushort_t*)alloc(128 * 128 * 2);
    ushort_t* wt2l   = (ushort_t*)alloc(256 * 128 * 2);
    ushort_t* wt2r   = (ushort_t*)alloc(256 * 128 * 2);
    ushort_t* wt3l   = (ushort_t*)alloc(128 * 256 * 2);
    ushort_t* wt3r   = (ushort_t*)alloc(128 * 256 * 2);
    ushort_t* t3b    = aggrb;   // layer-3: t3 (bf16 [N,128]); aggrb free by then

    float* scsh1  = scshs;            // [sc1(128) | sh1(128)]
    float* scsh2  = scshs + 256;      // [sc2(256) | sh2(256)]
    float* bias2  = biases;           // 256
    float* bias3l = biases + 256;     // 128
    float* bias3r = biases + 384;     // 128

    // CSR build: zero deg, then ONE fused dispatch (atomics || x->bf16 || W transposes)
    k_zero_i32<<<((int)(zero_bytes / 4) + 255) / 256, 256, 0, stream>>>((int*)ws, (int)(zero_bytes / 4));
    k_pre<<<6506, 256, 0, stream>>>(dst, deg, rank, x, xb, W1l, W1r, W2l, wt1l, wt1r, wt2l);
    k_scan1<<<SCAN_NB, SCAN_BS, 0, stream>>>(deg, offs, bsum);
    k_scan2<<<1, 128, 0, stream>>>(bsum, SCAN_NB);
    k_scan3<<<(N_NODES + 255) / 256, 256, 0, stream>>>(deg, offs, bsum, invd);
    k_fill2<<<(N_EDGES + 255) / 256, 256, 0, stream>>>(src, dst, offs, rank, eids);

    const int AGG_BLKS = (N_NODES + 3) / 4;   // one wave per node
    const int GX = (N_NODES + 127) / 128;     // 391

    // ---- Layer 1: SAGE(x) -> relu (+fused BN stats)  (K=128, F=128)
    k_agg16<0><<<AGG_BLKS, 256, 0, stream>>>(xb, eids, offs, deg, invd, nullptr, aggrb);
    k_gemm_mfma<1, 1, 1, 1, 1, 0><<<dim3(GX, 1), 256, 0, stream>>>(aggrb, xb, wt1l, wt1r, b1, h1b, 128, 128, parts, nullptr, nullptr);
    k_bn_scsh<128><<<128, 64, 0, stream>>>(parts, g1, be1, scsh1, GX);

    // ---- Layer 2: BN1 absorbed (agg-side fused, self-side in wt2r/bias2)  (K=128, F=256)
    k_prep2<<<129, 256, 0, stream>>>(W2r, b2, scsh1, wt2r, bias2);
    k_agg16<1><<<AGG_BLKS, 256, 0, stream>>>(h1b, eids, offs, deg, invd, scsh1, aggrb);
    k_gemm_mfma<1, 1, 1, 1, 1, 0><<<dim3(GX, 2), 256, 0, stream>>>(aggrb, h1b, wt2l, wt2r, bias2, h2b, 128, 256, parts, nullptr, nullptr);
    k_bn_scsh<256><<<256, 64, 0, stream>>>(parts, g2, be2, scsh2, GX);

    // ---- Layer 3 (commuted, BN2 absorbed): ONE dispatch computes both
    //      y=0: t3 = h2raw@wt3l' + bias3l (bf16); y=1: u3 = h2raw@wt3r' + bias3r (fp32)
    k_prep3<<<257, 256, 0, stream>>>(W3l, W3r, b3, scsh2, wt3l, wt3r, bias3l, bias3r);
    k_gemm_mfma<0, 1, 0, 1, 0, 1><<<dim3(GX, 2), 256, 0, stream>>>(h2b, nullptr, wt3l, wt3r, bias3l, t3b, 256, 128, nullptr, bias3r, u3f);
    k_agg_reparam<<<AGG_BLKS, 256, 0, stream>>>(t3b, eids, offs, deg, invd, u3f, eps, z);
}

// Round 8
// 258.096 us; speedup vs baseline: 3.1960x; 1.0456x over previous
//
#include <hip/hip_runtime.h>
#include <math.h>

#define N_NODES 50000
#define N_EDGES 800000
#define BN_EPS_F 1e-5f
#define SCAN_BS 512
#define SCAN_NB 98   // ceil(50000/512)
#define GXP 392      // padded partials stride (>= GX=391)

typedef unsigned short ushort_t;
typedef unsigned int uint_t;
typedef __attribute__((ext_vector_type(8))) short bf16x8;
typedef __attribute__((ext_vector_type(4))) float f32x4;

static __device__ __forceinline__ float4 ld4(const float* p) {
    return *reinterpret_cast<const float4*>(p);
}
static __device__ __forceinline__ float bf2f(ushort_t u) {
    return __uint_as_float(((uint_t)u) << 16);
}
static __device__ __forceinline__ ushort_t f2b(float f) {
    uint_t u = __float_as_uint(f);
    u += 0x7fffu + ((u >> 16) & 1u);
    return (ushort_t)(u >> 16);
}
static __device__ __forceinline__ void gload16(const void* g, void* l) {
    __builtin_amdgcn_global_load_lds(
        (const __attribute__((address_space(1))) void*)g,
        (__attribute__((address_space(3))) void*)l, 16, 0, 0);
}

// ---------------- CSR build ----------------

__global__ void k_zero_i32(int* __restrict__ p, int n) {
    int i = blockIdx.x * blockDim.x + threadIdx.x;
    if (i < n) p[i] = 0;
}

// fused: countrank (even blocks) + x->bf16 (odd blocks) + weight transposes (tail)
__global__ void k_pre(const int* __restrict__ dst, int* __restrict__ deg,
                      ushort_t* __restrict__ rank,
                      const float* __restrict__ x, ushort_t* __restrict__ xb,
                      const float* __restrict__ W1l, const float* __restrict__ W1r,
                      const float* __restrict__ W2l, ushort_t* __restrict__ wt1l,
                      ushort_t* __restrict__ wt1r, ushort_t* __restrict__ wt2l) {
    int b = blockIdx.x;
    if (b < 6250) {
        int role = b & 1;
        int id = (b >> 1) * 256 + threadIdx.x;   // < 800000 exact
        if (role == 0) {
            rank[id] = (ushort_t)atomicAdd(&deg[dst[id]], 1);
        } else {
            float4 a = ld4(x + (size_t)id * 8);
            float4 c = ld4(x + (size_t)id * 8 + 4);
            uint_t o0 = (uint_t)f2b(a.x) | ((uint_t)f2b(a.y) << 16);
            uint_t o1 = (uint_t)f2b(a.z) | ((uint_t)f2b(a.w) << 16);
            uint_t o2 = (uint_t)f2b(c.x) | ((uint_t)f2b(c.y) << 16);
            uint_t o3 = (uint_t)f2b(c.z) | ((uint_t)f2b(c.w) << 16);
            *reinterpret_cast<uint4*>(xb + (size_t)id * 8) = make_uint4(o0, o1, o2, o3);
        }
    } else {
        int idx = (b - 6250) * 256 + threadIdx.x;   // 0..65535
        if (idx < 16384) {
            int f = idx >> 7, k = idx & 127;
            wt1l[idx] = f2b(W1l[(size_t)k * 128 + f]);
        } else if (idx < 32768) {
            int j = idx - 16384;
            int f = j >> 7, k = j & 127;
            wt1r[j] = f2b(W1r[(size_t)k * 128 + f]);
        } else {
            int j = idx - 32768;                    // F=256 K=128
            int f = j >> 7, k = j & 127;
            wt2l[j] = f2b(W2l[(size_t)k * 256 + f]);
        }
    }
}

__global__ void k_scan1(const int* __restrict__ deg, int* __restrict__ offs, int* __restrict__ bsum) {
    __shared__ int sh[SCAN_BS];
    int t = threadIdx.x;
    int g = blockIdx.x * SCAN_BS + t;
    int v = (g < N_NODES) ? deg[g] : 0;
    sh[t] = v;
    __syncthreads();
    for (int off = 1; off < SCAN_BS; off <<= 1) {
        int add = (t >= off) ? sh[t - off] : 0;
        __syncthreads();
        sh[t] += add;
        __syncthreads();
    }
    if (g < N_NODES) offs[g] = sh[t] - v;
    if (t == SCAN_BS - 1) bsum[blockIdx.x] = sh[t];
}

__global__ void k_scan2(int* __restrict__ bsum, int nb) {
    __shared__ int sh[128];
    int t = threadIdx.x;
    int v = (t < nb) ? bsum[t] : 0;
    sh[t] = v;
    __syncthreads();
    for (int off = 1; off < 128; off <<= 1) {
        int add = (t >= off) ? sh[t - off] : 0;
        __syncthreads();
        sh[t] += add;
        __syncthreads();
    }
    if (t < nb) bsum[t] = sh[t] - v;
}

__global__ void k_scan3(const int* __restrict__ deg, int* __restrict__ offs,
                        const int* __restrict__ bsum, float* __restrict__ inv_deg) {
    int g = blockIdx.x * blockDim.x + threadIdx.x;
    if (g < N_NODES) {
        offs[g] += bsum[g / SCAN_BS];
        int d = deg[g];
        inv_deg[g] = 1.0f / (float)(d > 1 ? d : 1);
    }
}

// atomic-free scatter, ushort payload
__global__ void k_fill2(const int* __restrict__ src, const int* __restrict__ dst,
                        const int* __restrict__ offs, const ushort_t* __restrict__ rank,
                        ushort_t* __restrict__ eids) {
    int e = blockIdx.x * blockDim.x + threadIdx.x;
    if (e < N_EDGES) eids[offs[dst[e]] + (int)rank[e]] = (ushort_t)src[e];
}

// ---------------- late weight prep (need BN scsh) ----------------

__global__ void k_prep2(const float* __restrict__ W2r, const float* __restrict__ b2,
                        const float* __restrict__ scsh1, ushort_t* __restrict__ wt2r,
                        float* __restrict__ bias2) {
    int bid = blockIdx.x;
    if (bid < 128) {
        int idx = bid * 256 + threadIdx.x;      // F=256 K=128
        int f = idx >> 7, k = idx & 127;
        wt2r[idx] = f2b(scsh1[k] * W2r[(size_t)k * 256 + f]);
    } else {
        int f = threadIdx.x;
        float s = b2[f];
        for (int k = 0; k < 128; ++k) s += scsh1[128 + k] * W2r[(size_t)k * 256 + f];
        bias2[f] = s;
    }
}

__global__ void k_prep3(const float* __restrict__ W3l, const float* __restrict__ W3r,
                        const float* __restrict__ b3, const float* __restrict__ scsh2,
                        ushort_t* __restrict__ wt3l, ushort_t* __restrict__ wt3r,
                        float* __restrict__ bias3l, float* __restrict__ bias3r) {
    int bid = blockIdx.x;
    if (bid < 256) {
        int half = bid >> 7;
        int idx = (bid & 127) * 256 + threadIdx.x;   // F=128 K=256
        int f = idx >> 8, k = idx & 255;
        const float* W = half ? W3r : W3l;
        ushort_t* WT = half ? wt3r : wt3l;
        WT[idx] = f2b(scsh2[k] * W[(size_t)k * 128 + f]);
    } else {
        int t = threadIdx.x;
        int f = t & 127;
        const float* W = (t < 128) ? W3l : W3r;
        float s = (t < 128) ? 0.f : b3[f];
        for (int k = 0; k < 256; ++k) s += scsh2[256 + k] * W[(size_t)k * 128 + f];
        float* out = (t < 128) ? bias3l : bias3r;
        out[f] = s;
    }
}

// ---------------- gather core: one 16-lane GROUP per node, 8-deep pipeline ----------------

#define ACCUM8(a) do { \
    acc[0] += bf2f((ushort_t)(a).x); acc[1] += bf2f((ushort_t)((a).x >> 16)); \
    acc[2] += bf2f((ushort_t)(a).y); acc[3] += bf2f((ushort_t)((a).y >> 16)); \
    acc[4] += bf2f((ushort_t)(a).z); acc[5] += bf2f((ushort_t)((a).z >> 16)); \
    acc[6] += bf2f((ushort_t)(a).w); acc[7] += bf2f((ushort_t)((a).w >> 16)); } while (0)

// each of the 16 lanes of a group owns a 16B column slice (coff) of F=128 bf16 rows
static __device__ __forceinline__ void gather_rows_g(
        const ushort_t* __restrict__ h, const ushort_t* __restrict__ eids,
        int beg, int d, size_t coff, float* acc) {
    int j = 0;
    for (; j + 8 <= d; j += 8) {
        uint4 a[8];
#pragma unroll
        for (int k = 0; k < 8; ++k) {
            int s = eids[beg + j + k];
            a[k] = *reinterpret_cast<const uint4*>(h + (size_t)s * 128 + coff);
        }
#pragma unroll
        for (int k = 0; k < 8; ++k) ACCUM8(a[k]);
    }
    for (; j + 4 <= d; j += 4) {
        uint4 a[4];
#pragma unroll
        for (int k = 0; k < 4; ++k) {
            int s = eids[beg + j + k];
            a[k] = *reinterpret_cast<const uint4*>(h + (size_t)s * 128 + coff);
        }
#pragma unroll
        for (int k = 0; k < 4; ++k) ACCUM8(a[k]);
    }
    for (; j + 2 <= d; j += 2) {
        int s0 = eids[beg + j];
        int s1 = eids[beg + j + 1];
        uint4 a = *reinterpret_cast<const uint4*>(h + (size_t)s0 * 128 + coff);
        uint4 b = *reinterpret_cast<const uint4*>(h + (size_t)s1 * 128 + coff);
        ACCUM8(a); ACCUM8(b);
    }
    if (j < d) {
        int s0 = eids[beg + j];
        uint4 a = *reinterpret_cast<const uint4*>(h + (size_t)s0 * 128 + coff);
        ACCUM8(a);
    }
}

// mean aggregation, one 16-lane group per node (16 nodes/block). BN=1: y = d>0 ? mean*sc+sh : 0
template<int BN>
__global__ __launch_bounds__(256) void k_agg16(
        const ushort_t* __restrict__ h, const ushort_t* __restrict__ eids,
        const int* __restrict__ offs, const int* __restrict__ deg,
        const float* __restrict__ inv_deg, const float* __restrict__ scsh,
        ushort_t* __restrict__ out) {
    const int node = blockIdx.x * 16 + (threadIdx.x >> 4);
    const int lr = threadIdx.x & 15;
    if (node >= N_NODES) return;
    float acc[8];
#pragma unroll
    for (int v = 0; v < 8; ++v) acc[v] = 0.f;
    const int beg = offs[node];
    const int d = deg[node];
    const size_t coff = (size_t)lr * 8;
    gather_rows_g(h, eids, beg, d, coff, acc);

    float sc = inv_deg[node];
    if (BN) {
        float4 sa0 = ld4(&scsh[lr * 8]), sa1 = ld4(&scsh[lr * 8 + 4]);
        float4 sb0 = ld4(&scsh[128 + lr * 8]), sb1 = ld4(&scsh[128 + lr * 8 + 4]);
        if (d > 0) {
            acc[0] = acc[0] * sc * sa0.x + sb0.x; acc[1] = acc[1] * sc * sa0.y + sb0.y;
            acc[2] = acc[2] * sc * sa0.z + sb0.z; acc[3] = acc[3] * sc * sa0.w + sb0.w;
            acc[4] = acc[4] * sc * sa1.x + sb1.x; acc[5] = acc[5] * sc * sa1.y + sb1.y;
            acc[6] = acc[6] * sc * sa1.z + sb1.z; acc[7] = acc[7] * sc * sa1.w + sb1.w;
        } else {
#pragma unroll
            for (int v = 0; v < 8; ++v) acc[v] = 0.f;
        }
    } else {
#pragma unroll
        for (int v = 0; v < 8; ++v) acc[v] *= sc;
    }
    uint4 o;
    o.x = (uint_t)f2b(acc[0]) | ((uint_t)f2b(acc[1]) << 16);
    o.y = (uint_t)f2b(acc[2]) | ((uint_t)f2b(acc[3]) << 16);
    o.z = (uint_t)f2b(acc[4]) | ((uint_t)f2b(acc[5]) << 16);
    o.w = (uint_t)f2b(acc[6]) | ((uint_t)f2b(acc[7]) << 16);
    *reinterpret_cast<uint4*>(out + (size_t)node * 128 + coff) = o;
}

// fused layer-3 aggregate + reparameterize; u is bf16 [N,128]
__global__ __launch_bounds__(256) void k_agg_reparam(
        const ushort_t* __restrict__ t3, const ushort_t* __restrict__ eids,
        const int* __restrict__ offs, const int* __restrict__ deg,
        const float* __restrict__ inv_deg, const ushort_t* __restrict__ u,
        const float* __restrict__ eps, float* __restrict__ z) {
    const int node = blockIdx.x * 16 + (threadIdx.x >> 4);
    const int lr = threadIdx.x & 15;
    if (node >= N_NODES) return;
    float acc[8];
#pragma unroll
    for (int v = 0; v < 8; ++v) acc[v] = 0.f;
    const int beg = offs[node];
    const int d = deg[node];
    const size_t coff = (size_t)lr * 8;
    gather_rows_g(t3, eids, beg, d, coff, acc);
    // lanes lr<8 hold mean cols, lr>=8 hold logstd cols; pull partner's sums
    float ls[8];
#pragma unroll
    for (int v = 0; v < 8; ++v) ls[v] = __shfl_down(acc[v], 8);

    if (lr < 8) {
        float sc = inv_deg[node];
        uint4 um4 = *reinterpret_cast<const uint4*>(u + (size_t)node * 128 + lr * 8);
        uint4 ul4 = *reinterpret_cast<const uint4*>(u + (size_t)node * 128 + 64 + lr * 8);
        const float* ep = eps + (size_t)node * 64 + lr * 8;
        float4 e0 = ld4(ep), e1 = ld4(ep + 4);
        float um[8], ul[8];
        um[0] = bf2f((ushort_t)um4.x); um[1] = bf2f((ushort_t)(um4.x >> 16));
        um[2] = bf2f((ushort_t)um4.y); um[3] = bf2f((ushort_t)(um4.y >> 16));
        um[4] = bf2f((ushort_t)um4.z); um[5] = bf2f((ushort_t)(um4.z >> 16));
        um[6] = bf2f((ushort_t)um4.w); um[7] = bf2f((ushort_t)(um4.w >> 16));
        ul[0] = bf2f((ushort_t)ul4.x); ul[1] = bf2f((ushort_t)(ul4.x >> 16));
        ul[2] = bf2f((ushort_t)ul4.y); ul[3] = bf2f((ushort_t)(ul4.y >> 16));
        ul[4] = bf2f((ushort_t)ul4.z); ul[5] = bf2f((ushort_t)(ul4.z >> 16));
        ul[6] = bf2f((ushort_t)ul4.w); ul[7] = bf2f((ushort_t)(ul4.w >> 16));
        float4 o0, o1;
        o0.x = (acc[0] * sc + um[0]) + expf(ls[0] * sc + ul[0]) * e0.x;
        o0.y = (acc[1] * sc + um[1]) + expf(ls[1] * sc + ul[1]) * e0.y;
        o0.z = (acc[2] * sc + um[2]) + expf(ls[2] * sc + ul[2]) * e0.z;
        o0.w = (acc[3] * sc + um[3]) + expf(ls[3] * sc + ul[3]) * e0.w;
        o1.x = (acc[4] * sc + um[4]) + expf(ls[4] * sc + ul[4]) * e1.x;
        o1.y = (acc[5] * sc + um[5]) + expf(ls[5] * sc + ul[5]) * e1.y;
        o1.z = (acc[6] * sc + um[6]) + expf(ls[6] * sc + ul[6]) * e1.z;
        o1.w = (acc[7] * sc + um[7]) + expf(ls[7] * sc + ul[7]) * e1.w;
        float* zp = z + (size_t)node * 64 + lr * 8;
        *reinterpret_cast<float4*>(zp) = o0;
        *reinterpret_cast<float4*>(zp + 4) = o1;
    }
}

// ---------------- MFMA GEMM (+ fused BN stats / +SELY dual-output mode) ----------------
// out[M][F] = A1@B1' (+ A2@B2') (+ bias); B args are WT [F][K] bf16.
// SELY: blockIdx.y selects {B1,bias,out} (y=0) vs {B2,bias2,out2} (y=1); both bf16, col0=0.

template<int RELU, int OUTB, int DUAL, int BIAS, int STATS, int SELY>
__global__ __launch_bounds__(256) void k_gemm_mfma(
        const ushort_t* __restrict__ A1, const ushort_t* __restrict__ A2,
        const ushort_t* __restrict__ B1, const ushort_t* __restrict__ B2,
        const float* __restrict__ bias, void* __restrict__ out,
        int K, int F, float* __restrict__ partials,
        const float* __restrict__ bias2, void* __restrict__ out2) {
    __shared__ __align__(16) short lds[8192];   // A: [0,4096), B: [4096,8192)
    const int tid = threadIdx.x;
    const int lane = tid & 63;
    const int w = tid >> 6;
    const int row0 = blockIdx.x * 128;
    const int col0 = SELY ? 0 : blockIdx.y * 128;
    const int wr = (w >> 1) * 64;
    const int wc = (w & 1) * 64;

    const ushort_t* __restrict__ B0 = (SELY && blockIdx.y) ? B2 : B1;
    const float* __restrict__ biasp = (SELY && blockIdx.y) ? bias2 : bias;
    void* __restrict__ outp = (SELY && blockIdx.y) ? out2 : out;

    int rowA[2], slA[2];
#pragma unroll
    for (int p = 0; p < 2; ++p) {
        int c = (p * 4 + w) * 64 + lane;
        int r = c >> 2, sp = c & 3;
        rowA[p] = r;
        slA[p] = sp ^ ((r >> 1) & 3);
    }
    const int q = lane >> 4, lr = lane & 15;
    int aoff[4], boff[4];
#pragma unroll
    for (int f = 0; f < 4; ++f) {
        int ra = wr + f * 16 + lr;
        aoff[f] = ra * 32 + (q ^ ((ra >> 1) & 3)) * 8;
        int rb = wc + f * 16 + lr;
        boff[f] = 4096 + rb * 32 + (q ^ ((rb >> 1) & 3)) * 8;
    }

    f32x4 acc[4][4];
#pragma unroll
    for (int mf = 0; mf < 4; ++mf)
#pragma unroll
        for (int nf = 0; nf < 4; ++nf)
            acc[mf][nf] = (f32x4){0.f, 0.f, 0.f, 0.f};

    for (int m = 0; m < (DUAL ? 2 : 1); ++m) {
        const ushort_t* __restrict__ A = m ? A2 : A1;
        const ushort_t* __restrict__ B = m ? B2 : B0;
        for (int k0 = 0; k0 < K; k0 += 32) {
            __syncthreads();
#pragma unroll
            for (int p = 0; p < 2; ++p) {
                int gr = row0 + rowA[p];
                if (gr > N_NODES - 1) gr = N_NODES - 1;
                gload16(A + (size_t)gr * K + k0 + slA[p] * 8, &lds[(p * 4 + w) * 512]);
                int gc = col0 + rowA[p];
                gload16(B + (size_t)gc * K + k0 + slA[p] * 8, &lds[4096 + (p * 4 + w) * 512]);
            }
            asm volatile("s_waitcnt vmcnt(0)" ::: "memory");
            __syncthreads();
            bf16x8 av[4], bv[4];
#pragma unroll
            for (int f = 0; f < 4; ++f) {
                av[f] = *reinterpret_cast<const bf16x8*>(&lds[aoff[f]]);
                bv[f] = *reinterpret_cast<const bf16x8*>(&lds[boff[f]]);
            }
#pragma unroll
            for (int mf = 0; mf < 4; ++mf)
#pragma unroll
                for (int nf = 0; nf < 4; ++nf)
                    acc[mf][nf] = __builtin_amdgcn_mfma_f32_16x16x32_bf16(
                        av[mf], bv[nf], acc[mf][nf], 0, 0, 0);
        }
    }

    // epilogue: D lane map (m89): col = lane&15, row = (lane>>4)*4 + b
    const int orow = row0 + wr + q * 4;
    const int ocol = col0 + wc + lr;
    float s[4], s2[4];
#pragma unroll
    for (int nf = 0; nf < 4; ++nf) { s[nf] = 0.f; s2[nf] = 0.f; }
#pragma unroll
    for (int nf = 0; nf < 4; ++nf) {
        int colg = ocol + nf * 16;
        float bvs = BIAS ? biasp[colg] : 0.f;
#pragma unroll
        for (int mf = 0; mf < 4; ++mf) {
#pragma unroll
            for (int b = 0; b < 4; ++b) {
                int r = orow + mf * 16 + b;
                if (r < N_NODES) {
                    float v = acc[mf][nf][b] + bvs;
                    if (RELU) v = fmaxf(v, 0.f);
                    if (STATS) { s[nf] += v; s2[nf] += v * v; }
                    if (OUTB)
                        ((ushort_t*)outp)[(size_t)r * F + colg] = f2b(v);
                    else
                        ((float*)outp)[(size_t)r * F + colg] = v;
                }
            }
        }
    }

    if constexpr (STATS) {
        __syncthreads();
        float* sdf = (float*)lds;
        const int u = (w >> 1) * 4 + q;         // 8 contributors per column
#pragma unroll
        for (int nf = 0; nf < 4; ++nf) {
            int cb = wc + nf * 16 + lr;
            sdf[u * 128 + cb] = s[nf];
            sdf[1024 + u * 128 + cb] = s2[nf];
        }
        __syncthreads();
        if (tid < 128) {
            float ss = 0.f, qq = 0.f;
#pragma unroll
            for (int u2 = 0; u2 < 8; ++u2) {
                ss += sdf[u2 * 128 + tid];
                qq += sdf[1024 + u2 * 128 + tid];
            }
            int cg = col0 + tid;
            partials[(size_t)cg * GXP + blockIdx.x] = ss;
            partials[(size_t)(F + cg) * GXP + blockIdx.x] = qq;
        }
    }
}

// ---------------- BN: reduce partials -> scale/shift ----------------

template<int F>
__global__ __launch_bounds__(64) void k_bn_scsh(
        const float* __restrict__ partials, const float* __restrict__ gamma,
        const float* __restrict__ beta, float* __restrict__ scsh, int GX) {
    const int c = blockIdx.x;
    const int l = threadIdx.x;
    float s = 0.f, q2 = 0.f;
    for (int g = l; g < GX; g += 64) {
        s += partials[(size_t)c * GXP + g];
        q2 += partials[(size_t)(F + c) * GXP + g];
    }
#pragma unroll
    for (int off = 1; off < 64; off <<= 1) {
        s += __shfl_xor(s, off);
        q2 += __shfl_xor(q2, off);
    }
    if (l == 0) {
        float mean = s * (1.0f / N_NODES);
        float var = q2 * (1.0f / N_NODES) - mean * mean;
        float sc = gamma[c] * rsqrtf(var + BN_EPS_F);
        scsh[c] = sc;
        scsh[F + c] = beta[c] - mean * sc;
    }
}

// ---------------- launch ----------------

extern "C" void kernel_launch(void* const* d_in, const int* in_sizes, int n_in,
                              void* d_out, int out_size, void* d_ws, size_t ws_size,
                              hipStream_t stream) {
    (void)in_sizes; (void)n_in; (void)out_size; (void)ws_size;
    const float* x   = (const float*)d_in[0];
    const int*   src = (const int*)d_in[1];
    const int*   dst = (const int*)d_in[2];
    const float* eps = (const float*)d_in[3];
    const float* W1l = (const float*)d_in[4];
    const float* W1r = (const float*)d_in[5];
    const float* b1  = (const float*)d_in[6];
    const float* g1  = (const float*)d_in[7];
    const float* be1 = (const float*)d_in[8];
    const float* W2l = (const float*)d_in[9];
    const float* W2r = (const float*)d_in[10];
    const float* b2  = (const float*)d_in[11];
    const float* g2  = (const float*)d_in[12];
    const float* be2 = (const float*)d_in[13];
    const float* W3l = (const float*)d_in[14];
    const float* W3r = (const float*)d_in[15];
    const float* b3  = (const float*)d_in[16];
    float* z = (float*)d_out;

    char* ws = (char*)d_ws;
    size_t off = 0;
    auto alloc = [&](size_t bytes) -> char* {
        char* p = ws + off;
        off += (bytes + 255) & ~(size_t)255;
        return p;
    };
    int*      deg    = (int*)alloc(N_NODES * 4);        // zeroed per call
    size_t zero_bytes = off;
    ushort_t* rank   = (ushort_t*)alloc((size_t)N_EDGES * 2);
    ushort_t* eids   = (ushort_t*)alloc((size_t)N_EDGES * 2);
    float*    scshs  = (float*)alloc(1024 * 4);         // scsh1 (256) + scsh2 (512)
    float*    biases = (float*)alloc(512 * 4);          // bias2 (256) + bias3l (128) + bias3r (128)
    int*      offs   = (int*)alloc(N_NODES * 4);
    int*      bsum   = (int*)alloc(128 * 4);
    float*    invd   = (float*)alloc(N_NODES * 4);
    ushort_t* xb     = (ushort_t*)alloc((size_t)N_NODES * 128 * 2);
    ushort_t* h1b    = (ushort_t*)alloc((size_t)N_NODES * 128 * 2);
    ushort_t* h2b    = (ushort_t*)alloc((size_t)N_NODES * 256 * 2);
    ushort_t* aggrb  = (ushort_t*)alloc((size_t)N_NODES * 256 * 2);   // layer-1/2 aggr; reused as t3
    ushort_t* u3b    = (ushort_t*)alloc((size_t)N_NODES * 128 * 2);
    float*    parts  = (float*)alloc((size_t)512 * GXP * 4);          // [2F][GXP], F<=256
    ushort_t* wt1l   = (ushort_t*)alloc(128 * 128 * 2);
    ushort_t* wt1r   = (ushort_t*)alloc(128 * 128 * 2);
    ushort_t* wt2l   = (ushort_t*)alloc(256 * 128 * 2);
    ushort_t* wt2r   = (ushort_t*)alloc(256 * 128 * 2);
    ushort_t* wt3l   = (ushort_t*)alloc(128 * 256 * 2);
    ushort_t* wt3r   = (ushort_t*)alloc(128 * 256 * 2);
    ushort_t* t3b    = aggrb;   // layer-3: t3 (bf16 [N,128]); aggrb free by then

    float* scsh1  = scshs;            // [sc1(128) | sh1(128)]
    float* scsh2  = scshs + 256;      // [sc2(256) | sh2(256)]
    float* bias2  = biases;           // 256
    float* bias3l = biases + 256;     // 128
    float* bias3r = biases + 384;     // 128

    // CSR build: zero deg, then ONE fused dispatch (atomics || x->bf16 || W transposes)
    k_zero_i32<<<((int)(zero_bytes / 4) + 255) / 256, 256, 0, stream>>>((int*)ws, (int)(zero_bytes / 4));
    k_pre<<<6506, 256, 0, stream>>>(dst, deg, rank, x, xb, W1l, W1r, W2l, wt1l, wt1r, wt2l);
    k_scan1<<<SCAN_NB, SCAN_BS, 0, stream>>>(deg, offs, bsum);
    k_scan2<<<1, 128, 0, stream>>>(bsum, SCAN_NB);
    k_scan3<<<(N_NODES + 255) / 256, 256, 0, stream>>>(deg, offs, bsum, invd);
    k_fill2<<<(N_EDGES + 255) / 256, 256, 0, stream>>>(src, dst, offs, rank, eids);

    const int AGG_BLKS = N_NODES / 16;        // 3125: one 16-lane group per node
    const int GX = (N_NODES + 127) / 128;     // 391

    // ---- Layer 1: SAGE(x) -> relu (+fused BN stats)  (K=128, F=128)
    k_agg16<0><<<AGG_BLKS, 256, 0, stream>>>(xb, eids, offs, deg, invd, nullptr, aggrb);
    k_gemm_mfma<1, 1, 1, 1, 1, 0><<<dim3(GX, 1), 256, 0, stream>>>(aggrb, xb, wt1l, wt1r, b1, h1b, 128, 128, parts, nullptr, nullptr);
    k_bn_scsh<128><<<128, 64, 0, stream>>>(parts, g1, be1, scsh1, GX);

    // ---- Layer 2: BN1 absorbed (agg-side fused, self-side in wt2r/bias2)  (K=128, F=256)
    k_prep2<<<129, 256, 0, stream>>>(W2r, b2, scsh1, wt2r, bias2);
    k_agg16<1><<<AGG_BLKS, 256, 0, stream>>>(h1b, eids, offs, deg, invd, scsh1, aggrb);
    k_gemm_mfma<1, 1, 1, 1, 1, 0><<<dim3(GX, 2), 256, 0, stream>>>(aggrb, h1b, wt2l, wt2r, bias2, h2b, 128, 256, parts, nullptr, nullptr);
    k_bn_scsh<256><<<256, 64, 0, stream>>>(parts, g2, be2, scsh2, GX);

    // ---- Layer 3 (commuted, BN2 absorbed): ONE dispatch computes both (bf16 outs)
    //      y=0: t3 = h2raw@wt3l' + bias3l; y=1: u3 = h2raw@wt3r' + bias3r
    k_prep3<<<257, 256, 0, stream>>>(W3l, W3r, b3, scsh2, wt3l, wt3r, bias3l, bias3r);
    k_gemm_mfma<0, 1, 0, 1, 0, 1><<<dim3(GX, 2), 256, 0, stream>>>(h2b, nullptr, wt3l, wt3r, bias3l, t3b, 256, 128, nullptr, bias3r, u3b);
    k_agg_reparam<<<AGG_BLKS, 256, 0, stream>>>(t3b, eids, offs, deg, invd, u3b, eps, z);
}

// Round 9
// 256.336 us; speedup vs baseline: 3.2179x; 1.0069x over previous
//
#include <hip/hip_runtime.h>
#include <math.h>

#define N_NODES 50000
#define N_EDGES 800000
#define BN_EPS_F 1e-5f
#define SCAN_BS 512
#define SCAN_NB 98   // ceil(50000/512)
#define GXR 196      // row-chunks of 256 rows
#define GXP2 200     // padded partials stride

typedef unsigned short ushort_t;
typedef unsigned int uint_t;
typedef __attribute__((ext_vector_type(8))) short bf16x8;
typedef __attribute__((ext_vector_type(4))) float f32x4;

static __device__ __forceinline__ float4 ld4(const float* p) {
    return *reinterpret_cast<const float4*>(p);
}
static __device__ __forceinline__ float bf2f(ushort_t u) {
    return __uint_as_float(((uint_t)u) << 16);
}
static __device__ __forceinline__ ushort_t f2b(float f) {
    uint_t u = __float_as_uint(f);
    u += 0x7fffu + ((u >> 16) & 1u);
    return (ushort_t)(u >> 16);
}

// ---------------- CSR build ----------------

__global__ void k_zero_i32(int* __restrict__ p, int n) {
    int i = blockIdx.x * blockDim.x + threadIdx.x;
    if (i < n) p[i] = 0;
}

// fused: countrank (even blocks) + x->bf16 (odd blocks) + weight transposes (tail)
__global__ void k_pre(const int* __restrict__ dst, int* __restrict__ deg,
                      ushort_t* __restrict__ rank,
                      const float* __restrict__ x, ushort_t* __restrict__ xb,
                      const float* __restrict__ W1l, const float* __restrict__ W1r,
                      const float* __restrict__ W2l, ushort_t* __restrict__ wt1l,
                      ushort_t* __restrict__ wt1r, ushort_t* __restrict__ wt2l) {
    int b = blockIdx.x;
    if (b < 6250) {
        int role = b & 1;
        int id = (b >> 1) * 256 + threadIdx.x;   // < 800000 exact
        if (role == 0) {
            rank[id] = (ushort_t)atomicAdd(&deg[dst[id]], 1);
        } else {
            float4 a = ld4(x + (size_t)id * 8);
            float4 c = ld4(x + (size_t)id * 8 + 4);
            uint_t o0 = (uint_t)f2b(a.x) | ((uint_t)f2b(a.y) << 16);
            uint_t o1 = (uint_t)f2b(a.z) | ((uint_t)f2b(a.w) << 16);
            uint_t o2 = (uint_t)f2b(c.x) | ((uint_t)f2b(c.y) << 16);
            uint_t o3 = (uint_t)f2b(c.z) | ((uint_t)f2b(c.w) << 16);
            *reinterpret_cast<uint4*>(xb + (size_t)id * 8) = make_uint4(o0, o1, o2, o3);
        }
    } else {
        int idx = (b - 6250) * 256 + threadIdx.x;   // 0..65535
        if (idx < 16384) {
            int f = idx >> 7, k = idx & 127;
            wt1l[idx] = f2b(W1l[(size_t)k * 128 + f]);
        } else if (idx < 32768) {
            int j = idx - 16384;
            int f = j >> 7, k = j & 127;
            wt1r[j] = f2b(W1r[(size_t)k * 128 + f]);
        } else {
            int j = idx - 32768;                    // F=256 K=128
            int f = j >> 7, k = j & 127;
            wt2l[j] = f2b(W2l[(size_t)k * 256 + f]);
        }
    }
}

__global__ void k_scan1(const int* __restrict__ deg, int* __restrict__ offs, int* __restrict__ bsum) {
    __shared__ int sh[SCAN_BS];
    int t = threadIdx.x;
    int g = blockIdx.x * SCAN_BS + t;
    int v = (g < N_NODES) ? deg[g] : 0;
    sh[t] = v;
    __syncthreads();
    for (int off = 1; off < SCAN_BS; off <<= 1) {
        int add = (t >= off) ? sh[t - off] : 0;
        __syncthreads();
        sh[t] += add;
        __syncthreads();
    }
    if (g < N_NODES) offs[g] = sh[t] - v;
    if (t == SCAN_BS - 1) bsum[blockIdx.x] = sh[t];
}

__global__ void k_scan2(int* __restrict__ bsum, int nb) {
    __shared__ int sh[128];
    int t = threadIdx.x;
    int v = (t < nb) ? bsum[t] : 0;
    sh[t] = v;
    __syncthreads();
    for (int off = 1; off < 128; off <<= 1) {
        int add = (t >= off) ? sh[t - off] : 0;
        __syncthreads();
        sh[t] += add;
        __syncthreads();
    }
    if (t < nb) bsum[t] = sh[t] - v;
}

__global__ void k_scan3(const int* __restrict__ deg, int* __restrict__ offs,
                        const int* __restrict__ bsum, float* __restrict__ inv_deg) {
    int g = blockIdx.x * blockDim.x + threadIdx.x;
    if (g < N_NODES) {
        offs[g] += bsum[g / SCAN_BS];
        int d = deg[g];
        inv_deg[g] = 1.0f / (float)(d > 1 ? d : 1);
    }
}

// atomic-free scatter, ushort payload
__global__ void k_fill2(const int* __restrict__ src, const int* __restrict__ dst,
                        const int* __restrict__ offs, const ushort_t* __restrict__ rank,
                        ushort_t* __restrict__ eids) {
    int e = blockIdx.x * blockDim.x + threadIdx.x;
    if (e < N_EDGES) eids[offs[dst[e]] + (int)rank[e]] = (ushort_t)src[e];
}

// ---------------- late weight prep (need BN scsh) ----------------

__global__ void k_prep2(const float* __restrict__ W2r, const float* __restrict__ b2,
                        const float* __restrict__ scsh1, ushort_t* __restrict__ wt2r,
                        float* __restrict__ bias2) {
    int bid = blockIdx.x;
    if (bid < 128) {
        int idx = bid * 256 + threadIdx.x;      // F=256 K=128
        int f = idx >> 7, k = idx & 127;
        wt2r[idx] = f2b(scsh1[k] * W2r[(size_t)k * 256 + f]);
    } else {
        int f = threadIdx.x;
        float s = b2[f];
        for (int k = 0; k < 128; ++k) s += scsh1[128 + k] * W2r[(size_t)k * 256 + f];
        bias2[f] = s;
    }
}

__global__ void k_prep3(const float* __restrict__ W3l, const float* __restrict__ W3r,
                        const float* __restrict__ b3, const float* __restrict__ scsh2,
                        ushort_t* __restrict__ wt3l, ushort_t* __restrict__ wt3r,
                        float* __restrict__ bias3l, float* __restrict__ bias3r) {
    int bid = blockIdx.x;
    if (bid < 256) {
        int half = bid >> 7;
        int idx = (bid & 127) * 256 + threadIdx.x;   // F=128 K=256
        int f = idx >> 8, k = idx & 255;
        const float* W = half ? W3r : W3l;
        ushort_t* WT = half ? wt3r : wt3l;
        WT[idx] = f2b(scsh2[k] * W[(size_t)k * 128 + f]);
    } else {
        int t = threadIdx.x;
        int f = t & 127;
        const float* W = (t < 128) ? W3l : W3r;
        float s = (t < 128) ? 0.f : b3[f];
        for (int k = 0; k < 256; ++k) s += scsh2[256 + k] * W[(size_t)k * 128 + f];
        float* out = (t < 128) ? bias3l : bias3r;
        out[f] = s;
    }
}

// ---------------- gather core: one 16-lane GROUP per node, 8-deep pipeline ----------------

#define ACCUM8(a) do { \
    acc[0] += bf2f((ushort_t)(a).x); acc[1] += bf2f((ushort_t)((a).x >> 16)); \
    acc[2] += bf2f((ushort_t)(a).y); acc[3] += bf2f((ushort_t)((a).y >> 16)); \
    acc[4] += bf2f((ushort_t)(a).z); acc[5] += bf2f((ushort_t)((a).z >> 16)); \
    acc[6] += bf2f((ushort_t)(a).w); acc[7] += bf2f((ushort_t)((a).w >> 16)); } while (0)

static __device__ __forceinline__ void gather_rows_g(
        const ushort_t* __restrict__ h, const ushort_t* __restrict__ eids,
        int beg, int d, size_t coff, float* acc) {
    int j = 0;
    for (; j + 8 <= d; j += 8) {
        uint4 a[8];
#pragma unroll
        for (int k = 0; k < 8; ++k) {
            int s = eids[beg + j + k];
            a[k] = *reinterpret_cast<const uint4*>(h + (size_t)s * 128 + coff);
        }
#pragma unroll
        for (int k = 0; k < 8; ++k) ACCUM8(a[k]);
    }
    for (; j + 4 <= d; j += 4) {
        uint4 a[4];
#pragma unroll
        for (int k = 0; k < 4; ++k) {
            int s = eids[beg + j + k];
            a[k] = *reinterpret_cast<const uint4*>(h + (size_t)s * 128 + coff);
        }
#pragma unroll
        for (int k = 0; k < 4; ++k) ACCUM8(a[k]);
    }
    for (; j + 2 <= d; j += 2) {
        int s0 = eids[beg + j];
        int s1 = eids[beg + j + 1];
        uint4 a = *reinterpret_cast<const uint4*>(h + (size_t)s0 * 128 + coff);
        uint4 b = *reinterpret_cast<const uint4*>(h + (size_t)s1 * 128 + coff);
        ACCUM8(a); ACCUM8(b);
    }
    if (j < d) {
        int s0 = eids[beg + j];
        uint4 a = *reinterpret_cast<const uint4*>(h + (size_t)s0 * 128 + coff);
        ACCUM8(a);
    }
}

// mean aggregation, one 16-lane group per node (16 nodes/block). BN=1: y = d>0 ? mean*sc+sh : 0
template<int BN>
__global__ __launch_bounds__(256) void k_agg16(
        const ushort_t* __restrict__ h, const ushort_t* __restrict__ eids,
        const int* __restrict__ offs, const int* __restrict__ deg,
        const float* __restrict__ inv_deg, const float* __restrict__ scsh,
        ushort_t* __restrict__ out) {
    const int node = blockIdx.x * 16 + (threadIdx.x >> 4);
    const int lr = threadIdx.x & 15;
    if (node >= N_NODES) return;
    float acc[8];
#pragma unroll
    for (int v = 0; v < 8; ++v) acc[v] = 0.f;
    const int beg = offs[node];
    const int d = deg[node];
    const size_t coff = (size_t)lr * 8;
    gather_rows_g(h, eids, beg, d, coff, acc);

    float sc = inv_deg[node];
    if (BN) {
        float4 sa0 = ld4(&scsh[lr * 8]), sa1 = ld4(&scsh[lr * 8 + 4]);
        float4 sb0 = ld4(&scsh[128 + lr * 8]), sb1 = ld4(&scsh[128 + lr * 8 + 4]);
        if (d > 0) {
            acc[0] = acc[0] * sc * sa0.x + sb0.x; acc[1] = acc[1] * sc * sa0.y + sb0.y;
            acc[2] = acc[2] * sc * sa0.z + sb0.z; acc[3] = acc[3] * sc * sa0.w + sb0.w;
            acc[4] = acc[4] * sc * sa1.x + sb1.x; acc[5] = acc[5] * sc * sa1.y + sb1.y;
            acc[6] = acc[6] * sc * sa1.z + sb1.z; acc[7] = acc[7] * sc * sa1.w + sb1.w;
        } else {
#pragma unroll
            for (int v = 0; v < 8; ++v) acc[v] = 0.f;
        }
    } else {
#pragma unroll
        for (int v = 0; v < 8; ++v) acc[v] *= sc;
    }
    uint4 o;
    o.x = (uint_t)f2b(acc[0]) | ((uint_t)f2b(acc[1]) << 16);
    o.y = (uint_t)f2b(acc[2]) | ((uint_t)f2b(acc[3]) << 16);
    o.z = (uint_t)f2b(acc[4]) | ((uint_t)f2b(acc[5]) << 16);
    o.w = (uint_t)f2b(acc[6]) | ((uint_t)f2b(acc[7]) << 16);
    *reinterpret_cast<uint4*>(out + (size_t)node * 128 + coff) = o;
}

// fused layer-3 aggregate + reparameterize; u is bf16 [N,128]
__global__ __launch_bounds__(256) void k_agg_reparam(
        const ushort_t* __restrict__ t3, const ushort_t* __restrict__ eids,
        const int* __restrict__ offs, const int* __restrict__ deg,
        const float* __restrict__ inv_deg, const ushort_t* __restrict__ u,
        const float* __restrict__ eps, float* __restrict__ z) {
    const int node = blockIdx.x * 16 + (threadIdx.x >> 4);
    const int lr = threadIdx.x & 15;
    if (node >= N_NODES) return;
    float acc[8];
#pragma unroll
    for (int v = 0; v < 8; ++v) acc[v] = 0.f;
    const int beg = offs[node];
    const int d = deg[node];
    const size_t coff = (size_t)lr * 8;
    gather_rows_g(t3, eids, beg, d, coff, acc);
    float ls[8];
#pragma unroll
    for (int v = 0; v < 8; ++v) ls[v] = __shfl_down(acc[v], 8);

    if (lr < 8) {
        float sc = inv_deg[node];
        uint4 um4 = *reinterpret_cast<const uint4*>(u + (size_t)node * 128 + lr * 8);
        uint4 ul4 = *reinterpret_cast<const uint4*>(u + (size_t)node * 128 + 64 + lr * 8);
        const float* ep = eps + (size_t)node * 64 + lr * 8;
        float4 e0 = ld4(ep), e1 = ld4(ep + 4);
        float um[8], ul[8];
        um[0] = bf2f((ushort_t)um4.x); um[1] = bf2f((ushort_t)(um4.x >> 16));
        um[2] = bf2f((ushort_t)um4.y); um[3] = bf2f((ushort_t)(um4.y >> 16));
        um[4] = bf2f((ushort_t)um4.z); um[5] = bf2f((ushort_t)(um4.z >> 16));
        um[6] = bf2f((ushort_t)um4.w); um[7] = bf2f((ushort_t)(um4.w >> 16));
        ul[0] = bf2f((ushort_t)ul4.x); ul[1] = bf2f((ushort_t)(ul4.x >> 16));
        ul[2] = bf2f((ushort_t)ul4.y); ul[3] = bf2f((ushort_t)(ul4.y >> 16));
        ul[4] = bf2f((ushort_t)ul4.z); ul[5] = bf2f((ushort_t)(ul4.z >> 16));
        ul[6] = bf2f((ushort_t)ul4.w); ul[7] = bf2f((ushort_t)(ul4.w >> 16));
        float4 o0, o1;
        o0.x = (acc[0] * sc + um[0]) + expf(ls[0] * sc + ul[0]) * e0.x;
        o0.y = (acc[1] * sc + um[1]) + expf(ls[1] * sc + ul[1]) * e0.y;
        o0.z = (acc[2] * sc + um[2]) + expf(ls[2] * sc + ul[2]) * e0.z;
        o0.w = (acc[3] * sc + um[3]) + expf(ls[3] * sc + ul[3]) * e0.w;
        o1.x = (acc[4] * sc + um[4]) + expf(ls[4] * sc + ul[4]) * e1.x;
        o1.y = (acc[5] * sc + um[5]) + expf(ls[5] * sc + ul[5]) * e1.y;
        o1.z = (acc[6] * sc + um[6]) + expf(ls[6] * sc + ul[6]) * e1.z;
        o1.w = (acc[7] * sc + um[7]) + expf(ls[7] * sc + ul[7]) * e1.w;
        float* zp = z + (size_t)node * 64 + lr * 8;
        *reinterpret_cast<float4*>(zp) = o0;
        *reinterpret_cast<float4*>(zp + 4) = o1;
    }
}

// ---------------- barrier-free direct-fragment MFMA GEMM ----------------
// Block: 4 waves stacked on rows -> 256 rows x 64 cols. Fragments loaded
// directly from global (A row-major [M][K], W [F][K], both bf16, 16B/lane).
// bid decode puts all col-variants of a row-chunk on one XCD (bid&7 class).
// Epilogue: per-wave LDS transpose -> coalesced uint4 bf16 stores.
// SEL3: y = colblk(0..1) + 2*outsel; outsel picks {B,bias,out} pair.

template<int RELU, int DUAL, int STATS, int SEL3, int K, int YT>
__global__ __launch_bounds__(256) void k_gemm_direct(
        const ushort_t* __restrict__ A1, const ushort_t* __restrict__ A2,
        const ushort_t* __restrict__ B1, const ushort_t* __restrict__ B2,
        const float* __restrict__ bias, ushort_t* __restrict__ out,
        int F, float* __restrict__ partials,
        const float* __restrict__ bias2, ushort_t* __restrict__ out2) {
    // decode: class = bid&7 (XCD), rq = (bid>>3)%25, y = (bid>>3)/25
    const int bid = blockIdx.x;
    const int grp = bid >> 3;
    const int y = grp / 25;
    const int rq = grp - y * 25;
    const int r = (bid & 7) + (rq << 3);
    if (r >= GXR) return;
    const int row0 = r * 256;

    int colblk = y, outsel = 0;
    if (SEL3) { colblk = y & 1; outsel = y >> 1; }
    const int col0 = colblk * 64;
    const ushort_t* __restrict__ Bp = (SEL3 && outsel) ? B2 : B1;
    const float* __restrict__ biasp = (SEL3 && outsel) ? bias2 : bias;
    ushort_t* __restrict__ outp = (SEL3 && outsel) ? out2 : out;

    const int tid = threadIdx.x;
    const int lane = tid & 63;
    const int w = tid >> 6;
    const int q = lane >> 4, lr = lane & 15;
    const int wrow = row0 + w * 64;             // wave's 64-row strip

    // A fragment rows (clamped for tail), B fragment cols
    int arow[4];
    const ushort_t* bptr[4];
#pragma unroll
    for (int f = 0; f < 4; ++f) {
        int rr = wrow + f * 16 + lr;
        arow[f] = rr < N_NODES ? rr : N_NODES - 1;
        bptr[f] = Bp + (size_t)(col0 + f * 16 + lr) * K + q * 8;
    }

    f32x4 acc[4][4];
#pragma unroll
    for (int mf = 0; mf < 4; ++mf)
#pragma unroll
        for (int nf = 0; nf < 4; ++nf)
            acc[mf][nf] = (f32x4){0.f, 0.f, 0.f, 0.f};

#pragma unroll
    for (int m = 0; m < (DUAL ? 2 : 1); ++m) {
        const ushort_t* __restrict__ A = m ? A2 : A1;
        const ushort_t* __restrict__ B = m ? B2 : Bp;
#pragma unroll
        for (int k0 = 0; k0 < K; k0 += 32) {
            bf16x8 av[4], bv[4];
#pragma unroll
            for (int f = 0; f < 4; ++f) {
                av[f] = *reinterpret_cast<const bf16x8*>(A + (size_t)arow[f] * K + k0 + q * 8);
                bv[f] = SEL3 ? *reinterpret_cast<const bf16x8*>(bptr[f] + k0)
                             : *reinterpret_cast<const bf16x8*>(B + (size_t)(col0 + f * 16 + lr) * K + k0 + q * 8);
            }
#pragma unroll
            for (int mf = 0; mf < 4; ++mf)
#pragma unroll
                for (int nf = 0; nf < 4; ++nf)
                    acc[mf][nf] = __builtin_amdgcn_mfma_f32_16x16x32_bf16(
                        av[mf], bv[nf], acc[mf][nf], 0, 0, 0);
        }
    }

    // ---- epilogue: bias/relu/stats in regs, LDS transpose, coalesced store
    __shared__ __align__(16) short lw[4][64][68];     // 34816 B pack buffers
    __shared__ float sdf[2][16][64];                  // 8 KB stats partials

    float s[4], s2[4];
#pragma unroll
    for (int nf = 0; nf < 4; ++nf) { s[nf] = 0.f; s2[nf] = 0.f; }
#pragma unroll
    for (int nf = 0; nf < 4; ++nf) {
        float bvs = biasp[col0 + nf * 16 + lr];
#pragma unroll
        for (int mf = 0; mf < 4; ++mf) {
#pragma unroll
            for (int b = 0; b < 4; ++b) {
                int rrow = mf * 16 + q * 4 + b;       // row within wave strip
                float v = acc[mf][nf][b] + bvs;
                if (RELU) v = fmaxf(v, 0.f);
                if (STATS && (wrow + rrow) < N_NODES) { s[nf] += v; s2[nf] += v * v; }
                lw[w][rrow][nf * 16 + lr] = (short)f2b(v);
            }
        }
    }
    // same-wave LDS readback (compiler inserts lgkmcnt wait)
#pragma unroll
    for (int rr = 0; rr < 8; ++rr) {
        int row = rr * 8 + (lane >> 3);
        int gr = wrow + row;
        if (gr < N_NODES) {
            uint4 vv = *reinterpret_cast<const uint4*>(&lw[w][row][(lane & 7) * 8]);
            *reinterpret_cast<uint4*>(outp + (size_t)gr * F + col0 + (lane & 7) * 8) = vv;
        }
    }

    if constexpr (STATS) {
        const int u = w * 4 + q;                      // 16 contributors per col
#pragma unroll
        for (int nf = 0; nf < 4; ++nf) {
            sdf[0][u][nf * 16 + lr] = s[nf];
            sdf[1][u][nf * 16 + lr] = s2[nf];
        }
        __syncthreads();
        if (tid < 64) {
            float ss = 0.f, qq = 0.f;
#pragma unroll
            for (int u2 = 0; u2 < 16; ++u2) {
                ss += sdf[0][u2][tid];
                qq += sdf[1][u2][tid];
            }
            int cg = col0 + tid;
            partials[(size_t)cg * GXP2 + r] = ss;
            partials[(size_t)(F + cg) * GXP2 + r] = qq;
        }
    }
}

// ---------------- BN: reduce partials -> scale/shift ----------------

template<int F>
__global__ __launch_bounds__(64) void k_bn_scsh(
        const float* __restrict__ partials, const float* __restrict__ gamma,
        const float* __restrict__ beta, float* __restrict__ scsh) {
    const int c = blockIdx.x;
    const int l = threadIdx.x;
    float s = 0.f, q2 = 0.f;
    for (int g = l; g < GXR; g += 64) {
        s += partials[(size_t)c * GXP2 + g];
        q2 += partials[(size_t)(F + c) * GXP2 + g];
    }
#pragma unroll
    for (int off = 1; off < 64; off <<= 1) {
        s += __shfl_xor(s, off);
        q2 += __shfl_xor(q2, off);
    }
    if (l == 0) {
        float mean = s * (1.0f / N_NODES);
        float var = q2 * (1.0f / N_NODES) - mean * mean;
        float sc = gamma[c] * rsqrtf(var + BN_EPS_F);
        scsh[c] = sc;
        scsh[F + c] = beta[c] - mean * sc;
    }
}

// ---------------- launch ----------------

extern "C" void kernel_launch(void* const* d_in, const int* in_sizes, int n_in,
                              void* d_out, int out_size, void* d_ws, size_t ws_size,
                              hipStream_t stream) {
    (void)in_sizes; (void)n_in; (void)out_size; (void)ws_size;
    const float* x   = (const float*)d_in[0];
    const int*   src = (const int*)d_in[1];
    const int*   dst = (const int*)d_in[2];
    const float* eps = (const float*)d_in[3];
    const float* W1l = (const float*)d_in[4];
    const float* W1r = (const float*)d_in[5];
    const float* b1  = (const float*)d_in[6];
    const float* g1  = (const float*)d_in[7];
    const float* be1 = (const float*)d_in[8];
    const float* W2l = (const float*)d_in[9];
    const float* W2r = (const float*)d_in[10];
    const float* b2  = (const float*)d_in[11];
    const float* g2  = (const float*)d_in[12];
    const float* be2 = (const float*)d_in[13];
    const float* W3l = (const float*)d_in[14];
    const float* W3r = (const float*)d_in[15];
    const float* b3  = (const float*)d_in[16];
    float* z = (float*)d_out;

    char* ws = (char*)d_ws;
    size_t off = 0;
    auto alloc = [&](size_t bytes) -> char* {
        char* p = ws + off;
        off += (bytes + 255) & ~(size_t)255;
        return p;
    };
    int*      deg    = (int*)alloc(N_NODES * 4);        // zeroed per call
    size_t zero_bytes = off;
    ushort_t* rank   = (ushort_t*)alloc((size_t)N_EDGES * 2);
    ushort_t* eids   = (ushort_t*)alloc((size_t)N_EDGES * 2);
    float*    scshs  = (float*)alloc(1024 * 4);         // scsh1 (256) + scsh2 (512)
    float*    biases = (float*)alloc(512 * 4);          // bias2 + bias3l + bias3r
    int*      offs   = (int*)alloc(N_NODES * 4);
    int*      bsum   = (int*)alloc(128 * 4);
    float*    invd   = (float*)alloc(N_NODES * 4);
    ushort_t* xb     = (ushort_t*)alloc((size_t)N_NODES * 128 * 2);
    ushort_t* h1b    = (ushort_t*)alloc((size_t)N_NODES * 128 * 2);
    ushort_t* h2b    = (ushort_t*)alloc((size_t)N_NODES * 256 * 2);
    ushort_t* aggrb  = (ushort_t*)alloc((size_t)N_NODES * 256 * 2);   // layer-1/2 aggr; reused as t3
    ushort_t* u3b    = (ushort_t*)alloc((size_t)N_NODES * 128 * 2);
    float*    parts  = (float*)alloc((size_t)512 * GXP2 * 4);         // [2F][GXP2], F<=256
    ushort_t* wt1l   = (ushort_t*)alloc(128 * 128 * 2);
    ushort_t* wt1r   = (ushort_t*)alloc(128 * 128 * 2);
    ushort_t* wt2l   = (ushort_t*)alloc(256 * 128 * 2);
    ushort_t* wt2r   = (ushort_t*)alloc(256 * 128 * 2);
    ushort_t* wt3l   = (ushort_t*)alloc(128 * 256 * 2);
    ushort_t* wt3r   = (ushort_t*)alloc(128 * 256 * 2);
    ushort_t* t3b    = aggrb;   // layer-3: t3 (bf16 [N,128]); aggrb free by then

    float* scsh1  = scshs;            // [sc1(128) | sh1(128)]
    float* scsh2  = scshs + 256;      // [sc2(256) | sh2(256)]
    float* bias2  = biases;           // 256
    float* bias3l = biases + 256;     // 128
    float* bias3r = biases + 384;     // 128

    // CSR build: zero deg, then ONE fused dispatch (atomics || x->bf16 || W transposes)
    k_zero_i32<<<((int)(zero_bytes / 4) + 255) / 256, 256, 0, stream>>>((int*)ws, (int)(zero_bytes / 4));
    k_pre<<<6506, 256, 0, stream>>>(dst, deg, rank, x, xb, W1l, W1r, W2l, wt1l, wt1r, wt2l);
    k_scan1<<<SCAN_NB, SCAN_BS, 0, stream>>>(deg, offs, bsum);
    k_scan2<<<1, 128, 0, stream>>>(bsum, SCAN_NB);
    k_scan3<<<(N_NODES + 255) / 256, 256, 0, stream>>>(deg, offs, bsum, invd);
    k_fill2<<<(N_EDGES + 255) / 256, 256, 0, stream>>>(src, dst, offs, rank, eids);

    const int AGG_BLKS = N_NODES / 16;        // 3125: one 16-lane group per node

    // ---- Layer 1: SAGE(x) -> relu (+fused BN stats)  (K=128, F=128, YT=2)
    k_agg16<0><<<AGG_BLKS, 256, 0, stream>>>(xb, eids, offs, deg, invd, nullptr, aggrb);
    k_gemm_direct<1, 1, 1, 0, 128, 2><<<400, 256, 0, stream>>>(
        aggrb, xb, wt1l, wt1r, b1, h1b, 128, parts, nullptr, nullptr);
    k_bn_scsh<128><<<128, 64, 0, stream>>>(parts, g1, be1, scsh1);

    // ---- Layer 2: BN1 absorbed (agg-side fused, self-side in wt2r/bias2)  (K=128, F=256, YT=4)
    k_prep2<<<129, 256, 0, stream>>>(W2r, b2, scsh1, wt2r, bias2);
    k_agg16<1><<<AGG_BLKS, 256, 0, stream>>>(h1b, eids, offs, deg, invd, scsh1, aggrb);
    k_gemm_direct<1, 1, 1, 0, 128, 4><<<800, 256, 0, stream>>>(
        aggrb, h1b, wt2l, wt2r, bias2, h2b, 256, parts, nullptr, nullptr);
    k_bn_scsh<256><<<256, 64, 0, stream>>>(parts, g2, be2, scsh2);

    // ---- Layer 3 (commuted, BN2 absorbed): ONE dispatch, SEL3 picks output
    //      outsel=0: t3 = h2@wt3l' + bias3l; outsel=1: u3 = h2@wt3r' + bias3r
    k_prep3<<<257, 256, 0, stream>>>(W3l, W3r, b3, scsh2, wt3l, wt3r, bias3l, bias3r);
    k_gemm_direct<0, 0, 0, 1, 256, 4><<<800, 256, 0, stream>>>(
        h2b, nullptr, wt3l, wt3r, bias3l, t3b, 128, nullptr, bias3r, u3b);
    k_agg_reparam<<<AGG_BLKS, 256, 0, stream>>>(t3b, eids, offs, deg, invd, u3b, eps, z);
}